// Round 1
// 922.963 us; speedup vs baseline: 1.1060x; 1.1060x over previous
//
#include <hip/hip_runtime.h>
#include <hip/hip_bf16.h>

typedef __hip_bfloat16 bf16;
#define DEV __device__ __forceinline__

// storage-dtype-generic accessors (F32 ? fp32 : bf16)
template<bool F32> DEV float LDX(const void* p, size_t i) {
  return F32 ? ((const float*)p)[i] : __bfloat162float(((const bf16*)p)[i]);
}
template<bool F32> DEV void STX(void* p, size_t i, float v) {
  if (F32) ((float*)p)[i] = v; else ((bf16*)p)[i] = __float2bfloat16(v);
}

DEV float wsum64(float v) {
  v += __shfl_xor(v, 1, 64);
  v += __shfl_xor(v, 2, 64);
  v += __shfl_xor(v, 4, 64);
  v += __shfl_xor(v, 8, 64);
  v += __shfl_xor(v, 16, 64);
  v += __shfl_xor(v, 32, 64);
  return v;
}

// Fold W_de/W_m through per-head column-sums of Wpd/Wpm.
// fold layout per layer l (stride 128 floats): [0..63] A_de[16][4],
// [64..95] A_m[8][4], [96..99] c[4]
__global__ __launch_bounds__(64) void fold_kernel(
    const float* __restrict__ W_de, const float* __restrict__ b_de,
    const float* __restrict__ W_m,  const float* __restrict__ b_m,
    const float* __restrict__ Wpd,  const float* __restrict__ bpd,
    const float* __restrict__ Wpm,  const float* __restrict__ bpm,
    float* __restrict__ fold)
{
  __shared__ float spd[64][4], spm[64][4];
  int t = threadIdx.x; // 0..63
  for (int l = 0; l < 2; ++l) {
    const float* wpd = Wpd + l * 4096;
    const float* wpm = Wpm + l * 4096;
    for (int hh = 0; hh < 4; ++hh) {
      float sd = 0.f, sm = 0.f;
      for (int hd = 0; hd < 16; ++hd) {
        sd += wpd[t * 64 + hh * 16 + hd];
        sm += wpm[t * 64 + hh * 16 + hd];
      }
      spd[t][hh] = sd; spm[t][hh] = sm;
    }
    __syncthreads();
    { // A_de[16][4]
      int i = t >> 2, hh = t & 3;
      float a = 0.f;
      for (int k = 0; k < 64; ++k) a += W_de[i * 64 + k] * spd[k][hh];
      fold[l * 128 + i * 4 + hh] = a;
    }
    if (t < 32) { // A_m[8][4]
      int i = t >> 2, hh = t & 3;
      float a = 0.f;
      for (int k = 0; k < 64; ++k) a += W_m[i * 64 + k] * spm[k][hh];
      fold[l * 128 + 64 + i * 4 + hh] = a;
    }
    if (t < 4) { // c[4] (zero in practice: all biases are zeros)
      int hh = t;
      float a = 0.f;
      for (int k = 0; k < 64; ++k)
        a += b_de[k] * spd[k][hh] + b_m[k] * spm[k][hh];
      for (int hd = 0; hd < 16; ++hd)
        a += bpd[l * 64 + hh * 16 + hd] + bpm[l * 64 + hh * 16 + hd];
      fold[l * 128 + 96 + hh] = a;
    }
    __syncthreads();
  }
}

// Per-edge folded score term for BOTH layers: ps[l][e][hh] =
// de_row . A_de[:,hh] + m_row . A_m[:,hh] + c[hh].
// Pure streaming kernel; removes de/m from the latency-critical edge loop.
__global__ __launch_bounds__(256) void escore_kernel(
    const float* __restrict__ de, const float* __restrict__ m,
    const float* __restrict__ fold, float* __restrict__ ps, int E)
{
  int e = blockIdx.x * 256 + threadIdx.x;
  if (e >= E) return;
  float dv[16], mv[8];
  #pragma unroll
  for (int i = 0; i < 4; ++i)
    *(float4*)(dv + 4 * i) = ((const float4*)(de + (size_t)e * 16))[i];
  #pragma unroll
  for (int i = 0; i < 2; ++i)
    *(float4*)(mv + 4 * i) = ((const float4*)(m + (size_t)e * 8))[i];
  #pragma unroll
  for (int l = 0; l < 2; ++l) {
    const float* f = fold + l * 128; // uniform -> scalar loads
    float4 o;
    float* op = (float*)&o;
    #pragma unroll
    for (int hh = 0; hh < 4; ++hh) {
      float a = f[96 + hh];
      #pragma unroll
      for (int i = 0; i < 16; ++i) a += dv[i] * f[i * 4 + hh];
      #pragma unroll
      for (int i = 0; i < 8; ++i) a += mv[i] * f[64 + i * 4 + hh];
      op[hh] = a;
    }
    ((float4*)(ps + (size_t)l * (size_t)E * 4))[e] = o;
  }
}

// dst is sorted: CSR offsets via binary search, no atomics.
__global__ __launch_bounds__(256) void rowptr_kernel(
    const int* __restrict__ dst, int E, int N, int* __restrict__ rp)
{
  int n = blockIdx.x * blockDim.x + threadIdx.x;
  if (n > N) return;
  int lo = 0, hi = E;
  while (lo < hi) {
    int mid = (lo + hi) >> 1;
    if (dst[mid] < n) lo = mid + 1; else hi = mid;
  }
  rp[n] = lo;
}

// h = x@W_h + pe@W_pe + b_pe ; one wave per row, lane = output col
template<bool H32>
__global__ __launch_bounds__(256) void hinit_kernel(
    const float* __restrict__ x, const float* __restrict__ pe,
    const float* __restrict__ W_h, const float* __restrict__ W_pe,
    const float* __restrict__ b_pe, void* __restrict__ H, int N)
{
  int w = blockIdx.x * 4 + (threadIdx.x >> 6);
  if (w >= N) return;
  int lane = threadIdx.x & 63;
  float x0 = x[(size_t)w * 128 + lane];
  float x1 = x[(size_t)w * 128 + 64 + lane];
  float pr = pe[(size_t)w * 16 + (lane & 15)];
  float a0 = b_pe[lane], a1 = 0.f;
  #pragma unroll 8
  for (int i = 0; i < 64; i += 2) {
    a0 += __shfl(x0, i, 64) * W_h[i * 64 + lane];
    a1 += __shfl(x0, i + 1, 64) * W_h[(i + 1) * 64 + lane];
  }
  #pragma unroll 8
  for (int i = 0; i < 64; i += 2) {
    a0 += __shfl(x1, i, 64) * W_h[(64 + i) * 64 + lane];
    a1 += __shfl(x1, i + 1, 64) * W_h[(64 + i + 1) * 64 + lane];
  }
  #pragma unroll
  for (int i = 0; i < 16; i += 2) {
    a0 += __shfl(pr, i, 64) * W_pe[i * 64 + lane];
    a1 += __shfl(pr, i + 1, 64) * W_pe[(i + 1) * 64 + lane];
  }
  STX<H32>(H, (size_t)w * 64 + lane, a0 + a1);
}

// K,V = h@W + b for layer l; one wave per row
template<bool H32, bool KV32>
__global__ __launch_bounds__(256) void kv_kernel(
    const void* __restrict__ H,
    const float* __restrict__ Wk, const float* __restrict__ bk,
    const float* __restrict__ Wv, const float* __restrict__ bv,
    void* __restrict__ K, void* __restrict__ V, int N, int l)
{
  int w = blockIdx.x * 4 + (threadIdx.x >> 6);
  if (w >= N) return;
  int lane = threadIdx.x & 63;
  const float* wk = Wk + l * 4096;
  const float* wv = Wv + l * 4096;
  float h = LDX<H32>(H, (size_t)w * 64 + lane);
  float ka = bk[l * 64 + lane];
  float va = bv[l * 64 + lane];
  #pragma unroll 8
  for (int k = 0; k < 64; ++k) {
    float hk = __shfl(h, k, 64);
    ka += hk * wk[k * 64 + lane];
    va += hk * wv[k * 64 + lane];
  }
  size_t o = (size_t)w * 64 + lane;
  STX<KV32>(K, o, ka);
  STX<KV32>(V, o, va);
}

// --- edge-loop chunk helpers: U independent gathers in flight per chunk ---
template<int U, bool KV32>
DEV void edge_chunk_ps(const void* __restrict__ K, const void* __restrict__ V,
                       const int* __restrict__ src, const float* __restrict__ psl,
                       int e, int lane, int hh, float q4,
                       float& acc, float& z)
{
  int s_[U]; float pk[U], pv[U], pp[U];
  #pragma unroll
  for (int u = 0; u < U; ++u) s_[u] = src[e + u];
  #pragma unroll
  for (int u = 0; u < U; ++u) {
    pk[u] = LDX<KV32>(K, (size_t)s_[u] * 64 + lane);
    pv[u] = LDX<KV32>(V, (size_t)s_[u] * 64 + lane);
  }
  #pragma unroll
  for (int u = 0; u < U; ++u) pp[u] = psl[(size_t)(e + u) * 4 + hh];
  #pragma unroll
  for (int u = 0; u < U; ++u) {
    float t = pk[u] * q4;
    t += __shfl_xor(t, 1, 64);
    t += __shfl_xor(t, 2, 64);
    t += __shfl_xor(t, 4, 64);
    t += __shfl_xor(t, 8, 64);
    float sv = __expf(fminf(fmaxf(t + pp[u], -5.f), 5.f));
    acc += sv * pv[u];
    z += sv;
  }
}

template<int U, bool KV32>
DEV void edge_chunk_dm(const void* __restrict__ K, const void* __restrict__ V,
                       const int* __restrict__ src,
                       const float* __restrict__ de, const float* __restrict__ m,
                       int e, int lane, int hh, int hd,
                       float a_de, float a_m, float c, float q4,
                       float& acc, float& z)
{
  int s_[U]; float pk[U], pv[U], pd[U], pm[U];
  #pragma unroll
  for (int u = 0; u < U; ++u) s_[u] = src[e + u];
  #pragma unroll
  for (int u = 0; u < U; ++u) {
    pk[u] = LDX<KV32>(K, (size_t)s_[u] * 64 + lane);
    pv[u] = LDX<KV32>(V, (size_t)s_[u] * 64 + lane);
    pd[u] = de[(size_t)(e + u) * 16 + hd];
    pm[u] = (hd < 8) ? m[(size_t)(e + u) * 8 + hd] : 0.f;
  }
  #pragma unroll
  for (int u = 0; u < U; ++u) {
    float t = pk[u] * q4 + pd[u] * a_de + pm[u] * a_m;
    t += __shfl_xor(t, 1, 64);
    t += __shfl_xor(t, 2, 64);
    t += __shfl_xor(t, 4, 64);
    t += __shfl_xor(t, 8, 64);
    float sv = __expf(fminf(fmaxf(t + c, -5.f), 5.f));
    acc += sv * pv[u];
    z += sv;
  }
}

// Fused per-layer: Q row matvec -> attention edge loop -> Wpi/WO/LN/FFN/LN.
// One wave per destination node; lane = head*16 + hd = output col.
template<bool H32, bool KV32, bool PS>
__global__ __launch_bounds__(256) void layer_kernel(
    void* __restrict__ H, const void* __restrict__ K, const void* __restrict__ V,
    const int* __restrict__ src, const int* __restrict__ rp,
    const float* __restrict__ de, const float* __restrict__ m,
    const float* __restrict__ fold, const float* __restrict__ eps,
    const float* __restrict__ Wq, const float* __restrict__ bq,
    const float* __restrict__ I, const float* __restrict__ Wpi, const float* __restrict__ bpi,
    const float* __restrict__ WO, const float* __restrict__ bO,
    const float* __restrict__ g1, const float* __restrict__ b1,
    const float* __restrict__ Wf1, const float* __restrict__ bf1,
    const float* __restrict__ Wf2, const float* __restrict__ bf2,
    const float* __restrict__ g2, const float* __restrict__ b2,
    int N, int E, int l)
{
  constexpr float BN_S = 0.9999950000374997f; // 1/sqrt(1+1e-5)
  int w = blockIdx.x * 4 + (threadIdx.x >> 6);
  if (w >= N) return;
  int lane = threadIdx.x & 63;
  int hh = lane >> 4, hd = lane & 15;

  float h = LDX<H32>(H, (size_t)w * 64 + lane); // residual h_in1

  // Q row = h@Wq + bq (dual accumulator: halve dependent-FMA chain)
  const float* wq = Wq + l * 4096;
  float q0 = bq[l * 64 + lane], q1 = 0.f;
  #pragma unroll 8
  for (int k = 0; k < 64; k += 2) {
    q0 += __shfl(h, k, 64) * wq[k * 64 + lane];
    q1 += __shfl(h, k + 1, 64) * wq[(k + 1) * 64 + lane];
  }
  // score = 16*(dot*SCALE) + folded = 4*dot + folded -> fold 4 into q once
  float q4 = 4.f * (q0 + q1);

  // attention over incoming edges, 8-wide software-pipelined gathers
  float acc = 0.f, z = 0.f;
  int e0 = rp[w], e1 = rp[w + 1];
  int e = e0;
  if (PS) {
    const float* psl = eps + (size_t)l * (size_t)E * 4;
    for (; e + 8 <= e1; e += 8)
      edge_chunk_ps<8, KV32>(K, V, src, psl, e, lane, hh, q4, acc, z);
    if (e + 4 <= e1) {
      edge_chunk_ps<4, KV32>(K, V, src, psl, e, lane, hh, q4, acc, z);
      e += 4;
    }
    for (; e < e1; ++e)
      edge_chunk_ps<1, KV32>(K, V, src, psl, e, lane, hh, q4, acc, z);
  } else {
    const float* f = fold + l * 128;
    float a_de = f[hd * 4 + hh];
    float a_m = (hd < 8) ? f[64 + hd * 4 + hh] : 0.f;
    float c = f[96 + hh];
    for (; e + 4 <= e1; e += 4)
      edge_chunk_dm<4, KV32>(K, V, src, de, m, e, lane, hh, hd, a_de, a_m, c, q4, acc, z);
    for (; e < e1; ++e)
      edge_chunk_dm<1, KV32>(K, V, src, de, m, e, lane, hh, hd, a_de, a_m, c, q4, acc, z);
  }
  float attn = acc / (z + 1e-10f);

  // u = attn + I@Wpi + bpi
  float Ir = I[(size_t)w * 16 + (lane & 15)];
  float u = attn + bpi[l * 64 + lane];
  const float* wpi = Wpi + l * 1024;
  #pragma unroll
  for (int i = 0; i < 16; ++i) u += __shfl(Ir, i, 64) * wpi[i * 64 + lane];

  // v = u@WO + bO ; h1 = LN(h + v)*BN_S
  const float* wo = WO + l * 4096;
  float v0 = bO[l * 64 + lane], v1 = 0.f;
  #pragma unroll 8
  for (int k = 0; k < 64; k += 2) {
    v0 += __shfl(u, k, 64) * wo[k * 64 + lane];
    v1 += __shfl(u, k + 1, 64) * wo[(k + 1) * 64 + lane];
  }
  float hw = h + v0 + v1;
  float mu = wsum64(hw) * (1.f / 64.f);
  float d = hw - mu;
  float var = wsum64(d * d) * (1.f / 64.f);
  float rs = 1.f / sqrtf(var + 1e-5f);
  float h1 = (d * rs * g1[l * 64 + lane] + b1[l * 64 + lane]) * BN_S;

  // FFN: relu(h1@Wf1+bf1)@Wf2+bf2
  const float* wf1 = Wf1 + l * 8192;
  float t0 = bf1[l * 128 + lane];
  float t1 = bf1[l * 128 + 64 + lane];
  #pragma unroll 4
  for (int k = 0; k < 64; ++k) {
    float hk = __shfl(h1, k, 64);
    t0 += hk * wf1[k * 128 + lane];
    t1 += hk * wf1[k * 128 + 64 + lane];
  }
  t0 = fmaxf(t0, 0.f);
  t1 = fmaxf(t1, 0.f);
  const float* wf2 = Wf2 + l * 8192;
  float y0 = bf2[l * 64 + lane], y1 = 0.f;
  #pragma unroll 8
  for (int j = 0; j < 64; ++j) {
    y0 += __shfl(t0, j, 64) * wf2[j * 64 + lane];
    y1 += __shfl(t1, j, 64) * wf2[(64 + j) * 64 + lane];
  }
  float w2 = h1 + y0 + y1;
  float mu2 = wsum64(w2) * (1.f / 64.f);
  float d2 = w2 - mu2;
  float var2 = wsum64(d2 * d2) * (1.f / 64.f);
  float rs2 = 1.f / sqrtf(var2 + 1e-5f);
  float h2 = (d2 * rs2 * g2[l * 64 + lane] + b2[l * 64 + lane]) * BN_S;
  STX<H32>(H, (size_t)w * 64 + lane, h2);
}

// out0 = h (fp32); x_hat = selu(h@Wr1+br1)@Wr2+br2 (fp32)
template<bool H32>
__global__ __launch_bounds__(256) void readout_kernel(
    const void* __restrict__ H,
    const float* __restrict__ Wr1, const float* __restrict__ br1,
    const float* __restrict__ Wr2, const float* __restrict__ br2,
    float* __restrict__ out, int N)
{
  int w = blockIdx.x * 4 + (threadIdx.x >> 6);
  if (w >= N) return;
  int lane = threadIdx.x & 63;
  float h = LDX<H32>(H, (size_t)w * 64 + lane);
  out[(size_t)w * 64 + lane] = h;
  int j = lane & 15;
  float md = br1[j];
  #pragma unroll 8
  for (int k = 0; k < 64; ++k) md += __shfl(h, k, 64) * Wr1[k * 16 + j];
  const float SC = 1.0507009873554805f, AL = 1.6732632423543772f;
  md = (md > 0.f) ? SC * md : SC * AL * expm1f(md);
  float x0 = br2[lane];
  float x1 = br2[64 + lane];
  #pragma unroll
  for (int jj = 0; jj < 16; ++jj) {
    float mj = __shfl(md, jj, 64);
    x0 += mj * Wr2[jj * 128 + lane];
    x1 += mj * Wr2[jj * 128 + 64 + lane];
  }
  size_t base = (size_t)N * 64 + (size_t)w * 128;
  out[base + lane] = x0;
  out[base + 64 + lane] = x1;
}

extern "C" void kernel_launch(void* const* d_in, const int* in_sizes, int n_in,
                              void* d_out, int out_size, void* d_ws, size_t ws_size,
                              hipStream_t stream)
{
  const int* src    = (const int*)d_in[0];
  const int* dst    = (const int*)d_in[1];
  const float* x    = (const float*)d_in[2];
  const float* pe   = (const float*)d_in[3];
  const float* de   = (const float*)d_in[4];
  const float* m    = (const float*)d_in[5];
  const float* I    = (const float*)d_in[6];
  const float* W_h  = (const float*)d_in[7];
  const float* W_pe = (const float*)d_in[8];
  const float* b_pe = (const float*)d_in[9];
  const float* W_de = (const float*)d_in[10];
  const float* b_de = (const float*)d_in[11];
  const float* W_m  = (const float*)d_in[12];
  const float* b_m  = (const float*)d_in[13];
  const float* Wq   = (const float*)d_in[14];
  const float* bq   = (const float*)d_in[15];
  const float* Wk   = (const float*)d_in[16];
  const float* bk   = (const float*)d_in[17];
  const float* Wv   = (const float*)d_in[18];
  const float* bv   = (const float*)d_in[19];
  const float* Wpd  = (const float*)d_in[20];
  const float* bpd  = (const float*)d_in[21];
  const float* Wpm  = (const float*)d_in[22];
  const float* bpm  = (const float*)d_in[23];
  const float* WO   = (const float*)d_in[24];
  const float* bO   = (const float*)d_in[25];
  const float* Wpi  = (const float*)d_in[26];
  const float* bpi  = (const float*)d_in[27];
  const float* g1   = (const float*)d_in[28];
  const float* b1   = (const float*)d_in[29];
  const float* g2   = (const float*)d_in[30];
  const float* b2   = (const float*)d_in[31];
  const float* Wf1  = (const float*)d_in[32];
  const float* bf1  = (const float*)d_in[33];
  const float* Wf2  = (const float*)d_in[34];
  const float* bf2  = (const float*)d_in[35];
  const float* Wr1  = (const float*)d_in[36];
  const float* br1  = (const float*)d_in[37];
  const float* Wr2  = (const float*)d_in[38];
  const float* br2  = (const float*)d_in[39];

  const int E = in_sizes[0];
  const int N = in_sizes[2] / 128;
  const size_t b64 = (size_t)N * 64;

  // ws layout: row_ptr | fold | H | [K | V] | [ps] — ALL scratch in d_ws.
  char* ws = (char*)d_ws;
  int* row_ptr = (int*)ws;
  size_t rp_bytes = (((size_t)(N + 1) * 4) + 255) & ~(size_t)255;
  float* fold = (float*)(ws + rp_bytes);
  char* buf = ws + rp_bytes + 1024;
  size_t base = rp_bytes + 1024;
  float* out = (float*)d_out;

  void *Hp, *Kp, *Vp;
  size_t endoff;
  int tier;
  if (ws_size >= base + 3 * b64 * 4) {            // T1: H,K,V fp32
    tier = 1; Hp = buf; Kp = buf + b64 * 4; Vp = buf + 2 * b64 * 4;
    endoff = base + 3 * b64 * 4;
  } else if (ws_size >= base + b64 * 4 + 2 * b64 * 2) { // T2: H fp32, K/V bf16
    tier = 2; Hp = buf; Kp = buf + b64 * 4; Vp = buf + b64 * 4 + b64 * 2;
    endoff = base + b64 * 4 + 2 * b64 * 2;
  } else if (ws_size >= base + 3 * b64 * 2) {     // T3: all bf16
    tier = 3; Hp = buf; Kp = buf + b64 * 2; Vp = buf + 2 * b64 * 2;
    endoff = base + 3 * b64 * 2;
  } else {                                        // T4: H,K bf16 ws; V bf16 in d_out
    tier = 4; Hp = buf; Kp = buf + b64 * 2; Vp = (void*)(out + b64);
    endoff = base + 2 * b64 * 2;
  }

  // per-edge folded score table (both layers), if workspace allows
  size_t psb = (size_t)E * 32; // 2 layers * 4 heads * 4B
  float* eps = (ws_size >= endoff + psb) ? (float*)(ws + endoff) : nullptr;

  int nb = (N + 3) / 4; // 4 waves (rows/nodes) per 256-thread block

  rowptr_kernel<<<(N + 256) / 256, 256, 0, stream>>>(dst, E, N, row_ptr);
  fold_kernel<<<1, 64, 0, stream>>>(W_de, b_de, W_m, b_m, Wpd, bpd, Wpm, bpm, fold);
  if (eps)
    escore_kernel<<<(E + 255) / 256, 256, 0, stream>>>(de, m, fold, eps, E);

#define PIPE(H32V, KV32V)                                                          \
  do {                                                                             \
    hinit_kernel<H32V><<<nb, 256, 0, stream>>>(x, pe, W_h, W_pe, b_pe, Hp, N);     \
    for (int l = 0; l < 2; ++l) {                                                  \
      kv_kernel<H32V, KV32V><<<nb, 256, 0, stream>>>(Hp, Wk, bk, Wv, bv, Kp, Vp, N, l); \
      if (eps)                                                                     \
        layer_kernel<H32V, KV32V, true><<<nb, 256, 0, stream>>>(Hp, Kp, Vp, src,   \
            row_ptr, de, m, fold, eps, Wq, bq, I, Wpi, bpi, WO, bO, g1, b1,        \
            Wf1, bf1, Wf2, bf2, g2, b2, N, E, l);                                  \
      else                                                                         \
        layer_kernel<H32V, KV32V, false><<<nb, 256, 0, stream>>>(Hp, Kp, Vp, src,  \
            row_ptr, de, m, fold, eps, Wq, bq, I, Wpi, bpi, WO, bO, g1, b1,        \
            Wf1, bf1, Wf2, bf2, g2, b2, N, E, l);                                  \
    }                                                                              \
    readout_kernel<H32V><<<nb, 256, 0, stream>>>(Hp, Wr1, br1, Wr2, br2, out, N);  \
  } while (0)

  if (tier == 1)      PIPE(true, true);
  else if (tier == 2) PIPE(true, false);
  else                PIPE(false, false); // tiers 3 & 4 share dtypes

#undef PIPE
}

// Round 2
// 643.724 us; speedup vs baseline: 1.5857x; 1.4338x over previous
//
#include <hip/hip_runtime.h>
#include <hip/hip_bf16.h>

typedef __hip_bfloat16 bf16;
typedef __attribute__((ext_vector_type(8))) short s8v;
typedef __attribute__((ext_vector_type(4))) float f4v;
#define DEV __device__ __forceinline__
#define MFMA(a, b, c) __builtin_amdgcn_mfma_f32_16x16x32_bf16(a, b, c, 0, 0, 0)

// split-bf16 weight table offsets (elements); each section: [hi sz][lo sz]
constexpr int OFF_WQ = 0, OFF_WK = 8192, OFF_WV = 16384, OFF_WO = 24576;
constexpr int OFF_WF1 = 32768, OFF_WF2 = 49152, OFF_WPI = 65536;
constexpr int PL = 69632; // per-layer stride
constexpr int OFF_WH = 139264, OFF_WPE = 155648, OFF_WR1 = 159744, OFF_WR2 = 161792;
constexpr int WBF_TOT = 169984;

DEV short f2bs(float f) { union { bf16 b; short s; } u; u.b = __float2bfloat16(f); return u.s; }
DEV float bs2f(short s) { union { bf16 b; short s2; } u; u.s2 = s; return __bfloat162float(u.b); }

DEV void split8(const float* p, s8v& hi, s8v& lo) {
  #pragma unroll
  for (int j = 0; j < 8; ++j) {
    float f = p[j];
    short h = f2bs(f);
    hi[j] = h;
    lo[j] = f2bs(f - bs2f(h));
  }
}

// ---------------- weight prep: transpose + split to bf16 hi/lo ----------------
__global__ __launch_bounds__(256) void prep_kernel(
    const float* __restrict__ Wq, const float* __restrict__ Wk,
    const float* __restrict__ Wv, const float* __restrict__ WO,
    const float* __restrict__ Wf1, const float* __restrict__ Wf2,
    const float* __restrict__ Wpi, const float* __restrict__ W_h,
    const float* __restrict__ W_pe, const float* __restrict__ Wr1,
    const float* __restrict__ Wr2, short* __restrict__ wb)
{
  const float* srcs[18] = {
    Wq, Wk, Wv, WO, Wf1, Wf2, Wpi,
    Wq + 4096, Wk + 4096, Wv + 4096, WO + 4096, Wf1 + 8192, Wf2 + 8192, Wpi + 1024,
    W_h, W_pe, Wr1, Wr2 };
  const int Ks[18]  = {64,64,64,64, 64,128,16, 64,64,64,64, 64,128,16, 128,16,64,16};
  const int Kps[18] = {64,64,64,64, 64,128,32, 64,64,64,64, 64,128,32, 128,32,64,32};
  const int Ncs[18] = {64,64,64,64,128, 64,64, 64,64,64,64,128, 64,64,  64,64,16,128};
  const int dsts[18] = {
    OFF_WQ, OFF_WK, OFF_WV, OFF_WO, OFF_WF1, OFF_WF2, OFF_WPI,
    PL + OFF_WQ, PL + OFF_WK, PL + OFF_WV, PL + OFF_WO, PL + OFF_WF1, PL + OFF_WF2, PL + OFF_WPI,
    OFF_WH, OFF_WPE, OFF_WR1, OFF_WR2 };
  int gid = blockIdx.x * 256 + threadIdx.x, gsz = gridDim.x * 256;
  #pragma unroll 1
  for (int s = 0; s < 18; ++s) {
    const float* sp = srcs[s];
    int K = Ks[s], Kp = Kps[s], Nc = Ncs[s], d0 = dsts[s];
    int tot = Kp * Nc;
    for (int i = gid; i < tot; i += gsz) {
      int o = i / Kp, kk = i % Kp;
      float v = (kk < K) ? sp[kk * Nc + o] : 0.f; // dst[o][kk] = src[kk][o], zero-pad K
      short h = f2bs(v);
      wb[d0 + i] = h;
      wb[d0 + tot + i] = f2bs(v - bs2f(h));
    }
  }
}

// ---------------- fold de/m through per-head column sums (unchanged) ----------------
__global__ __launch_bounds__(64) void fold_kernel(
    const float* __restrict__ W_de, const float* __restrict__ b_de,
    const float* __restrict__ W_m,  const float* __restrict__ b_m,
    const float* __restrict__ Wpd,  const float* __restrict__ bpd,
    const float* __restrict__ Wpm,  const float* __restrict__ bpm,
    float* __restrict__ fold)
{
  __shared__ float spd[64][4], spm[64][4];
  int t = threadIdx.x;
  for (int l = 0; l < 2; ++l) {
    const float* wpd = Wpd + l * 4096;
    const float* wpm = Wpm + l * 4096;
    for (int hh = 0; hh < 4; ++hh) {
      float sd = 0.f, sm = 0.f;
      for (int hd = 0; hd < 16; ++hd) {
        sd += wpd[t * 64 + hh * 16 + hd];
        sm += wpm[t * 64 + hh * 16 + hd];
      }
      spd[t][hh] = sd; spm[t][hh] = sm;
    }
    __syncthreads();
    { int i = t >> 2, hh = t & 3;
      float a = 0.f;
      for (int k = 0; k < 64; ++k) a += W_de[i * 64 + k] * spd[k][hh];
      fold[l * 128 + i * 4 + hh] = a; }
    if (t < 32) { int i = t >> 2, hh = t & 3;
      float a = 0.f;
      for (int k = 0; k < 64; ++k) a += W_m[i * 64 + k] * spm[k][hh];
      fold[l * 128 + 64 + i * 4 + hh] = a; }
    if (t < 4) { int hh = t;
      float a = 0.f;
      for (int k = 0; k < 64; ++k) a += b_de[k] * spd[k][hh] + b_m[k] * spm[k][hh];
      for (int hd = 0; hd < 16; ++hd)
        a += bpd[l * 64 + hh * 16 + hd] + bpm[l * 64 + hh * 16 + hd];
      fold[l * 128 + 96 + hh] = a; }
    __syncthreads();
  }
}

// ---------------- per-edge folded score (one layer), bf16 out ----------------
__global__ __launch_bounds__(256) void escore_kernel(
    const float* __restrict__ de, const float* __restrict__ m,
    const float* __restrict__ fold, ushort* __restrict__ epsl, int E, int lay)
{
  int e = blockIdx.x * 256 + threadIdx.x;
  if (e >= E) return;
  float dv[16], mv[8];
  #pragma unroll
  for (int i = 0; i < 4; ++i)
    *(float4*)(dv + 4 * i) = ((const float4*)(de + (size_t)e * 16))[i];
  #pragma unroll
  for (int i = 0; i < 2; ++i)
    *(float4*)(mv + 4 * i) = ((const float4*)(m + (size_t)e * 8))[i];
  const float* f = fold + lay * 128;
  ushort4 o;
  ushort* op = (ushort*)&o;
  #pragma unroll
  for (int hh = 0; hh < 4; ++hh) {
    float a = f[96 + hh];
    #pragma unroll
    for (int i = 0; i < 16; ++i) a += dv[i] * f[i * 4 + hh];
    #pragma unroll
    for (int i = 0; i < 8; ++i) a += mv[i] * f[64 + i * 4 + hh];
    op[hh] = (ushort)f2bs(a);
  }
  *(ushort4*)(epsl + (size_t)e * 4) = o;
}

// ---------------- CSR rowptr ----------------
__global__ __launch_bounds__(256) void rowptr_kernel(
    const int* __restrict__ dst, int E, int N, int* __restrict__ rp)
{
  int n = blockIdx.x * blockDim.x + threadIdx.x;
  if (n > N) return;
  int lo = 0, hi = E;
  while (lo < hi) {
    int mid = (lo + hi) >> 1;
    if (dst[mid] < n) lo = mid + 1; else hi = mid;
  }
  rp[n] = lo;
}

// ---------------- hinit: H = x@W_h + pe@W_pe + b_pe (MFMA, split A+B) ----------------
__global__ __launch_bounds__(256) void hinit_mfma(
    const float* __restrict__ x, const float* __restrict__ pe,
    const short* __restrict__ wb, const float* __restrict__ b_pe,
    ushort* __restrict__ Hb, int N)
{
  __shared__ __align__(16) ushort sH[64][72];
  int tid = threadIdx.x, wv = tid >> 6, ln = tid & 63;
  int q = ln >> 4, p16 = ln & 15;
  int nb0 = blockIdx.x * 64;
  int arow = nb0 + wv * 16 + p16; if (arow >= N) arow = N - 1;
  f4v acc[4] = {};
  for (int kt = 0; kt < 4; ++kt) {
    s8v ah, al;
    split8(x + (size_t)arow * 128 + kt * 32 + 8 * q, ah, al);
    #pragma unroll
    for (int ct = 0; ct < 4; ++ct) {
      int bo = (ct * 16 + p16) * 128 + kt * 32 + 8 * q;
      s8v bh = *(const s8v*)(wb + OFF_WH + bo);
      s8v bl = *(const s8v*)(wb + OFF_WH + 8192 + bo);
      acc[ct] = MFMA(ah, bh, acc[ct]);
      acc[ct] = MFMA(ah, bl, acc[ct]);
      acc[ct] = MFMA(al, bh, acc[ct]);
    }
  }
  { // pe: K=16 zero-padded to 32
    s8v ah = {}, al = {};
    if (q < 2) split8(pe + (size_t)arow * 16 + 8 * q, ah, al);
    #pragma unroll
    for (int ct = 0; ct < 4; ++ct) {
      int bo = (ct * 16 + p16) * 32 + 8 * q;
      s8v bh = *(const s8v*)(wb + OFF_WPE + bo);
      s8v bl = *(const s8v*)(wb + OFF_WPE + 2048 + bo);
      acc[ct] = MFMA(ah, bh, acc[ct]);
      acc[ct] = MFMA(ah, bl, acc[ct]);
      acc[ct] = MFMA(al, bh, acc[ct]);
    }
  }
  #pragma unroll
  for (int ct = 0; ct < 4; ++ct) {
    float bb = b_pe[ct * 16 + p16];
    #pragma unroll
    for (int j = 0; j < 4; ++j)
      sH[wv * 16 + q * 4 + j][ct * 16 + p16] = (ushort)f2bs(acc[ct][j] + bb);
  }
  __syncthreads();
  int row = tid >> 2, part = tid & 3;
  if (nb0 + row < N) {
    uint4 a0 = *(uint4*)&sH[row][part * 16];
    uint4 a1 = *(uint4*)&sH[row][part * 16 + 8];
    *(uint4*)(Hb + (size_t)(nb0 + row) * 64 + part * 16) = a0;
    *(uint4*)(Hb + (size_t)(nb0 + row) * 64 + part * 16 + 8) = a1;
  }
}

// ---------------- QKV (MFMA): Q f32 out, K/V bf16 out ----------------
__global__ __launch_bounds__(256) void qkv_mfma(
    const ushort* __restrict__ Hb, const short* __restrict__ wb,
    const float* __restrict__ bq, const float* __restrict__ bk, const float* __restrict__ bv,
    float* __restrict__ Qb, ushort* __restrict__ Kb, ushort* __restrict__ Vb,
    int N, int lay)
{
  __shared__ __align__(16) ushort sKV[2][64][72];
  int tid = threadIdx.x, wv = tid >> 6, ln = tid & 63;
  int q = ln >> 4, p16 = ln & 15;
  int nb0 = blockIdx.x * 64;
  int arow = nb0 + wv * 16 + p16; if (arow >= N) arow = N - 1;
  int wbase = lay * PL;
  s8v a0 = *(const s8v*)(Hb + (size_t)arow * 64 + 8 * q);
  s8v a1 = *(const s8v*)(Hb + (size_t)arow * 64 + 32 + 8 * q);
  f4v qa[4] = {}, ka[4] = {}, va[4] = {};
  #pragma unroll
  for (int kt = 0; kt < 2; ++kt) {
    s8v a = kt ? a1 : a0;
    #pragma unroll
    for (int ct = 0; ct < 4; ++ct) {
      int bo = (ct * 16 + p16) * 64 + kt * 32 + 8 * q;
      s8v bh, bl;
      bh = *(const s8v*)(wb + wbase + OFF_WQ + bo);
      bl = *(const s8v*)(wb + wbase + OFF_WQ + 4096 + bo);
      qa[ct] = MFMA(a, bh, qa[ct]); qa[ct] = MFMA(a, bl, qa[ct]);
      bh = *(const s8v*)(wb + wbase + OFF_WK + bo);
      bl = *(const s8v*)(wb + wbase + OFF_WK + 4096 + bo);
      ka[ct] = MFMA(a, bh, ka[ct]); ka[ct] = MFMA(a, bl, ka[ct]);
      bh = *(const s8v*)(wb + wbase + OFF_WV + bo);
      bl = *(const s8v*)(wb + wbase + OFF_WV + 4096 + bo);
      va[ct] = MFMA(a, bh, va[ct]); va[ct] = MFMA(a, bl, va[ct]);
    }
  }
  #pragma unroll
  for (int ct = 0; ct < 4; ++ct) {
    int col = ct * 16 + p16;
    float bQ = bq[lay * 64 + col], bK = bk[lay * 64 + col], bV = bv[lay * 64 + col];
    #pragma unroll
    for (int j = 0; j < 4; ++j) {
      int r = nb0 + wv * 16 + q * 4 + j;
      if (r < N) Qb[(size_t)r * 64 + col] = qa[ct][j] + bQ;
      sKV[0][wv * 16 + q * 4 + j][col] = (ushort)f2bs(ka[ct][j] + bK);
      sKV[1][wv * 16 + q * 4 + j][col] = (ushort)f2bs(va[ct][j] + bV);
    }
  }
  __syncthreads();
  int row = tid >> 2, part = tid & 3;
  if (nb0 + row < N) {
    uint4 k0 = *(uint4*)&sKV[0][row][part * 16];
    uint4 k1 = *(uint4*)&sKV[0][row][part * 16 + 8];
    *(uint4*)(Kb + (size_t)(nb0 + row) * 64 + part * 16) = k0;
    *(uint4*)(Kb + (size_t)(nb0 + row) * 64 + part * 16 + 8) = k1;
    uint4 v0 = *(uint4*)&sKV[1][row][part * 16];
    uint4 v1 = *(uint4*)&sKV[1][row][part * 16 + 8];
    *(uint4*)(Vb + (size_t)(nb0 + row) * 64 + part * 16) = v0;
    *(uint4*)(Vb + (size_t)(nb0 + row) * 64 + part * 16 + 8) = v1;
  }
}

// ---------------- edge attention: 2 waves per node, U-deep gather pipeline ----------------
template<int U>
DEV void echunk(const ushort* __restrict__ K, const ushort* __restrict__ V,
                const int* __restrict__ src, const ushort* __restrict__ epsl,
                int e, int ln, int hh, float q4, float& acc, float& z)
{
  int s_[U]; float pk[U], pv[U], pp[U];
  #pragma unroll
  for (int u = 0; u < U; ++u) s_[u] = src[e + u];
  #pragma unroll
  for (int u = 0; u < U; ++u) {
    pk[u] = bs2f((short)K[(size_t)s_[u] * 64 + ln]);
    pv[u] = bs2f((short)V[(size_t)s_[u] * 64 + ln]);
  }
  #pragma unroll
  for (int u = 0; u < U; ++u) pp[u] = bs2f((short)epsl[(size_t)(e + u) * 4 + hh]);
  #pragma unroll
  for (int u = 0; u < U; ++u) {
    float t = pk[u] * q4;
    t += __shfl_xor(t, 1, 64);
    t += __shfl_xor(t, 2, 64);
    t += __shfl_xor(t, 4, 64);
    t += __shfl_xor(t, 8, 64);
    float sv = __expf(fminf(fmaxf(t + pp[u], -5.f), 5.f));
    acc += sv * pv[u];
    z += sv;
  }
}

__global__ __launch_bounds__(256, 8) void edge_kernel(
    const float* __restrict__ Qb, const ushort* __restrict__ Kb,
    const ushort* __restrict__ Vb, const int* __restrict__ src,
    const int* __restrict__ rp, const ushort* __restrict__ epsl,
    ushort* __restrict__ attnb, int N)
{
  __shared__ float s_acc[2][64], s_z[2][64];
  int tid = threadIdx.x, ln = tid & 63;
  int half = (tid >> 6) & 1, nid = tid >> 7;
  int w = blockIdx.x * 2 + nid;
  int hh = ln >> 4;
  float acc = 0.f, z = 0.f, q4 = 0.f;
  int e0 = 0, e1 = 0;
  if (w < N) { e0 = rp[w]; e1 = rp[w + 1]; q4 = 4.f * Qb[(size_t)w * 64 + ln]; }
  int mid = e0 + ((e1 - e0 + 1) >> 1);
  int a = half ? mid : e0, b = half ? e1 : mid;
  int e = a;
  for (; e + 8 <= b; e += 8) echunk<8>(Kb, Vb, src, epsl, e, ln, hh, q4, acc, z);
  if (e + 4 <= b) { echunk<4>(Kb, Vb, src, epsl, e, ln, hh, q4, acc, z); e += 4; }
  for (; e < b; ++e) echunk<1>(Kb, Vb, src, epsl, e, ln, hh, q4, acc, z);
  if (half == 0) { s_acc[nid][ln] = acc; s_z[nid][ln] = z; }
  __syncthreads();
  if (half == 1 && w < N) {
    acc += s_acc[nid][ln];
    z += s_z[nid][ln];
    attnb[(size_t)w * 64 + ln] = (ushort)f2bs(acc / (z + 1e-10f));
  }
}

// ---------------- post: u=attn+I@Wpi -> @WO -> LN1 -> FFN -> LN2 (MFMA) ----------------
__global__ __launch_bounds__(256) void post_mfma(
    ushort* __restrict__ Hb, const ushort* __restrict__ attnb,
    const float* __restrict__ I, const short* __restrict__ wb,
    const float* __restrict__ bpi, const float* __restrict__ bO,
    const float* __restrict__ g1, const float* __restrict__ b1,
    const float* __restrict__ bf1, const float* __restrict__ bf2,
    const float* __restrict__ g2, const float* __restrict__ b2,
    int N, int lay)
{
  constexpr float BN_S = 0.9999950000374997f;
  __shared__ __align__(16) ushort sH[64][72];
  __shared__ __align__(16) ushort sA[64][72];
  __shared__ float sF[64][65];
  __shared__ __align__(16) ushort sT[64][136];
  int tid = threadIdx.x, wv = tid >> 6, ln = tid & 63;
  int q = ln >> 4, p16 = ln & 15;
  int nb0 = blockIdx.x * 64;
  { // stage H + attn (coalesced)
    int row = tid >> 2, part = tid & 3;
    int gr = nb0 + row; if (gr >= N) gr = N - 1;
    uint4 h0 = *(const uint4*)(Hb + (size_t)gr * 64 + part * 16);
    uint4 h1 = *(const uint4*)(Hb + (size_t)gr * 64 + part * 16 + 8);
    *(uint4*)&sH[row][part * 16] = h0;
    *(uint4*)&sH[row][part * 16 + 8] = h1;
    uint4 t0 = *(const uint4*)(attnb + (size_t)gr * 64 + part * 16);
    uint4 t1 = *(const uint4*)(attnb + (size_t)gr * 64 + part * 16 + 8);
    *(uint4*)&sA[row][part * 16] = t0;
    *(uint4*)&sA[row][part * 16 + 8] = t1;
  }
  __syncthreads();
  int wbase = lay * PL;
  int arow = nb0 + wv * 16 + p16; if (arow >= N) arow = N - 1;
  // ---- u = I@Wpi + bpi + attn (C-layout) ----
  f4v uacc[4] = {};
  {
    s8v ah = {}, al = {};
    if (q < 2) split8(I + (size_t)arow * 16 + 8 * q, ah, al);
    #pragma unroll
    for (int ct = 0; ct < 4; ++ct) {
      int bo = (ct * 16 + p16) * 32 + 8 * q;
      s8v bh = *(const s8v*)(wb + wbase + OFF_WPI + bo);
      s8v bl = *(const s8v*)(wb + wbase + OFF_WPI + 2048 + bo);
      uacc[ct] = MFMA(ah, bh, uacc[ct]);
      uacc[ct] = MFMA(ah, bl, uacc[ct]);
      uacc[ct] = MFMA(al, bh, uacc[ct]);
    }
  }
  #pragma unroll
  for (int ct = 0; ct < 4; ++ct) {
    int col = ct * 16 + p16;
    float bb = bpi[lay * 64 + col];
    #pragma unroll
    for (int j = 0; j < 4; ++j) {
      uacc[ct][j] += bb + bs2f((short)sA[wv * 16 + q * 4 + j][col]);
      sF[wv * 16 + q * 4 + j][col] = uacc[ct][j];
    }
  }
  __syncthreads();
  // ---- v = u@WO + bO ; hw = h + v ; LN1 -> h1 ----
  f4v vacc[4] = {};
  #pragma unroll
  for (int kt = 0; kt < 2; ++kt) {
    s8v ah, al;
    split8(&sF[wv * 16 + p16][kt * 32 + 8 * q], ah, al);
    #pragma unroll
    for (int ct = 0; ct < 4; ++ct) {
      int bo = (ct * 16 + p16) * 64 + kt * 32 + 8 * q;
      s8v bh = *(const s8v*)(wb + wbase + OFF_WO + bo);
      s8v bl = *(const s8v*)(wb + wbase + OFF_WO + 4096 + bo);
      vacc[ct] = MFMA(ah, bh, vacc[ct]);
      vacc[ct] = MFMA(ah, bl, vacc[ct]);
      vacc[ct] = MFMA(al, bh, vacc[ct]);
    }
  }
  float hw[4][4];
  #pragma unroll
  for (int ct = 0; ct < 4; ++ct) {
    int col = ct * 16 + p16;
    float bb = bO[lay * 64 + col];
    #pragma unroll
    for (int j = 0; j < 4; ++j)
      hw[ct][j] = bs2f((short)sH[wv * 16 + q * 4 + j][col]) + vacc[ct][j] + bb;
  }
  float h1r[4][4];
  {
    float s0[4], mu[4], vv[4], rs[4];
    #pragma unroll
    for (int j = 0; j < 4; ++j) s0[j] = hw[0][j] + hw[1][j] + hw[2][j] + hw[3][j];
    #pragma unroll
    for (int msk = 1; msk < 16; msk <<= 1)
      #pragma unroll
      for (int j = 0; j < 4; ++j) s0[j] += __shfl_xor(s0[j], msk, 64);
    #pragma unroll
    for (int j = 0; j < 4; ++j) { mu[j] = s0[j] * (1.f / 64.f); vv[j] = 0.f; }
    #pragma unroll
    for (int ct = 0; ct < 4; ++ct)
      #pragma unroll
      for (int j = 0; j < 4; ++j) { float d = hw[ct][j] - mu[j]; hw[ct][j] = d; vv[j] += d * d; }
    #pragma unroll
    for (int msk = 1; msk < 16; msk <<= 1)
      #pragma unroll
      for (int j = 0; j < 4; ++j) vv[j] += __shfl_xor(vv[j], msk, 64);
    #pragma unroll
    for (int j = 0; j < 4; ++j) rs[j] = 1.f / sqrtf(vv[j] * (1.f / 64.f) + 1e-5f);
    #pragma unroll
    for (int ct = 0; ct < 4; ++ct) {
      int col = ct * 16 + p16;
      float gg = g1[lay * 64 + col], bb = b1[lay * 64 + col];
      #pragma unroll
      for (int j = 0; j < 4; ++j)
        h1r[ct][j] = (hw[ct][j] * rs[j] * gg + bb) * BN_S;
    }
  }
  __syncthreads();
  #pragma unroll
  for (int ct = 0; ct < 4; ++ct)
    #pragma unroll
    for (int j = 0; j < 4; ++j)
      sF[wv * 16 + q * 4 + j][ct * 16 + p16] = h1r[ct][j];
  __syncthreads();
  // ---- t = relu(h1@Wf1 + bf1) -> sT ----
  f4v tacc[8] = {};
  #pragma unroll
  for (int kt = 0; kt < 2; ++kt) {
    s8v ah, al;
    split8(&sF[wv * 16 + p16][kt * 32 + 8 * q], ah, al);
    #pragma unroll
    for (int ct = 0; ct < 8; ++ct) {
      int bo = (ct * 16 + p16) * 64 + kt * 32 + 8 * q;
      s8v bh = *(const s8v*)(wb + wbase + OFF_WF1 + bo);
      s8v bl = *(const s8v*)(wb + wbase + OFF_WF1 + 8192 + bo);
      tacc[ct] = MFMA(ah, bh, tacc[ct]);
      tacc[ct] = MFMA(ah, bl, tacc[ct]);
      tacc[ct] = MFMA(al, bh, tacc[ct]);
    }
  }
  #pragma unroll
  for (int ct = 0; ct < 8; ++ct) {
    int col = ct * 16 + p16;
    float bb = bf1[lay * 128 + col];
    #pragma unroll
    for (int j = 0; j < 4; ++j)
      sT[wv * 16 + q * 4 + j][col] = (ushort)f2bs(fmaxf(tacc[ct][j] + bb, 0.f));
  }
  __syncthreads();
  // ---- y = t@Wf2 + bf2 ; w2 = h1 + y ; LN2 -> h2 ----
  f4v yacc[4] = {};
  #pragma unroll
  for (int kt = 0; kt < 4; ++kt) {
    s8v at = *(const s8v*)&sT[wv * 16 + p16][kt * 32 + 8 * q];
    #pragma unroll
    for (int ct = 0; ct < 4; ++ct) {
      int bo = (ct * 16 + p16) * 128 + kt * 32 + 8 * q;
      s8v bh = *(const s8v*)(wb + wbase + OFF_WF2 + bo);
      s8v bl = *(const s8v*)(wb + wbase + OFF_WF2 + 8192 + bo);
      yacc[ct] = MFMA(at, bh, yacc[ct]);
      yacc[ct] = MFMA(at, bl, yacc[ct]);
    }
  }
  float w2[4][4];
  #pragma unroll
  for (int ct = 0; ct < 4; ++ct) {
    int col = ct * 16 + p16;
    float bb = bf2[lay * 64 + col];
    #pragma unroll
    for (int j = 0; j < 4; ++j)
      w2[ct][j] = h1r[ct][j] + yacc[ct][j] + bb;
  }
  {
    float s0[4], mu[4], vv[4], rs[4];
    #pragma unroll
    for (int j = 0; j < 4; ++j) s0[j] = w2[0][j] + w2[1][j] + w2[2][j] + w2[3][j];
    #pragma unroll
    for (int msk = 1; msk < 16; msk <<= 1)
      #pragma unroll
      for (int j = 0; j < 4; ++j) s0[j] += __shfl_xor(s0[j], msk, 64);
    #pragma unroll
    for (int j = 0; j < 4; ++j) { mu[j] = s0[j] * (1.f / 64.f); vv[j] = 0.f; }
    #pragma unroll
    for (int ct = 0; ct < 4; ++ct)
      #pragma unroll
      for (int j = 0; j < 4; ++j) { float d = w2[ct][j] - mu[j]; w2[ct][j] = d; vv[j] += d * d; }
    #pragma unroll
    for (int msk = 1; msk < 16; msk <<= 1)
      #pragma unroll
      for (int j = 0; j < 4; ++j) vv[j] += __shfl_xor(vv[j], msk, 64);
    #pragma unroll
    for (int j = 0; j < 4; ++j) rs[j] = 1.f / sqrtf(vv[j] * (1.f / 64.f) + 1e-5f);
    #pragma unroll
    for (int ct = 0; ct < 4; ++ct) {
      int col = ct * 16 + p16;
      float gg = g2[lay * 64 + col], bb = b2[lay * 64 + col];
      #pragma unroll
      for (int j = 0; j < 4; ++j)
        sH[wv * 16 + q * 4 + j][col] = (ushort)f2bs((w2[ct][j] * rs[j] * gg + bb) * BN_S);
    }
  }
  __syncthreads();
  {
    int row = tid >> 2, part = tid & 3;
    if (nb0 + row < N) {
      uint4 a0 = *(uint4*)&sH[row][part * 16];
      uint4 a1 = *(uint4*)&sH[row][part * 16 + 8];
      *(uint4*)(Hb + (size_t)(nb0 + row) * 64 + part * 16) = a0;
      *(uint4*)(Hb + (size_t)(nb0 + row) * 64 + part * 16 + 8) = a1;
    }
  }
}

// ---------------- readout: out0 = h ; x_hat = selu(h@Wr1+br1)@Wr2+br2 ----------------
__global__ __launch_bounds__(256) void readout_mfma(
    const ushort* __restrict__ Hb, const short* __restrict__ wb,
    const float* __restrict__ br1, const float* __restrict__ br2,
    float* __restrict__ out, int N)
{
  __shared__ __align__(16) ushort sH[64][72];
  __shared__ float sM[64][17];
  int tid = threadIdx.x, wv = tid >> 6, ln = tid & 63;
  int q = ln >> 4, p16 = ln & 15;
  int nb0 = blockIdx.x * 64;
  {
    int row = tid >> 2, part = tid & 3;
    int gr = nb0 + row; if (gr >= N) gr = N - 1;
    uint4 h0 = *(const uint4*)(Hb + (size_t)gr * 64 + part * 16);
    uint4 h1 = *(const uint4*)(Hb + (size_t)gr * 64 + part * 16 + 8);
    *(uint4*)&sH[row][part * 16] = h0;
    *(uint4*)&sH[row][part * 16 + 8] = h1;
  }
  __syncthreads();
  { // h out (fp32)
    int row = tid >> 2, part = tid & 3;
    if (nb0 + row < N) {
      #pragma unroll
      for (int c = 0; c < 16; ++c)
        out[(size_t)(nb0 + row) * 64 + part * 16 + c] = bs2f((short)sH[row][part * 16 + c]);
    }
  }
  // md = selu(h@Wr1 + br1)  (C-layout: col=p16 of 16)
  f4v macc = {};
  #pragma unroll
  for (int kt = 0; kt < 2; ++kt) {
    s8v a = *(const s8v*)&sH[wv * 16 + p16][kt * 32 + 8 * q];
    int bo = p16 * 64 + kt * 32 + 8 * q;
    s8v bh = *(const s8v*)(wb + OFF_WR1 + bo);
    s8v bl = *(const s8v*)(wb + OFF_WR1 + 1024 + bo);
    macc = MFMA(a, bh, macc);
    macc = MFMA(a, bl, macc);
  }
  const float SC = 1.0507009873554805f, AL = 1.6732632423543772f;
  #pragma unroll
  for (int j = 0; j < 4; ++j) {
    float md = macc[j] + br1[p16];
    md = (md > 0.f) ? SC * md : SC * AL * expm1f(md);
    sM[wv * 16 + q * 4 + j][p16] = md;
  }
  __syncthreads();
  // x_hat = md@Wr2 + br2 (K=16 padded to 32)
  f4v xacc[8] = {};
  {
    s8v ah = {}, al = {};
    if (q < 2) split8(&sM[wv * 16 + p16][8 * q], ah, al);
    #pragma unroll
    for (int ct = 0; ct < 8; ++ct) {
      int bo = (ct * 16 + p16) * 32 + 8 * q;
      s8v bh = *(const s8v*)(wb + OFF_WR2 + bo);
      s8v bl = *(const s8v*)(wb + OFF_WR2 + 4096 + bo);
      xacc[ct] = MFMA(ah, bh, xacc[ct]);
      xacc[ct] = MFMA(ah, bl, xacc[ct]);
      xacc[ct] = MFMA(al, bh, xacc[ct]);
    }
  }
  #pragma unroll
  for (int ct = 0; ct < 8; ++ct) {
    int col = ct * 16 + p16;
    float bb = br2[col];
    #pragma unroll
    for (int j = 0; j < 4; ++j) {
      int r = nb0 + wv * 16 + q * 4 + j;
      if (r < N) out[(size_t)N * 64 + (size_t)r * 128 + col] = xacc[ct][j] + bb;
    }
  }
}

extern "C" void kernel_launch(void* const* d_in, const int* in_sizes, int n_in,
                              void* d_out, int out_size, void* d_ws, size_t ws_size,
                              hipStream_t stream)
{
  const int* src    = (const int*)d_in[0];
  const int* dst    = (const int*)d_in[1];
  const float* x    = (const float*)d_in[2];
  const float* pe   = (const float*)d_in[3];
  const float* de   = (const float*)d_in[4];
  const float* m    = (const float*)d_in[5];
  const float* I    = (const float*)d_in[6];
  const float* W_h  = (const float*)d_in[7];
  const float* W_pe = (const float*)d_in[8];
  const float* b_pe = (const float*)d_in[9];
  const float* W_de = (const float*)d_in[10];
  const float* b_de = (const float*)d_in[11];
  const float* W_m  = (const float*)d_in[12];
  const float* b_m  = (const float*)d_in[13];
  const float* Wq   = (const float*)d_in[14];
  const float* bq   = (const float*)d_in[15];
  const float* Wk   = (const float*)d_in[16];
  const float* bk   = (const float*)d_in[17];
  const float* Wv   = (const float*)d_in[18];
  const float* bv   = (const float*)d_in[19];
  const float* Wpd  = (const float*)d_in[20];
  const float* bpd  = (const float*)d_in[21];
  const float* Wpm  = (const float*)d_in[22];
  const float* bpm  = (const float*)d_in[23];
  const float* WO   = (const float*)d_in[24];
  const float* bO   = (const float*)d_in[25];
  const float* Wpi  = (const float*)d_in[26];
  const float* bpi  = (const float*)d_in[27];
  const float* g1   = (const float*)d_in[28];
  const float* b1   = (const float*)d_in[29];
  const float* g2   = (const float*)d_in[30];
  const float* b2   = (const float*)d_in[31];
  const float* Wf1  = (const float*)d_in[32];
  const float* bf1  = (const float*)d_in[33];
  const float* Wf2  = (const float*)d_in[34];
  const float* bf2  = (const float*)d_in[35];
  const float* Wr1  = (const float*)d_in[36];
  const float* br1  = (const float*)d_in[37];
  const float* Wr2  = (const float*)d_in[38];
  const float* br2  = (const float*)d_in[39];

  const int E = in_sizes[0];
  const int N = in_sizes[2] / 128;

  // ws: rowptr | fold | split-weights | H (bf16)
  char* ws = (char*)d_ws;
  int* row_ptr = (int*)ws;
  size_t rp_bytes = (((size_t)(N + 1) * 4) + 255) & ~(size_t)255;
  float* fold = (float*)(ws + rp_bytes);
  short* wb = (short*)(ws + rp_bytes + 1024);
  ushort* Hb = (ushort*)(ws + rp_bytes + 1024 + (size_t)WBF_TOT * 2);
  size_t ws_used = rp_bytes + 1024 + (size_t)WBF_TOT * 2 + (size_t)N * 128;

  // d_out doubles as scratch until readout rewrites every byte:
  // K bf16 [0,128N) | V bf16 [128N,256N) | Q f32 [256N,512N) | attn bf16 [512N,640N) | eps [640N,640N+8E)
  float* out = (float*)d_out;
  ushort* Kb = (ushort*)out;
  ushort* Vb = Kb + (size_t)N * 64;
  float* Qb = out + (size_t)N * 64;
  ushort* attnb = (ushort*)((char*)d_out + (size_t)N * 512);
  ushort* epsb;
  if (ws_size >= ws_used + (size_t)E * 8)
    epsb = (ushort*)((char*)d_ws + ws_used);
  else
    epsb = (ushort*)((char*)d_out + (size_t)N * 640); // fits iff E <= 16N (true here)

  int nb64 = (N + 63) / 64;

  prep_kernel<<<64, 256, 0, stream>>>(Wq, Wk, Wv, WO, Wf1, Wf2, Wpi, W_h, W_pe, Wr1, Wr2, wb);
  fold_kernel<<<1, 64, 0, stream>>>(W_de, b_de, W_m, b_m, Wpd, bpd, Wpm, bpm, fold);
  rowptr_kernel<<<(N + 256) / 256, 256, 0, stream>>>(dst, E, N, row_ptr);
  hinit_mfma<<<nb64, 256, 0, stream>>>(x, pe, wb, b_pe, Hb, N);

  for (int lay = 0; lay < 2; ++lay) {
    escore_kernel<<<(E + 255) / 256, 256, 0, stream>>>(de, m, fold, epsb, E, lay);
    qkv_mfma<<<nb64, 256, 0, stream>>>(Hb, wb, bq, bk, bv, Qb, Kb, Vb, N, lay);
    edge_kernel<<<(N + 1) / 2, 256, 0, stream>>>(Qb, Kb, Vb, src, row_ptr, epsb, attnb, N);
    post_mfma<<<nb64, 256, 0, stream>>>(Hb, attnb, I, wb, bpi, bO, g1, b1,
                                        bf1, bf2, g2, b2, N, lay);
  }
  readout_mfma<<<nb64, 256, 0, stream>>>(Hb, wb, br1, br2, out, N);
}

// Round 3
// 610.266 us; speedup vs baseline: 1.6727x; 1.0548x over previous
//
#include <hip/hip_runtime.h>
#include <hip/hip_bf16.h>

typedef __hip_bfloat16 bf16;
typedef __attribute__((ext_vector_type(8))) short s8v;
typedef __attribute__((ext_vector_type(4))) float f4v;
#define DEV __device__ __forceinline__
#define MFMA(a, b, c) __builtin_amdgcn_mfma_f32_16x16x32_bf16(a, b, c, 0, 0, 0)

// split-bf16 weight table offsets (elements); each section: [hi sz][lo sz]
constexpr int OFF_WQ = 0, OFF_WK = 8192, OFF_WV = 16384, OFF_WO = 24576;
constexpr int OFF_WF1 = 32768, OFF_WF2 = 49152, OFF_WPI = 65536;
constexpr int PL = 69632; // per-layer stride
constexpr int OFF_WH = 139264, OFF_WPE = 155648, OFF_WR1 = 159744, OFF_WR2 = 161792;
constexpr int WBF_TOT = 169984;

constexpr float LOG2E = 1.4426950408889634f;
constexpr float QSC = 4.f * LOG2E;         // folds 16*SCALE and log2(e) into Q
constexpr float CLB = 5.f * LOG2E;         // clamp bound in log2 domain

DEV short f2bs(float f) { union { bf16 b; short s; } u; u.b = __float2bfloat16(f); return u.s; }
DEV float bs2f(short s) { union { bf16 b; short s2; } u; u.s2 = s; return __bfloat162float(u.b); }

DEV void split8(const float* p, s8v& hi, s8v& lo) {
  #pragma unroll
  for (int j = 0; j < 8; ++j) {
    float f = p[j];
    short h = f2bs(f);
    hi[j] = h;
    lo[j] = f2bs(f - bs2f(h));
  }
}

// ---------------- weight prep: transpose + split to bf16 hi/lo ----------------
// 2D grid: x covers elements (max tot 8192 -> 32 blocks), y = section 0..17.
__global__ __launch_bounds__(256) void prep_kernel(
    const float* __restrict__ Wq, const float* __restrict__ Wk,
    const float* __restrict__ Wv, const float* __restrict__ WO,
    const float* __restrict__ Wf1, const float* __restrict__ Wf2,
    const float* __restrict__ Wpi, const float* __restrict__ W_h,
    const float* __restrict__ W_pe, const float* __restrict__ Wr1,
    const float* __restrict__ Wr2, short* __restrict__ wb)
{
  const float* sp; int K, ksh, Nc, d0;
  switch (blockIdx.y) {
    case 0:  sp = Wq;         K = 64;  ksh = 6; Nc = 64;  d0 = OFF_WQ;       break;
    case 1:  sp = Wk;         K = 64;  ksh = 6; Nc = 64;  d0 = OFF_WK;       break;
    case 2:  sp = Wv;         K = 64;  ksh = 6; Nc = 64;  d0 = OFF_WV;       break;
    case 3:  sp = WO;         K = 64;  ksh = 6; Nc = 64;  d0 = OFF_WO;       break;
    case 4:  sp = Wf1;        K = 64;  ksh = 6; Nc = 128; d0 = OFF_WF1;      break;
    case 5:  sp = Wf2;        K = 128; ksh = 7; Nc = 64;  d0 = OFF_WF2;      break;
    case 6:  sp = Wpi;        K = 16;  ksh = 5; Nc = 64;  d0 = OFF_WPI;      break;
    case 7:  sp = Wq + 4096;  K = 64;  ksh = 6; Nc = 64;  d0 = PL + OFF_WQ;  break;
    case 8:  sp = Wk + 4096;  K = 64;  ksh = 6; Nc = 64;  d0 = PL + OFF_WK;  break;
    case 9:  sp = Wv + 4096;  K = 64;  ksh = 6; Nc = 64;  d0 = PL + OFF_WV;  break;
    case 10: sp = WO + 4096;  K = 64;  ksh = 6; Nc = 64;  d0 = PL + OFF_WO;  break;
    case 11: sp = Wf1 + 8192; K = 64;  ksh = 6; Nc = 128; d0 = PL + OFF_WF1; break;
    case 12: sp = Wf2 + 8192; K = 128; ksh = 7; Nc = 64;  d0 = PL + OFF_WF2; break;
    case 13: sp = Wpi + 1024; K = 16;  ksh = 5; Nc = 64;  d0 = PL + OFF_WPI; break;
    case 14: sp = W_h;        K = 128; ksh = 7; Nc = 64;  d0 = OFF_WH;       break;
    case 15: sp = W_pe;       K = 16;  ksh = 5; Nc = 64;  d0 = OFF_WPE;      break;
    case 16: sp = Wr1;        K = 64;  ksh = 6; Nc = 16;  d0 = OFF_WR1;      break;
    default: sp = Wr2;        K = 16;  ksh = 5; Nc = 128; d0 = OFF_WR2;      break;
  }
  int Kp = 1 << ksh;
  int tot = Kp * Nc;
  int i = blockIdx.x * 256 + threadIdx.x;
  if (i >= tot) return;
  int o = i >> ksh, kk = i & (Kp - 1);
  float v = (kk < K) ? sp[kk * Nc + o] : 0.f; // dst[o][kk] = src[kk][o], zero-pad K
  short h = f2bs(v);
  wb[d0 + i] = h;
  wb[d0 + tot + i] = f2bs(v - bs2f(h));
}

// ---------------- fold de/m through per-head column sums ----------------
__global__ __launch_bounds__(256) void fold_kernel(
    const float* __restrict__ W_de, const float* __restrict__ b_de,
    const float* __restrict__ W_m,  const float* __restrict__ b_m,
    const float* __restrict__ Wpd,  const float* __restrict__ bpd,
    const float* __restrict__ Wpm,  const float* __restrict__ bpm,
    float* __restrict__ fold)
{
  __shared__ float spd[64][4], spm[64][4];
  int tid = threadIdx.x;
  for (int l = 0; l < 2; ++l) {
    { // phase 1: 256 threads = (t, hh)
      int t = tid >> 2, hh = tid & 3;
      const float* wpd = Wpd + l * 4096 + t * 64 + hh * 16;
      const float* wpm = Wpm + l * 4096 + t * 64 + hh * 16;
      float sd = 0.f, sm = 0.f;
      #pragma unroll
      for (int hd = 0; hd < 16; ++hd) { sd += wpd[hd]; sm += wpm[hd]; }
      spd[t][hh] = sd; spm[t][hh] = sm;
    }
    __syncthreads();
    if (tid < 64) { int i = tid >> 2, hh = tid & 3;
      float a = 0.f;
      for (int k = 0; k < 64; ++k) a += W_de[i * 64 + k] * spd[k][hh];
      fold[l * 128 + i * 4 + hh] = a; }
    if (tid < 32) { int i = tid >> 2, hh = tid & 3;
      float a = 0.f;
      for (int k = 0; k < 64; ++k) a += W_m[i * 64 + k] * spm[k][hh];
      fold[l * 128 + 64 + i * 4 + hh] = a; }
    if (tid < 4) { int hh = tid;
      float a = 0.f;
      for (int k = 0; k < 64; ++k) a += b_de[k] * spd[k][hh] + b_m[k] * spm[k][hh];
      for (int hd = 0; hd < 16; ++hd)
        a += bpd[l * 64 + hh * 16 + hd] + bpm[l * 64 + hh * 16 + hd];
      fold[l * 128 + 96 + hh] = a; }
    __syncthreads();
  }
}

// ---------------- per-edge folded score, pre-scaled by log2(e), bf16 out ------
// If ep1 != null: writes layer0 -> ep0 and layer1 -> ep1 (de/m read once).
// Else: writes layer `lay` -> ep0.
__global__ __launch_bounds__(256) void escore_kernel(
    const float* __restrict__ de, const float* __restrict__ m,
    const float* __restrict__ fold, ushort* __restrict__ ep0,
    ushort* __restrict__ ep1, int E, int lay)
{
  int e = blockIdx.x * 256 + threadIdx.x;
  if (e >= E) return;
  float dv[16], mv[8];
  #pragma unroll
  for (int i = 0; i < 4; ++i)
    *(float4*)(dv + 4 * i) = ((const float4*)(de + (size_t)e * 16))[i];
  #pragma unroll
  for (int i = 0; i < 2; ++i)
    *(float4*)(mv + 4 * i) = ((const float4*)(m + (size_t)e * 8))[i];
  #pragma unroll
  for (int pass = 0; pass < 2; ++pass) {
    ushort* ep; int l;
    if (pass == 0) { ep = ep0; l = ep1 ? 0 : lay; }
    else { if (!ep1) break; ep = ep1; l = 1; }
    const float* f = fold + l * 128;
    ushort4 o;
    ushort* op = (ushort*)&o;
    #pragma unroll
    for (int hh = 0; hh < 4; ++hh) {
      float a = f[96 + hh];
      #pragma unroll
      for (int i = 0; i < 16; ++i) a += dv[i] * f[i * 4 + hh];
      #pragma unroll
      for (int i = 0; i < 8; ++i) a += mv[i] * f[64 + i * 4 + hh];
      op[hh] = (ushort)f2bs(a * LOG2E);
    }
    *(ushort4*)(ep + (size_t)e * 4) = o;
  }
}

// ---------------- CSR rowptr ----------------
__global__ __launch_bounds__(256) void rowptr_kernel(
    const int* __restrict__ dst, int E, int N, int* __restrict__ rp)
{
  int n = blockIdx.x * blockDim.x + threadIdx.x;
  if (n > N) return;
  int lo = 0, hi = E;
  while (lo < hi) {
    int mid = (lo + hi) >> 1;
    if (dst[mid] < n) lo = mid + 1; else hi = mid;
  }
  rp[n] = lo;
}

// ---------------- hinit: H = x@W_h + pe@W_pe + b_pe (MFMA, split A+B) --------
__global__ __launch_bounds__(256) void hinit_mfma(
    const float* __restrict__ x, const float* __restrict__ pe,
    const short* __restrict__ wb, const float* __restrict__ b_pe,
    ushort* __restrict__ Hb, int N)
{
  __shared__ __align__(16) ushort sH[64][72];
  int tid = threadIdx.x, wv = tid >> 6, ln = tid & 63;
  int q = ln >> 4, p16 = ln & 15;
  int nb0 = blockIdx.x * 64;
  int arow = nb0 + wv * 16 + p16; if (arow >= N) arow = N - 1;
  f4v acc[4] = {};
  for (int kt = 0; kt < 4; ++kt) {
    s8v ah, al;
    split8(x + (size_t)arow * 128 + kt * 32 + 8 * q, ah, al);
    #pragma unroll
    for (int ct = 0; ct < 4; ++ct) {
      int bo = (ct * 16 + p16) * 128 + kt * 32 + 8 * q;
      s8v bh = *(const s8v*)(wb + OFF_WH + bo);
      s8v bl = *(const s8v*)(wb + OFF_WH + 8192 + bo);
      acc[ct] = MFMA(ah, bh, acc[ct]);
      acc[ct] = MFMA(ah, bl, acc[ct]);
      acc[ct] = MFMA(al, bh, acc[ct]);
    }
  }
  { // pe: K=16 zero-padded to 32
    s8v ah = {}, al = {};
    if (q < 2) split8(pe + (size_t)arow * 16 + 8 * q, ah, al);
    #pragma unroll
    for (int ct = 0; ct < 4; ++ct) {
      int bo = (ct * 16 + p16) * 32 + 8 * q;
      s8v bh = *(const s8v*)(wb + OFF_WPE + bo);
      s8v bl = *(const s8v*)(wb + OFF_WPE + 2048 + bo);
      acc[ct] = MFMA(ah, bh, acc[ct]);
      acc[ct] = MFMA(ah, bl, acc[ct]);
      acc[ct] = MFMA(al, bh, acc[ct]);
    }
  }
  #pragma unroll
  for (int ct = 0; ct < 4; ++ct) {
    float bb = b_pe[ct * 16 + p16];
    #pragma unroll
    for (int j = 0; j < 4; ++j)
      sH[wv * 16 + q * 4 + j][ct * 16 + p16] = (ushort)f2bs(acc[ct][j] + bb);
  }
  __syncthreads();
  int row = tid >> 2, part = tid & 3;
  if (nb0 + row < N) {
    uint4 a0 = *(uint4*)&sH[row][part * 16];
    uint4 a1 = *(uint4*)&sH[row][part * 16 + 8];
    *(uint4*)(Hb + (size_t)(nb0 + row) * 64 + part * 16) = a0;
    *(uint4*)(Hb + (size_t)(nb0 + row) * 64 + part * 16 + 8) = a1;
  }
}

// ---------------- QKV (MFMA): Q f32 (scaled by 4*log2e), K/V packed bf16 -----
__global__ __launch_bounds__(256) void qkv_mfma(
    const ushort* __restrict__ Hb, const short* __restrict__ wb,
    const float* __restrict__ bq, const float* __restrict__ bk, const float* __restrict__ bv,
    float* __restrict__ Qb, uint* __restrict__ KVb, int N, int lay)
{
  __shared__ __align__(16) uint sKV[64][72];
  int tid = threadIdx.x, wv = tid >> 6, ln = tid & 63;
  int q = ln >> 4, p16 = ln & 15;
  int nb0 = blockIdx.x * 64;
  int arow = nb0 + wv * 16 + p16; if (arow >= N) arow = N - 1;
  int wbase = lay * PL;
  s8v a0 = *(const s8v*)(Hb + (size_t)arow * 64 + 8 * q);
  s8v a1 = *(const s8v*)(Hb + (size_t)arow * 64 + 32 + 8 * q);
  f4v qa[4] = {}, ka[4] = {}, va[4] = {};
  #pragma unroll
  for (int kt = 0; kt < 2; ++kt) {
    s8v a = kt ? a1 : a0;
    #pragma unroll
    for (int ct = 0; ct < 4; ++ct) {
      int bo = (ct * 16 + p16) * 64 + kt * 32 + 8 * q;
      s8v bh, bl;
      bh = *(const s8v*)(wb + wbase + OFF_WQ + bo);
      bl = *(const s8v*)(wb + wbase + OFF_WQ + 4096 + bo);
      qa[ct] = MFMA(a, bh, qa[ct]); qa[ct] = MFMA(a, bl, qa[ct]);
      bh = *(const s8v*)(wb + wbase + OFF_WK + bo);
      bl = *(const s8v*)(wb + wbase + OFF_WK + 4096 + bo);
      ka[ct] = MFMA(a, bh, ka[ct]); ka[ct] = MFMA(a, bl, ka[ct]);
      bh = *(const s8v*)(wb + wbase + OFF_WV + bo);
      bl = *(const s8v*)(wb + wbase + OFF_WV + 4096 + bo);
      va[ct] = MFMA(a, bh, va[ct]); va[ct] = MFMA(a, bl, va[ct]);
    }
  }
  #pragma unroll
  for (int ct = 0; ct < 4; ++ct) {
    int col = ct * 16 + p16;
    float bQ = bq[lay * 64 + col], bK = bk[lay * 64 + col], bV = bv[lay * 64 + col];
    #pragma unroll
    for (int j = 0; j < 4; ++j) {
      int r = nb0 + wv * 16 + q * 4 + j;
      if (r < N) Qb[(size_t)r * 64 + col] = (qa[ct][j] + bQ) * QSC;
      uint kw = (uint)(ushort)f2bs(ka[ct][j] + bK);
      uint vw = (uint)(ushort)f2bs(va[ct][j] + bV);
      sKV[wv * 16 + q * 4 + j][col] = kw | (vw << 16);
    }
  }
  __syncthreads();
  int row = tid >> 2, part = tid & 3;
  if (nb0 + row < N) {
    #pragma unroll
    for (int c = 0; c < 4; ++c) {
      uint4 t = *(uint4*)&sKV[row][part * 16 + c * 4];
      *(uint4*)(KVb + (size_t)(nb0 + row) * 64 + part * 16 + c * 4) = t;
    }
  }
}

// ---------------- edge attention: 1 wave/node, scalarized CSR, 16-deep -------
__global__ __launch_bounds__(256, 8) void edge_kernel(
    const float* __restrict__ Qb, const uint* __restrict__ KVb,
    const int* __restrict__ src, const int* __restrict__ rp,
    const ushort* __restrict__ epsl, ushort* __restrict__ attnb, int N)
{
  int tid = threadIdx.x, ln = tid & 63;
  int wv = __builtin_amdgcn_readfirstlane(tid >> 6); // wave-uniform -> SGPR
  int w = blockIdx.x * 4 + wv;
  if (w >= N) return;
  int hh = ln >> 4;
  int e0 = rp[w], e1 = rp[w + 1]; // uniform -> s_load
  float qs = Qb[(size_t)w * 64 + ln];
  float acc = 0.f, z = 0.f;
  int elast = e1 - 1;
  for (int e = e0; e < e1; e += 16) {
    uint kv[16]; ushort pp[16];
    #pragma unroll
    for (int u = 0; u < 16; ++u) {
      int ei = e + u; if (ei > elast) ei = elast; // uniform clamp
      int sidx = src[ei];                         // uniform -> s_load
      kv[u] = KVb[(size_t)sidx * 64 + ln];        // SGPR base + lane offset
      pp[u] = epsl[(size_t)ei * 4 + hh];
    }
    #pragma unroll
    for (int u = 0; u < 16; ++u) {
      if (e + u > elast) break; // uniform branch, zero VALU cost
      float kf = __uint_as_float(kv[u] << 16);
      float vf = __uint_as_float(kv[u] & 0xffff0000u);
      float ppf = __uint_as_float(((uint)pp[u]) << 16);
      float t = kf * qs;
      t += __shfl_xor(t, 1, 64);
      t += __shfl_xor(t, 2, 64);
      t += __shfl_xor(t, 4, 64);
      t += __shfl_xor(t, 8, 64);
      float sv = __builtin_amdgcn_exp2f(fminf(fmaxf(t + ppf, -CLB), CLB));
      acc = fmaf(sv, vf, acc);
      z += sv;
    }
  }
  attnb[(size_t)w * 64 + ln] = (ushort)f2bs(acc / (z + 1e-10f));
}

// ---------------- post: u=attn+I@Wpi -> @WO -> LN1 -> FFN -> LN2 (MFMA) ------
__global__ __launch_bounds__(256) void post_mfma(
    ushort* __restrict__ Hb, const ushort* __restrict__ attnb,
    const float* __restrict__ I, const short* __restrict__ wb,
    const float* __restrict__ bpi, const float* __restrict__ bO,
    const float* __restrict__ g1, const float* __restrict__ b1,
    const float* __restrict__ bf1, const float* __restrict__ bf2,
    const float* __restrict__ g2, const float* __restrict__ b2,
    int N, int lay)
{
  constexpr float BN_S = 0.9999950000374997f;
  __shared__ __align__(16) ushort sH[64][72];
  __shared__ __align__(16) ushort sA[64][72];
  __shared__ float sF[64][65];
  __shared__ __align__(16) ushort sT[64][136];
  int tid = threadIdx.x, wv = tid >> 6, ln = tid & 63;
  int q = ln >> 4, p16 = ln & 15;
  int nb0 = blockIdx.x * 64;
  { // stage H + attn (coalesced)
    int row = tid >> 2, part = tid & 3;
    int gr = nb0 + row; if (gr >= N) gr = N - 1;
    uint4 h0 = *(const uint4*)(Hb + (size_t)gr * 64 + part * 16);
    uint4 h1 = *(const uint4*)(Hb + (size_t)gr * 64 + part * 16 + 8);
    *(uint4*)&sH[row][part * 16] = h0;
    *(uint4*)&sH[row][part * 16 + 8] = h1;
    uint4 t0 = *(const uint4*)(attnb + (size_t)gr * 64 + part * 16);
    uint4 t1 = *(const uint4*)(attnb + (size_t)gr * 64 + part * 16 + 8);
    *(uint4*)&sA[row][part * 16] = t0;
    *(uint4*)&sA[row][part * 16 + 8] = t1;
  }
  __syncthreads();
  int wbase = lay * PL;
  int arow = nb0 + wv * 16 + p16; if (arow >= N) arow = N - 1;
  // ---- u = I@Wpi + bpi + attn ----
  f4v uacc[4] = {};
  {
    s8v ah = {}, al = {};
    if (q < 2) split8(I + (size_t)arow * 16 + 8 * q, ah, al);
    #pragma unroll
    for (int ct = 0; ct < 4; ++ct) {
      int bo = (ct * 16 + p16) * 32 + 8 * q;
      s8v bh = *(const s8v*)(wb + wbase + OFF_WPI + bo);
      s8v bl = *(const s8v*)(wb + wbase + OFF_WPI + 2048 + bo);
      uacc[ct] = MFMA(ah, bh, uacc[ct]);
      uacc[ct] = MFMA(ah, bl, uacc[ct]);
      uacc[ct] = MFMA(al, bh, uacc[ct]);
    }
  }
  #pragma unroll
  for (int ct = 0; ct < 4; ++ct) {
    int col = ct * 16 + p16;
    float bb = bpi[lay * 64 + col];
    #pragma unroll
    for (int j = 0; j < 4; ++j) {
      uacc[ct][j] += bb + bs2f((short)sA[wv * 16 + q * 4 + j][col]);
      sF[wv * 16 + q * 4 + j][col] = uacc[ct][j];
    }
  }
  __syncthreads();
  // ---- v = u@WO + bO ; hw = h + v ; LN1 -> h1 ----
  f4v vacc[4] = {};
  #pragma unroll
  for (int kt = 0; kt < 2; ++kt) {
    s8v ah, al;
    split8(&sF[wv * 16 + p16][kt * 32 + 8 * q], ah, al);
    #pragma unroll
    for (int ct = 0; ct < 4; ++ct) {
      int bo = (ct * 16 + p16) * 64 + kt * 32 + 8 * q;
      s8v bh = *(const s8v*)(wb + wbase + OFF_WO + bo);
      s8v bl = *(const s8v*)(wb + wbase + OFF_WO + 4096 + bo);
      vacc[ct] = MFMA(ah, bh, vacc[ct]);
      vacc[ct] = MFMA(ah, bl, vacc[ct]);
      vacc[ct] = MFMA(al, bh, vacc[ct]);
    }
  }
  float hw[4][4];
  #pragma unroll
  for (int ct = 0; ct < 4; ++ct) {
    int col = ct * 16 + p16;
    float bb = bO[lay * 64 + col];
    #pragma unroll
    for (int j = 0; j < 4; ++j)
      hw[ct][j] = bs2f((short)sH[wv * 16 + q * 4 + j][col]) + vacc[ct][j] + bb;
  }
  float h1r[4][4];
  {
    float s0[4], mu[4], vv[4], rs[4];
    #pragma unroll
    for (int j = 0; j < 4; ++j) s0[j] = hw[0][j] + hw[1][j] + hw[2][j] + hw[3][j];
    #pragma unroll
    for (int msk = 1; msk < 16; msk <<= 1)
      #pragma unroll
      for (int j = 0; j < 4; ++j) s0[j] += __shfl_xor(s0[j], msk, 64);
    #pragma unroll
    for (int j = 0; j < 4; ++j) { mu[j] = s0[j] * (1.f / 64.f); vv[j] = 0.f; }
    #pragma unroll
    for (int ct = 0; ct < 4; ++ct)
      #pragma unroll
      for (int j = 0; j < 4; ++j) { float d = hw[ct][j] - mu[j]; hw[ct][j] = d; vv[j] += d * d; }
    #pragma unroll
    for (int msk = 1; msk < 16; msk <<= 1)
      #pragma unroll
      for (int j = 0; j < 4; ++j) vv[j] += __shfl_xor(vv[j], msk, 64);
    #pragma unroll
    for (int j = 0; j < 4; ++j) rs[j] = 1.f / sqrtf(vv[j] * (1.f / 64.f) + 1e-5f);
    #pragma unroll
    for (int ct = 0; ct < 4; ++ct) {
      int col = ct * 16 + p16;
      float gg = g1[lay * 64 + col], bb = b1[lay * 64 + col];
      #pragma unroll
      for (int j = 0; j < 4; ++j)
        h1r[ct][j] = (hw[ct][j] * rs[j] * gg + bb) * BN_S;
    }
  }
  __syncthreads();
  #pragma unroll
  for (int ct = 0; ct < 4; ++ct)
    #pragma unroll
    for (int j = 0; j < 4; ++j)
      sF[wv * 16 + q * 4 + j][ct * 16 + p16] = h1r[ct][j];
  __syncthreads();
  // ---- t = relu(h1@Wf1 + bf1) -> sT ----
  f4v tacc[8] = {};
  #pragma unroll
  for (int kt = 0; kt < 2; ++kt) {
    s8v ah, al;
    split8(&sF[wv * 16 + p16][kt * 32 + 8 * q], ah, al);
    #pragma unroll
    for (int ct = 0; ct < 8; ++ct) {
      int bo = (ct * 16 + p16) * 64 + kt * 32 + 8 * q;
      s8v bh = *(const s8v*)(wb + wbase + OFF_WF1 + bo);
      s8v bl = *(const s8v*)(wb + wbase + OFF_WF1 + 8192 + bo);
      tacc[ct] = MFMA(ah, bh, tacc[ct]);
      tacc[ct] = MFMA(ah, bl, tacc[ct]);
      tacc[ct] = MFMA(al, bh, tacc[ct]);
    }
  }
  #pragma unroll
  for (int ct = 0; ct < 8; ++ct) {
    int col = ct * 16 + p16;
    float bb = bf1[lay * 128 + col];
    #pragma unroll
    for (int j = 0; j < 4; ++j)
      sT[wv * 16 + q * 4 + j][col] = (ushort)f2bs(fmaxf(tacc[ct][j] + bb, 0.f));
  }
  __syncthreads();
  // ---- y = t@Wf2 + bf2 ; w2 = h1 + y ; LN2 -> h2 ----
  f4v yacc[4] = {};
  #pragma unroll
  for (int kt = 0; kt < 4; ++kt) {
    s8v at = *(const s8v*)&sT[wv * 16 + p16][kt * 32 + 8 * q];
    #pragma unroll
    for (int ct = 0; ct < 4; ++ct) {
      int bo = (ct * 16 + p16) * 128 + kt * 32 + 8 * q;
      s8v bh = *(const s8v*)(wb + wbase + OFF_WF2 + bo);
      s8v bl = *(const s8v*)(wb + wbase + OFF_WF2 + 8192 + bo);
      yacc[ct] = MFMA(at, bh, yacc[ct]);
      yacc[ct] = MFMA(at, bl, yacc[ct]);
    }
  }
  float w2[4][4];
  #pragma unroll
  for (int ct = 0; ct < 4; ++ct) {
    int col = ct * 16 + p16;
    float bb = bf2[lay * 64 + col];
    #pragma unroll
    for (int j = 0; j < 4; ++j)
      w2[ct][j] = h1r[ct][j] + yacc[ct][j] + bb;
  }
  {
    float s0[4], mu[4], vv[4], rs[4];
    #pragma unroll
    for (int j = 0; j < 4; ++j) s0[j] = w2[0][j] + w2[1][j] + w2[2][j] + w2[3][j];
    #pragma unroll
    for (int msk = 1; msk < 16; msk <<= 1)
      #pragma unroll
      for (int j = 0; j < 4; ++j) s0[j] += __shfl_xor(s0[j], msk, 64);
    #pragma unroll
    for (int j = 0; j < 4; ++j) { mu[j] = s0[j] * (1.f / 64.f); vv[j] = 0.f; }
    #pragma unroll
    for (int ct = 0; ct < 4; ++ct)
      #pragma unroll
      for (int j = 0; j < 4; ++j) { float d = w2[ct][j] - mu[j]; w2[ct][j] = d; vv[j] += d * d; }
    #pragma unroll
    for (int msk = 1; msk < 16; msk <<= 1)
      #pragma unroll
      for (int j = 0; j < 4; ++j) vv[j] += __shfl_xor(vv[j], msk, 64);
    #pragma unroll
    for (int j = 0; j < 4; ++j) rs[j] = 1.f / sqrtf(vv[j] * (1.f / 64.f) + 1e-5f);
    #pragma unroll
    for (int ct = 0; ct < 4; ++ct) {
      int col = ct * 16 + p16;
      float gg = g2[lay * 64 + col], bb = b2[lay * 64 + col];
      #pragma unroll
      for (int j = 0; j < 4; ++j)
        sH[wv * 16 + q * 4 + j][col] = (ushort)f2bs((w2[ct][j] * rs[j] * gg + bb) * BN_S);
    }
  }
  __syncthreads();
  {
    int row = tid >> 2, part = tid & 3;
    if (nb0 + row < N) {
      uint4 a0 = *(uint4*)&sH[row][part * 16];
      uint4 a1 = *(uint4*)&sH[row][part * 16 + 8];
      *(uint4*)(Hb + (size_t)(nb0 + row) * 64 + part * 16) = a0;
      *(uint4*)(Hb + (size_t)(nb0 + row) * 64 + part * 16 + 8) = a1;
    }
  }
}

// ---------------- readout: out0 = h ; x_hat = selu(h@Wr1+br1)@Wr2+br2 --------
__global__ __launch_bounds__(256) void readout_mfma(
    const ushort* __restrict__ Hb, const short* __restrict__ wb,
    const float* __restrict__ br1, const float* __restrict__ br2,
    float* __restrict__ out, int N)
{
  __shared__ __align__(16) ushort sH[64][72];
  __shared__ float sM[64][17];
  int tid = threadIdx.x, wv = tid >> 6, ln = tid & 63;
  int q = ln >> 4, p16 = ln & 15;
  int nb0 = blockIdx.x * 64;
  {
    int row = tid >> 2, part = tid & 3;
    int gr = nb0 + row; if (gr >= N) gr = N - 1;
    uint4 h0 = *(const uint4*)(Hb + (size_t)gr * 64 + part * 16);
    uint4 h1 = *(const uint4*)(Hb + (size_t)gr * 64 + part * 16 + 8);
    *(uint4*)&sH[row][part * 16] = h0;
    *(uint4*)&sH[row][part * 16 + 8] = h1;
  }
  __syncthreads();
  { // h out (fp32)
    int row = tid >> 2, part = tid & 3;
    if (nb0 + row < N) {
      #pragma unroll
      for (int c = 0; c < 16; ++c)
        out[(size_t)(nb0 + row) * 64 + part * 16 + c] = bs2f((short)sH[row][part * 16 + c]);
    }
  }
  // md = selu(h@Wr1 + br1)
  f4v macc = {};
  #pragma unroll
  for (int kt = 0; kt < 2; ++kt) {
    s8v a = *(const s8v*)&sH[wv * 16 + p16][kt * 32 + 8 * q];
    int bo = p16 * 64 + kt * 32 + 8 * q;
    s8v bh = *(const s8v*)(wb + OFF_WR1 + bo);
    s8v bl = *(const s8v*)(wb + OFF_WR1 + 1024 + bo);
    macc = MFMA(a, bh, macc);
    macc = MFMA(a, bl, macc);
  }
  const float SC = 1.0507009873554805f, AL = 1.6732632423543772f;
  #pragma unroll
  for (int j = 0; j < 4; ++j) {
    float md = macc[j] + br1[p16];
    md = (md > 0.f) ? SC * md : SC * AL * expm1f(md);
    sM[wv * 16 + q * 4 + j][p16] = md;
  }
  __syncthreads();
  // x_hat = md@Wr2 + br2 (K=16 padded to 32)
  f4v xacc[8] = {};
  {
    s8v ah = {}, al = {};
    if (q < 2) split8(&sM[wv * 16 + p16][8 * q], ah, al);
    #pragma unroll
    for (int ct = 0; ct < 8; ++ct) {
      int bo = (ct * 16 + p16) * 32 + 8 * q;
      s8v bh = *(const s8v*)(wb + OFF_WR2 + bo);
      s8v bl = *(const s8v*)(wb + OFF_WR2 + 4096 + bo);
      xacc[ct] = MFMA(ah, bh, xacc[ct]);
      xacc[ct] = MFMA(ah, bl, xacc[ct]);
      xacc[ct] = MFMA(al, bh, xacc[ct]);
    }
  }
  #pragma unroll
  for (int ct = 0; ct < 8; ++ct) {
    int col = ct * 16 + p16;
    float bb = br2[col];
    #pragma unroll
    for (int j = 0; j < 4; ++j) {
      int r = nb0 + wv * 16 + q * 4 + j;
      if (r < N) out[(size_t)N * 64 + (size_t)r * 128 + col] = xacc[ct][j] + bb;
    }
  }
}

extern "C" void kernel_launch(void* const* d_in, const int* in_sizes, int n_in,
                              void* d_out, int out_size, void* d_ws, size_t ws_size,
                              hipStream_t stream)
{
  const int* src    = (const int*)d_in[0];
  const int* dst    = (const int*)d_in[1];
  const float* x    = (const float*)d_in[2];
  const float* pe   = (const float*)d_in[3];
  const float* de   = (const float*)d_in[4];
  const float* m    = (const float*)d_in[5];
  const float* I    = (const float*)d_in[6];
  const float* W_h  = (const float*)d_in[7];
  const float* W_pe = (const float*)d_in[8];
  const float* b_pe = (const float*)d_in[9];
  const float* W_de = (const float*)d_in[10];
  const float* b_de = (const float*)d_in[11];
  const float* W_m  = (const float*)d_in[12];
  const float* b_m  = (const float*)d_in[13];
  const float* Wq   = (const float*)d_in[14];
  const float* bq   = (const float*)d_in[15];
  const float* Wk   = (const float*)d_in[16];
  const float* bk   = (const float*)d_in[17];
  const float* Wv   = (const float*)d_in[18];
  const float* bv   = (const float*)d_in[19];
  const float* Wpd  = (const float*)d_in[20];
  const float* bpd  = (const float*)d_in[21];
  const float* Wpm  = (const float*)d_in[22];
  const float* bpm  = (const float*)d_in[23];
  const float* WO   = (const float*)d_in[24];
  const float* bO   = (const float*)d_in[25];
  const float* Wpi  = (const float*)d_in[26];
  const float* bpi  = (const float*)d_in[27];
  const float* g1   = (const float*)d_in[28];
  const float* b1   = (const float*)d_in[29];
  const float* g2   = (const float*)d_in[30];
  const float* b2   = (const float*)d_in[31];
  const float* Wf1  = (const float*)d_in[32];
  const float* bf1  = (const float*)d_in[33];
  const float* Wf2  = (const float*)d_in[34];
  const float* bf2  = (const float*)d_in[35];
  const float* Wr1  = (const float*)d_in[36];
  const float* br1  = (const float*)d_in[37];
  const float* Wr2  = (const float*)d_in[38];
  const float* br2  = (const float*)d_in[39];

  const int E = in_sizes[0];
  const int N = in_sizes[2] / 128;

  // ws: rowptr | fold | split-weights | H (bf16) | [eps both layers]
  char* ws = (char*)d_ws;
  int* row_ptr = (int*)ws;
  size_t rp_bytes = (((size_t)(N + 1) * 4) + 255) & ~(size_t)255;
  float* fold = (float*)(ws + rp_bytes);
  short* wb = (short*)(ws + rp_bytes + 1024);
  ushort* Hb = (ushort*)(ws + rp_bytes + 1024 + (size_t)WBF_TOT * 2);
  size_t ws_used = rp_bytes + 1024 + (size_t)WBF_TOT * 2 + (size_t)N * 128;

  // d_out doubles as scratch until readout rewrites every byte:
  // KV packed [0,256N) | Q f32 [256N,512N) | attn bf16 [512N,640N) | eps [640N,640N+8E)
  float* out = (float*)d_out;
  uint* KVb = (uint*)out;
  float* Qb = out + (size_t)N * 64;
  ushort* attnb = (ushort*)((char*)d_out + (size_t)N * 512);

  bool both_eps = ws_size >= ws_used + (size_t)E * 16;
  ushort *eps0, *eps1 = nullptr;
  if (both_eps) {
    eps0 = (ushort*)(ws + ws_used);
    eps1 = eps0 + (size_t)E * 4;
  } else {
    eps0 = (ushort*)((char*)d_out + (size_t)N * 640); // fits iff E <= 16N (true here)
  }

  int nb64 = (N + 63) / 64;

  prep_kernel<<<dim3(32, 18), 256, 0, stream>>>(Wq, Wk, Wv, WO, Wf1, Wf2, Wpi,
                                                W_h, W_pe, Wr1, Wr2, wb);
  fold_kernel<<<1, 256, 0, stream>>>(W_de, b_de, W_m, b_m, Wpd, bpd, Wpm, bpm, fold);
  rowptr_kernel<<<(N + 256) / 256, 256, 0, stream>>>(dst, E, N, row_ptr);
  hinit_mfma<<<nb64, 256, 0, stream>>>(x, pe, wb, b_pe, Hb, N);
  if (both_eps)
    escore_kernel<<<(E + 255) / 256, 256, 0, stream>>>(de, m, fold, eps0, eps1, E, 0);

  for (int lay = 0; lay < 2; ++lay) {
    if (!both_eps)
      escore_kernel<<<(E + 255) / 256, 256, 0, stream>>>(de, m, fold, eps0, nullptr, E, lay);
    qkv_mfma<<<nb64, 256, 0, stream>>>(Hb, wb, bq, bk, bv, Qb, KVb, N, lay);
    edge_kernel<<<(N + 3) / 4, 256, 0, stream>>>(Qb, KVb, src, row_ptr,
                                                 (both_eps && lay) ? eps1 : eps0, attnb, N);
    post_mfma<<<nb64, 256, 0, stream>>>(Hb, attnb, I, wb, bpi, bO, g1, b1,
                                        bf1, bf2, g2, b2, N, lay);
  }
  readout_mfma<<<nb64, 256, 0, stream>>>(Hb, wb, br1, br2, out, N);
}

// Round 4
// 502.422 us; speedup vs baseline: 2.0317x; 1.2146x over previous
//
#include <hip/hip_runtime.h>
#include <hip/hip_bf16.h>

typedef __hip_bfloat16 bf16;
typedef __attribute__((ext_vector_type(8))) short s8v;
typedef __attribute__((ext_vector_type(4))) float f4v;
typedef __attribute__((ext_vector_type(8))) _Float16 h8v;
#define DEV __device__ __forceinline__
#define MFMA(a, b, c) __builtin_amdgcn_mfma_f32_16x16x32_bf16(a, b, c, 0, 0, 0)

// split-bf16 weight table offsets (elements); each section: [hi sz][lo sz]
constexpr int OFF_WQ = 0, OFF_WK = 8192, OFF_WV = 16384, OFF_WO = 24576;
constexpr int OFF_WF1 = 32768, OFF_WF2 = 49152, OFF_WPI = 65536;
constexpr int PL = 69632; // per-layer stride
constexpr int OFF_WH = 139264, OFF_WPE = 155648, OFF_WR1 = 159744, OFF_WR2 = 161792;
constexpr int WBF_TOT = 169984;

constexpr float LOG2E = 1.4426950408889634f;
constexpr float QSC = 4.f * LOG2E;         // folds 16*SCALE and log2(e) into Q
constexpr float CLB = 5.f * LOG2E;         // clamp bound in log2 domain

DEV short f2bs(float f) { union { bf16 b; short s; } u; u.b = __float2bfloat16(f); return u.s; }
DEV float bs2f(short s) { union { bf16 b; short s2; } u; u.s2 = s; return __bfloat162float(u.b); }
DEV ushort f2hs(float f) { union { _Float16 h; ushort u; } x; x.h = (_Float16)f; return x.u; }

DEV void split8(const float* p, s8v& hi, s8v& lo) {
  #pragma unroll
  for (int j = 0; j < 8; ++j) {
    float f = p[j];
    short h = f2bs(f);
    hi[j] = h;
    lo[j] = f2bs(f - bs2f(h));
  }
}

// ---------------- weight prep: transpose + split to bf16 hi/lo ----------------
__global__ __launch_bounds__(256) void prep_kernel(
    const float* __restrict__ Wq, const float* __restrict__ Wk,
    const float* __restrict__ Wv, const float* __restrict__ WO,
    const float* __restrict__ Wf1, const float* __restrict__ Wf2,
    const float* __restrict__ Wpi, const float* __restrict__ W_h,
    const float* __restrict__ W_pe, const float* __restrict__ Wr1,
    const float* __restrict__ Wr2, short* __restrict__ wb)
{
  const float* sp; int K, ksh, Nc, d0;
  switch (blockIdx.y) {
    case 0:  sp = Wq;         K = 64;  ksh = 6; Nc = 64;  d0 = OFF_WQ;       break;
    case 1:  sp = Wk;         K = 64;  ksh = 6; Nc = 64;  d0 = OFF_WK;       break;
    case 2:  sp = Wv;         K = 64;  ksh = 6; Nc = 64;  d0 = OFF_WV;       break;
    case 3:  sp = WO;         K = 64;  ksh = 6; Nc = 64;  d0 = OFF_WO;       break;
    case 4:  sp = Wf1;        K = 64;  ksh = 6; Nc = 128; d0 = OFF_WF1;      break;
    case 5:  sp = Wf2;        K = 128; ksh = 7; Nc = 64;  d0 = OFF_WF2;      break;
    case 6:  sp = Wpi;        K = 16;  ksh = 5; Nc = 64;  d0 = OFF_WPI;      break;
    case 7:  sp = Wq + 4096;  K = 64;  ksh = 6; Nc = 64;  d0 = PL + OFF_WQ;  break;
    case 8:  sp = Wk + 4096;  K = 64;  ksh = 6; Nc = 64;  d0 = PL + OFF_WK;  break;
    case 9:  sp = Wv + 4096;  K = 64;  ksh = 6; Nc = 64;  d0 = PL + OFF_WV;  break;
    case 10: sp = WO + 4096;  K = 64;  ksh = 6; Nc = 64;  d0 = PL + OFF_WO;  break;
    case 11: sp = Wf1 + 8192; K = 64;  ksh = 6; Nc = 128; d0 = PL + OFF_WF1; break;
    case 12: sp = Wf2 + 8192; K = 128; ksh = 7; Nc = 64;  d0 = PL + OFF_WF2; break;
    case 13: sp = Wpi + 1024; K = 16;  ksh = 5; Nc = 64;  d0 = PL + OFF_WPI; break;
    case 14: sp = W_h;        K = 128; ksh = 7; Nc = 64;  d0 = OFF_WH;       break;
    case 15: sp = W_pe;       K = 16;  ksh = 5; Nc = 64;  d0 = OFF_WPE;      break;
    case 16: sp = Wr1;        K = 64;  ksh = 6; Nc = 16;  d0 = OFF_WR1;      break;
    default: sp = Wr2;        K = 16;  ksh = 5; Nc = 128; d0 = OFF_WR2;      break;
  }
  int Kp = 1 << ksh;
  int tot = Kp * Nc;
  int i = blockIdx.x * 256 + threadIdx.x;
  if (i >= tot) return;
  int o = i >> ksh, kk = i & (Kp - 1);
  float v = (kk < K) ? sp[kk * Nc + o] : 0.f; // dst[o][kk] = src[kk][o], zero-pad K
  short h = f2bs(v);
  wb[d0 + i] = h;
  wb[d0 + tot + i] = f2bs(v - bs2f(h));
}

// ---------------- fold de/m through per-head column sums ----------------
__global__ __launch_bounds__(256) void fold_kernel(
    const float* __restrict__ W_de, const float* __restrict__ b_de,
    const float* __restrict__ W_m,  const float* __restrict__ b_m,
    const float* __restrict__ Wpd,  const float* __restrict__ bpd,
    const float* __restrict__ Wpm,  const float* __restrict__ bpm,
    float* __restrict__ fold)
{
  __shared__ float spd[64][4], spm[64][4];
  int tid = threadIdx.x;
  for (int l = 0; l < 2; ++l) {
    { // phase 1: 256 threads = (t, hh)
      int t = tid >> 2, hh = tid & 3;
      const float* wpd = Wpd + l * 4096 + t * 64 + hh * 16;
      const float* wpm = Wpm + l * 4096 + t * 64 + hh * 16;
      float sd = 0.f, sm = 0.f;
      #pragma unroll
      for (int hd = 0; hd < 16; ++hd) { sd += wpd[hd]; sm += wpm[hd]; }
      spd[t][hh] = sd; spm[t][hh] = sm;
    }
    __syncthreads();
    if (tid < 64) { int i = tid >> 2, hh = tid & 3;
      float a = 0.f;
      for (int k = 0; k < 64; ++k) a += W_de[i * 64 + k] * spd[k][hh];
      fold[l * 128 + i * 4 + hh] = a; }
    if (tid < 32) { int i = tid >> 2, hh = tid & 3;
      float a = 0.f;
      for (int k = 0; k < 64; ++k) a += W_m[i * 64 + k] * spm[k][hh];
      fold[l * 128 + 64 + i * 4 + hh] = a; }
    if (tid < 4) { int hh = tid;
      float a = 0.f;
      for (int k = 0; k < 64; ++k) a += b_de[k] * spd[k][hh] + b_m[k] * spm[k][hh];
      for (int hd = 0; hd < 16; ++hd)
        a += bpd[l * 64 + hh * 16 + hd] + bpm[l * 64 + hh * 16 + hd];
      fold[l * 128 + 96 + hh] = a; }
    __syncthreads();
  }
}

// ---------------- per-edge folded score, pre-scaled by log2(e), f16 out ------
__global__ __launch_bounds__(256) void escore_kernel(
    const float* __restrict__ de, const float* __restrict__ m,
    const float* __restrict__ fold, ushort* __restrict__ ep0,
    ushort* __restrict__ ep1, int E, int lay)
{
  int e = blockIdx.x * 256 + threadIdx.x;
  if (e >= E) return;
  float dv[16], mv[8];
  #pragma unroll
  for (int i = 0; i < 4; ++i)
    *(float4*)(dv + 4 * i) = ((const float4*)(de + (size_t)e * 16))[i];
  #pragma unroll
  for (int i = 0; i < 2; ++i)
    *(float4*)(mv + 4 * i) = ((const float4*)(m + (size_t)e * 8))[i];
  #pragma unroll
  for (int pass = 0; pass < 2; ++pass) {
    ushort* ep; int l;
    if (pass == 0) { ep = ep0; l = ep1 ? 0 : lay; }
    else { if (!ep1) break; ep = ep1; l = 1; }
    const float* f = fold + l * 128;
    ushort4 o;
    ushort* op = (ushort*)&o;
    #pragma unroll
    for (int hh = 0; hh < 4; ++hh) {
      float a = f[96 + hh];
      #pragma unroll
      for (int i = 0; i < 16; ++i) a += dv[i] * f[i * 4 + hh];
      #pragma unroll
      for (int i = 0; i < 8; ++i) a += mv[i] * f[64 + i * 4 + hh];
      op[hh] = f2hs(a * LOG2E);
    }
    *(ushort4*)(ep + (size_t)e * 4) = o;
  }
}

// ---------------- CSR rowptr ----------------
__global__ __launch_bounds__(256) void rowptr_kernel(
    const int* __restrict__ dst, int E, int N, int* __restrict__ rp)
{
  int n = blockIdx.x * blockDim.x + threadIdx.x;
  if (n > N) return;
  int lo = 0, hi = E;
  while (lo < hi) {
    int mid = (lo + hi) >> 1;
    if (dst[mid] < n) lo = mid + 1; else hi = mid;
  }
  rp[n] = lo;
}

// ---------------- hinit: H = x@W_h + pe@W_pe + b_pe (MFMA, split A+B) --------
__global__ __launch_bounds__(256) void hinit_mfma(
    const float* __restrict__ x, const float* __restrict__ pe,
    const short* __restrict__ wb, const float* __restrict__ b_pe,
    ushort* __restrict__ Hb, int N)
{
  __shared__ __align__(16) ushort sH[64][72];
  int tid = threadIdx.x, wv = tid >> 6, ln = tid & 63;
  int q = ln >> 4, p16 = ln & 15;
  int nb0 = blockIdx.x * 64;
  int arow = nb0 + wv * 16 + p16; if (arow >= N) arow = N - 1;
  f4v acc[4] = {};
  for (int kt = 0; kt < 4; ++kt) {
    s8v ah, al;
    split8(x + (size_t)arow * 128 + kt * 32 + 8 * q, ah, al);
    #pragma unroll
    for (int ct = 0; ct < 4; ++ct) {
      int bo = (ct * 16 + p16) * 128 + kt * 32 + 8 * q;
      s8v bh = *(const s8v*)(wb + OFF_WH + bo);
      s8v bl = *(const s8v*)(wb + OFF_WH + 8192 + bo);
      acc[ct] = MFMA(ah, bh, acc[ct]);
      acc[ct] = MFMA(ah, bl, acc[ct]);
      acc[ct] = MFMA(al, bh, acc[ct]);
    }
  }
  { // pe: K=16 zero-padded to 32
    s8v ah = {}, al = {};
    if (q < 2) split8(pe + (size_t)arow * 16 + 8 * q, ah, al);
    #pragma unroll
    for (int ct = 0; ct < 4; ++ct) {
      int bo = (ct * 16 + p16) * 32 + 8 * q;
      s8v bh = *(const s8v*)(wb + OFF_WPE + bo);
      s8v bl = *(const s8v*)(wb + OFF_WPE + 2048 + bo);
      acc[ct] = MFMA(ah, bh, acc[ct]);
      acc[ct] = MFMA(ah, bl, acc[ct]);
      acc[ct] = MFMA(al, bh, acc[ct]);
    }
  }
  #pragma unroll
  for (int ct = 0; ct < 4; ++ct) {
    float bb = b_pe[ct * 16 + p16];
    #pragma unroll
    for (int j = 0; j < 4; ++j)
      sH[wv * 16 + q * 4 + j][ct * 16 + p16] = (ushort)f2bs(acc[ct][j] + bb);
  }
  __syncthreads();
  int row = tid >> 2, part = tid & 3;
  if (nb0 + row < N) {
    uint4 a0 = *(uint4*)&sH[row][part * 16];
    uint4 a1 = *(uint4*)&sH[row][part * 16 + 8];
    *(uint4*)(Hb + (size_t)(nb0 + row) * 64 + part * 16) = a0;
    *(uint4*)(Hb + (size_t)(nb0 + row) * 64 + part * 16 + 8) = a1;
  }
}

// ---------------- QKV (MFMA): Q f32 (scaled by 4*log2e), K/V f16 -------------
__global__ __launch_bounds__(256) void qkv_mfma(
    const ushort* __restrict__ Hb, const short* __restrict__ wb,
    const float* __restrict__ bq, const float* __restrict__ bk, const float* __restrict__ bv,
    float* __restrict__ Qb, ushort* __restrict__ Kb, ushort* __restrict__ Vb,
    int N, int lay)
{
  __shared__ __align__(16) ushort sK[64][72];
  __shared__ __align__(16) ushort sV[64][72];
  int tid = threadIdx.x, wv = tid >> 6, ln = tid & 63;
  int q = ln >> 4, p16 = ln & 15;
  int nb0 = blockIdx.x * 64;
  int arow = nb0 + wv * 16 + p16; if (arow >= N) arow = N - 1;
  int wbase = lay * PL;
  s8v a0 = *(const s8v*)(Hb + (size_t)arow * 64 + 8 * q);
  s8v a1 = *(const s8v*)(Hb + (size_t)arow * 64 + 32 + 8 * q);
  f4v qa[4] = {}, ka[4] = {}, va[4] = {};
  #pragma unroll
  for (int kt = 0; kt < 2; ++kt) {
    s8v a = kt ? a1 : a0;
    #pragma unroll
    for (int ct = 0; ct < 4; ++ct) {
      int bo = (ct * 16 + p16) * 64 + kt * 32 + 8 * q;
      s8v bh, bl;
      bh = *(const s8v*)(wb + wbase + OFF_WQ + bo);
      bl = *(const s8v*)(wb + wbase + OFF_WQ + 4096 + bo);
      qa[ct] = MFMA(a, bh, qa[ct]); qa[ct] = MFMA(a, bl, qa[ct]);
      bh = *(const s8v*)(wb + wbase + OFF_WK + bo);
      bl = *(const s8v*)(wb + wbase + OFF_WK + 4096 + bo);
      ka[ct] = MFMA(a, bh, ka[ct]); ka[ct] = MFMA(a, bl, ka[ct]);
      bh = *(const s8v*)(wb + wbase + OFF_WV + bo);
      bl = *(const s8v*)(wb + wbase + OFF_WV + 4096 + bo);
      va[ct] = MFMA(a, bh, va[ct]); va[ct] = MFMA(a, bl, va[ct]);
    }
  }
  #pragma unroll
  for (int ct = 0; ct < 4; ++ct) {
    int col = ct * 16 + p16;
    float bQ = bq[lay * 64 + col], bK = bk[lay * 64 + col], bV = bv[lay * 64 + col];
    #pragma unroll
    for (int j = 0; j < 4; ++j) {
      int r = nb0 + wv * 16 + q * 4 + j;
      if (r < N) Qb[(size_t)r * 64 + col] = (qa[ct][j] + bQ) * QSC;
      sK[wv * 16 + q * 4 + j][col] = f2hs(ka[ct][j] + bK);
      sV[wv * 16 + q * 4 + j][col] = f2hs(va[ct][j] + bV);
    }
  }
  __syncthreads();
  int row = tid >> 2, part = tid & 3;
  if (nb0 + row < N) {
    uint4 k0 = *(uint4*)&sK[row][part * 16];
    uint4 k1 = *(uint4*)&sK[row][part * 16 + 8];
    *(uint4*)(Kb + (size_t)(nb0 + row) * 64 + part * 16) = k0;
    *(uint4*)(Kb + (size_t)(nb0 + row) * 64 + part * 16 + 8) = k1;
    uint4 v0 = *(uint4*)&sV[row][part * 16];
    uint4 v1 = *(uint4*)&sV[row][part * 16 + 8];
    *(uint4*)(Vb + (size_t)(nb0 + row) * 64 + part * 16) = v0;
    *(uint4*)(Vb + (size_t)(nb0 + row) * 64 + part * 16 + 8) = v1;
  }
}

// ---------------- edge attention: lane = (edge_slot, head) -------------------
// Wave per node. 16 edges/chunk, dot is lane-local (no per-edge cross-lane).
__global__ __launch_bounds__(256, 4) void edge_kernel(
    const float* __restrict__ Qb, const _Float16* __restrict__ Kb,
    const _Float16* __restrict__ Vb, const int* __restrict__ src,
    const int* __restrict__ rp, const _Float16* __restrict__ epsl,
    ushort* __restrict__ attnb, int N)
{
  __shared__ float red[4][16][64];
  int tid = threadIdx.x, ln = tid & 63;
  int wv = __builtin_amdgcn_readfirstlane(tid >> 6);
  int w = blockIdx.x * 4 + wv;
  bool wok = w < N;
  int wc = wok ? w : N - 1;
  int es = ln >> 2, h = ln & 3;

  // Q slice for this lane's head: 16 f32 (Q pre-scaled by 4*log2e)
  float q[16];
  const float* qp = Qb + (size_t)wc * 64 + h * 16;
  #pragma unroll
  for (int i = 0; i < 4; ++i)
    *(float4*)(q + 4 * i) = ((const float4*)qp)[i];

  int e0 = rp[wc], e1 = rp[wc + 1];
  int elast = e1 - 1;
  float acc[16];
  #pragma unroll
  for (int i = 0; i < 16; ++i) acc[i] = 0.f;
  float z = 0.f;

  for (int e = e0; e < e1; e += 16) {
    int eidx = e + es;
    bool val = eidx <= elast;
    int eic = val ? eidx : elast;
    int sidx = src[eic];
    size_t ko = (size_t)sidx * 64 + h * 16;
    h8v k0 = *(const h8v*)(Kb + ko);
    h8v k1 = *(const h8v*)(Kb + ko + 8);
    h8v v0 = *(const h8v*)(Vb + ko);
    h8v v1 = *(const h8v*)(Vb + ko + 8);
    float pe_ = (float)epsl[(size_t)eic * 4 + h];
    float t0 = 0.f, t1 = 0.f;
    #pragma unroll
    for (int i = 0; i < 8; ++i) {
      t0 = fmaf((float)k0[i], q[i], t0);
      t1 = fmaf((float)k1[i], q[i + 8], t1);
    }
    float sc = fminf(fmaxf(t0 + t1 + pe_, -CLB), CLB);
    float sv = __builtin_amdgcn_exp2f(sc);
    sv = val ? sv : 0.f;
    z += sv;
    #pragma unroll
    for (int i = 0; i < 8; ++i) {
      acc[i] = fmaf(sv, (float)v0[i], acc[i]);
      acc[i + 8] = fmaf(sv, (float)v1[i], acc[i + 8]);
    }
  }

  // z: reduce over edge-slot lanes (stride-4 xor network), replicated per head
  z += __shfl_xor(z, 4, 64);
  z += __shfl_xor(z, 8, 64);
  z += __shfl_xor(z, 16, 64);
  z += __shfl_xor(z, 32, 64);

  // acc: wave-private LDS transpose (es,h)-partials -> column layout
  float* rw = &red[wv][es][h * 16];
  #pragma unroll
  for (int i = 0; i < 4; ++i)
    *(float4*)(rw + i * 4) = *(const float4*)(acc + i * 4);
  __asm__ volatile("s_waitcnt lgkmcnt(0)" ::: "memory");
  int c = ln;
  float zc = __shfl(z, c >> 4, 64); // lanes 0..3 hold heads 0..3
  float s = 0.f;
  #pragma unroll
  for (int es2 = 0; es2 < 16; ++es2) s += red[wv][es2][c];
  if (wok) attnb[(size_t)w * 64 + c] = (ushort)f2bs(s / (zc + 1e-10f));
}

// ---------------- post: u=attn+I@Wpi -> @WO -> LN1 -> FFN -> LN2 (MFMA) ------
__global__ __launch_bounds__(256) void post_mfma(
    ushort* __restrict__ Hb, const ushort* __restrict__ attnb,
    const float* __restrict__ I, const short* __restrict__ wb,
    const float* __restrict__ bpi, const float* __restrict__ bO,
    const float* __restrict__ g1, const float* __restrict__ b1,
    const float* __restrict__ bf1, const float* __restrict__ bf2,
    const float* __restrict__ g2, const float* __restrict__ b2,
    int N, int lay)
{
  constexpr float BN_S = 0.9999950000374997f;
  __shared__ __align__(16) ushort sH[64][72];
  __shared__ __align__(16) ushort sA[64][72];
  __shared__ float sF[64][65];
  __shared__ __align__(16) ushort sT[64][136];
  int tid = threadIdx.x, wv = tid >> 6, ln = tid & 63;
  int q = ln >> 4, p16 = ln & 15;
  int nb0 = blockIdx.x * 64;
  { // stage H + attn (coalesced)
    int row = tid >> 2, part = tid & 3;
    int gr = nb0 + row; if (gr >= N) gr = N - 1;
    uint4 h0 = *(const uint4*)(Hb + (size_t)gr * 64 + part * 16);
    uint4 h1 = *(const uint4*)(Hb + (size_t)gr * 64 + part * 16 + 8);
    *(uint4*)&sH[row][part * 16] = h0;
    *(uint4*)&sH[row][part * 16 + 8] = h1;
    uint4 t0 = *(const uint4*)(attnb + (size_t)gr * 64 + part * 16);
    uint4 t1 = *(const uint4*)(attnb + (size_t)gr * 64 + part * 16 + 8);
    *(uint4*)&sA[row][part * 16] = t0;
    *(uint4*)&sA[row][part * 16 + 8] = t1;
  }
  __syncthreads();
  int wbase = lay * PL;
  int arow = nb0 + wv * 16 + p16; if (arow >= N) arow = N - 1;
  // ---- u = I@Wpi + bpi + attn ----
  f4v uacc[4] = {};
  {
    s8v ah = {}, al = {};
    if (q < 2) split8(I + (size_t)arow * 16 + 8 * q, ah, al);
    #pragma unroll
    for (int ct = 0; ct < 4; ++ct) {
      int bo = (ct * 16 + p16) * 32 + 8 * q;
      s8v bh = *(const s8v*)(wb + wbase + OFF_WPI + bo);
      s8v bl = *(const s8v*)(wb + wbase + OFF_WPI + 2048 + bo);
      uacc[ct] = MFMA(ah, bh, uacc[ct]);
      uacc[ct] = MFMA(ah, bl, uacc[ct]);
      uacc[ct] = MFMA(al, bh, uacc[ct]);
    }
  }
  #pragma unroll
  for (int ct = 0; ct < 4; ++ct) {
    int col = ct * 16 + p16;
    float bb = bpi[lay * 64 + col];
    #pragma unroll
    for (int j = 0; j < 4; ++j) {
      uacc[ct][j] += bb + bs2f((short)sA[wv * 16 + q * 4 + j][col]);
      sF[wv * 16 + q * 4 + j][col] = uacc[ct][j];
    }
  }
  __syncthreads();
  // ---- v = u@WO + bO ; hw = h + v ; LN1 -> h1 ----
  f4v vacc[4] = {};
  #pragma unroll
  for (int kt = 0; kt < 2; ++kt) {
    s8v ah, al;
    split8(&sF[wv * 16 + p16][kt * 32 + 8 * q], ah, al);
    #pragma unroll
    for (int ct = 0; ct < 4; ++ct) {
      int bo = (ct * 16 + p16) * 64 + kt * 32 + 8 * q;
      s8v bh = *(const s8v*)(wb + wbase + OFF_WO + bo);
      s8v bl = *(const s8v*)(wb + wbase + OFF_WO + 4096 + bo);
      vacc[ct] = MFMA(ah, bh, vacc[ct]);
      vacc[ct] = MFMA(ah, bl, vacc[ct]);
      vacc[ct] = MFMA(al, bh, vacc[ct]);
    }
  }
  float hw[4][4];
  #pragma unroll
  for (int ct = 0; ct < 4; ++ct) {
    int col = ct * 16 + p16;
    float bb = bO[lay * 64 + col];
    #pragma unroll
    for (int j = 0; j < 4; ++j)
      hw[ct][j] = bs2f((short)sH[wv * 16 + q * 4 + j][col]) + vacc[ct][j] + bb;
  }
  float h1r[4][4];
  {
    float s0[4], mu[4], vv[4], rs[4];
    #pragma unroll
    for (int j = 0; j < 4; ++j) s0[j] = hw[0][j] + hw[1][j] + hw[2][j] + hw[3][j];
    #pragma unroll
    for (int msk = 1; msk < 16; msk <<= 1)
      #pragma unroll
      for (int j = 0; j < 4; ++j) s0[j] += __shfl_xor(s0[j], msk, 64);
    #pragma unroll
    for (int j = 0; j < 4; ++j) { mu[j] = s0[j] * (1.f / 64.f); vv[j] = 0.f; }
    #pragma unroll
    for (int ct = 0; ct < 4; ++ct)
      #pragma unroll
      for (int j = 0; j < 4; ++j) { float d = hw[ct][j] - mu[j]; hw[ct][j] = d; vv[j] += d * d; }
    #pragma unroll
    for (int msk = 1; msk < 16; msk <<= 1)
      #pragma unroll
      for (int j = 0; j < 4; ++j) vv[j] += __shfl_xor(vv[j], msk, 64);
    #pragma unroll
    for (int j = 0; j < 4; ++j) rs[j] = 1.f / sqrtf(vv[j] * (1.f / 64.f) + 1e-5f);
    #pragma unroll
    for (int ct = 0; ct < 4; ++ct) {
      int col = ct * 16 + p16;
      float gg = g1[lay * 64 + col], bb = b1[lay * 64 + col];
      #pragma unroll
      for (int j = 0; j < 4; ++j)
        h1r[ct][j] = (hw[ct][j] * rs[j] * gg + bb) * BN_S;
    }
  }
  __syncthreads();
  #pragma unroll
  for (int ct = 0; ct < 4; ++ct)
    #pragma unroll
    for (int j = 0; j < 4; ++j)
      sF[wv * 16 + q * 4 + j][ct * 16 + p16] = h1r[ct][j];
  __syncthreads();
  // ---- t = relu(h1@Wf1 + bf1) -> sT ----
  f4v tacc[8] = {};
  #pragma unroll
  for (int kt = 0; kt < 2; ++kt) {
    s8v ah, al;
    split8(&sF[wv * 16 + p16][kt * 32 + 8 * q], ah, al);
    #pragma unroll
    for (int ct = 0; ct < 8; ++ct) {
      int bo = (ct * 16 + p16) * 64 + kt * 32 + 8 * q;
      s8v bh = *(const s8v*)(wb + wbase + OFF_WF1 + bo);
      s8v bl = *(const s8v*)(wb + wbase + OFF_WF1 + 8192 + bo);
      tacc[ct] = MFMA(ah, bh, tacc[ct]);
      tacc[ct] = MFMA(ah, bl, tacc[ct]);
      tacc[ct] = MFMA(al, bh, tacc[ct]);
    }
  }
  #pragma unroll
  for (int ct = 0; ct < 8; ++ct) {
    int col = ct * 16 + p16;
    float bb = bf1[lay * 128 + col];
    #pragma unroll
    for (int j = 0; j < 4; ++j)
      sT[wv * 16 + q * 4 + j][col] = (ushort)f2bs(fmaxf(tacc[ct][j] + bb, 0.f));
  }
  __syncthreads();
  // ---- y = t@Wf2 + bf2 ; w2 = h1 + y ; LN2 -> h2 ----
  f4v yacc[4] = {};
  #pragma unroll
  for (int kt = 0; kt < 4; ++kt) {
    s8v at = *(const s8v*)&sT[wv * 16 + p16][kt * 32 + 8 * q];
    #pragma unroll
    for (int ct = 0; ct < 4; ++ct) {
      int bo = (ct * 16 + p16) * 128 + kt * 32 + 8 * q;
      s8v bh = *(const s8v*)(wb + wbase + OFF_WF2 + bo);
      s8v bl = *(const s8v*)(wb + wbase + OFF_WF2 + 8192 + bo);
      yacc[ct] = MFMA(at, bh, yacc[ct]);
      yacc[ct] = MFMA(at, bl, yacc[ct]);
    }
  }
  float w2[4][4];
  #pragma unroll
  for (int ct = 0; ct < 4; ++ct) {
    int col = ct * 16 + p16;
    float bb = bf2[lay * 64 + col];
    #pragma unroll
    for (int j = 0; j < 4; ++j)
      w2[ct][j] = h1r[ct][j] + yacc[ct][j] + bb;
  }
  {
    float s0[4], mu[4], vv[4], rs[4];
    #pragma unroll
    for (int j = 0; j < 4; ++j) s0[j] = w2[0][j] + w2[1][j] + w2[2][j] + w2[3][j];
    #pragma unroll
    for (int msk = 1; msk < 16; msk <<= 1)
      #pragma unroll
      for (int j = 0; j < 4; ++j) s0[j] += __shfl_xor(s0[j], msk, 64);
    #pragma unroll
    for (int j = 0; j < 4; ++j) { mu[j] = s0[j] * (1.f / 64.f); vv[j] = 0.f; }
    #pragma unroll
    for (int ct = 0; ct < 4; ++ct)
      #pragma unroll
      for (int j = 0; j < 4; ++j) { float d = w2[ct][j] - mu[j]; w2[ct][j] = d; vv[j] += d * d; }
    #pragma unroll
    for (int msk = 1; msk < 16; msk <<= 1)
      #pragma unroll
      for (int j = 0; j < 4; ++j) vv[j] += __shfl_xor(vv[j], msk, 64);
    #pragma unroll
    for (int j = 0; j < 4; ++j) rs[j] = 1.f / sqrtf(vv[j] * (1.f / 64.f) + 1e-5f);
    #pragma unroll
    for (int ct = 0; ct < 4; ++ct) {
      int col = ct * 16 + p16;
      float gg = g2[lay * 64 + col], bb = b2[lay * 64 + col];
      #pragma unroll
      for (int j = 0; j < 4; ++j)
        sH[wv * 16 + q * 4 + j][col] = (ushort)f2bs((w2[ct][j] * rs[j] * gg + bb) * BN_S);
    }
  }
  __syncthreads();
  {
    int row = tid >> 2, part = tid & 3;
    if (nb0 + row < N) {
      uint4 a0 = *(uint4*)&sH[row][part * 16];
      uint4 a1 = *(uint4*)&sH[row][part * 16 + 8];
      *(uint4*)(Hb + (size_t)(nb0 + row) * 64 + part * 16) = a0;
      *(uint4*)(Hb + (size_t)(nb0 + row) * 64 + part * 16 + 8) = a1;
    }
  }
}

// ---------------- readout: out0 = h ; x_hat = selu(h@Wr1+br1)@Wr2+br2 --------
__global__ __launch_bounds__(256) void readout_mfma(
    const ushort* __restrict__ Hb, const short* __restrict__ wb,
    const float* __restrict__ br1, const float* __restrict__ br2,
    float* __restrict__ out, int N)
{
  __shared__ __align__(16) ushort sH[64][72];
  __shared__ float sM[64][17];
  int tid = threadIdx.x, wv = tid >> 6, ln = tid & 63;
  int q = ln >> 4, p16 = ln & 15;
  int nb0 = blockIdx.x * 64;
  {
    int row = tid >> 2, part = tid & 3;
    int gr = nb0 + row; if (gr >= N) gr = N - 1;
    uint4 h0 = *(const uint4*)(Hb + (size_t)gr * 64 + part * 16);
    uint4 h1 = *(const uint4*)(Hb + (size_t)gr * 64 + part * 16 + 8);
    *(uint4*)&sH[row][part * 16] = h0;
    *(uint4*)&sH[row][part * 16 + 8] = h1;
  }
  __syncthreads();
  { // h out (fp32)
    int row = tid >> 2, part = tid & 3;
    if (nb0 + row < N) {
      #pragma unroll
      for (int c = 0; c < 16; ++c)
        out[(size_t)(nb0 + row) * 64 + part * 16 + c] = bs2f((short)sH[row][part * 16 + c]);
    }
  }
  // md = selu(h@Wr1 + br1)
  f4v macc = {};
  #pragma unroll
  for (int kt = 0; kt < 2; ++kt) {
    s8v a = *(const s8v*)&sH[wv * 16 + p16][kt * 32 + 8 * q];
    int bo = p16 * 64 + kt * 32 + 8 * q;
    s8v bh = *(const s8v*)(wb + OFF_WR1 + bo);
    s8v bl = *(const s8v*)(wb + OFF_WR1 + 1024 + bo);
    macc = MFMA(a, bh, macc);
    macc = MFMA(a, bl, macc);
  }
  const float SC = 1.0507009873554805f, AL = 1.6732632423543772f;
  #pragma unroll
  for (int j = 0; j < 4; ++j) {
    float md = macc[j] + br1[p16];
    md = (md > 0.f) ? SC * md : SC * AL * expm1f(md);
    sM[wv * 16 + q * 4 + j][p16] = md;
  }
  __syncthreads();
  // x_hat = md@Wr2 + br2 (K=16 padded to 32)
  f4v xacc[8] = {};
  {
    s8v ah = {}, al = {};
    if (q < 2) split8(&sM[wv * 16 + p16][8 * q], ah, al);
    #pragma unroll
    for (int ct = 0; ct < 8; ++ct) {
      int bo = (ct * 16 + p16) * 32 + 8 * q;
      s8v bh = *(const s8v*)(wb + OFF_WR2 + bo);
      s8v bl = *(const s8v*)(wb + OFF_WR2 + 4096 + bo);
      xacc[ct] = MFMA(ah, bh, xacc[ct]);
      xacc[ct] = MFMA(ah, bl, xacc[ct]);
      xacc[ct] = MFMA(al, bh, xacc[ct]);
    }
  }
  #pragma unroll
  for (int ct = 0; ct < 8; ++ct) {
    int col = ct * 16 + p16;
    float bb = br2[col];
    #pragma unroll
    for (int j = 0; j < 4; ++j) {
      int r = nb0 + wv * 16 + q * 4 + j;
      if (r < N) out[(size_t)N * 64 + (size_t)r * 128 + col] = xacc[ct][j] + bb;
    }
  }
}

extern "C" void kernel_launch(void* const* d_in, const int* in_sizes, int n_in,
                              void* d_out, int out_size, void* d_ws, size_t ws_size,
                              hipStream_t stream)
{
  const int* src    = (const int*)d_in[0];
  const int* dst    = (const int*)d_in[1];
  const float* x    = (const float*)d_in[2];
  const float* pe   = (const float*)d_in[3];
  const float* de   = (const float*)d_in[4];
  const float* m    = (const float*)d_in[5];
  const float* I    = (const float*)d_in[6];
  const float* W_h  = (const float*)d_in[7];
  const float* W_pe = (const float*)d_in[8];
  const float* b_pe = (const float*)d_in[9];
  const float* W_de = (const float*)d_in[10];
  const float* b_de = (const float*)d_in[11];
  const float* W_m  = (const float*)d_in[12];
  const float* b_m  = (const float*)d_in[13];
  const float* Wq   = (const float*)d_in[14];
  const float* bq   = (const float*)d_in[15];
  const float* Wk   = (const float*)d_in[16];
  const float* bk   = (const float*)d_in[17];
  const float* Wv   = (const float*)d_in[18];
  const float* bv   = (const float*)d_in[19];
  const float* Wpd  = (const float*)d_in[20];
  const float* bpd  = (const float*)d_in[21];
  const float* Wpm  = (const float*)d_in[22];
  const float* bpm  = (const float*)d_in[23];
  const float* WO   = (const float*)d_in[24];
  const float* bO   = (const float*)d_in[25];
  const float* Wpi  = (const float*)d_in[26];
  const float* bpi  = (const float*)d_in[27];
  const float* g1   = (const float*)d_in[28];
  const float* b1   = (const float*)d_in[29];
  const float* g2   = (const float*)d_in[30];
  const float* b2   = (const float*)d_in[31];
  const float* Wf1  = (const float*)d_in[32];
  const float* bf1  = (const float*)d_in[33];
  const float* Wf2  = (const float*)d_in[34];
  const float* bf2  = (const float*)d_in[35];
  const float* Wr1  = (const float*)d_in[36];
  const float* br1  = (const float*)d_in[37];
  const float* Wr2  = (const float*)d_in[38];
  const float* br2  = (const float*)d_in[39];

  const int E = in_sizes[0];
  const int N = in_sizes[2] / 128;

  // ws: rowptr | fold | split-weights | H (bf16) | [eps both layers]
  char* ws = (char*)d_ws;
  int* row_ptr = (int*)ws;
  size_t rp_bytes = (((size_t)(N + 1) * 4) + 255) & ~(size_t)255;
  float* fold = (float*)(ws + rp_bytes);
  short* wb = (short*)(ws + rp_bytes + 1024);
  ushort* Hb = (ushort*)(ws + rp_bytes + 1024 + (size_t)WBF_TOT * 2);
  size_t ws_used = rp_bytes + 1024 + (size_t)WBF_TOT * 2 + (size_t)N * 128;

  // d_out doubles as scratch until readout rewrites every byte:
  // K f16 [0,128N) | V f16 [128N,256N) | Q f32 [256N,512N) | attn bf16 [512N,640N)
  // | eps fallback f16 [640N, 640N+8E)  (fits iff E <= 16N, true here)
  float* out = (float*)d_out;
  ushort* Kb = (ushort*)out;
  ushort* Vb = Kb + (size_t)N * 64;
  float* Qb = out + (size_t)N * 64;
  ushort* attnb = (ushort*)((char*)d_out + (size_t)N * 512);

  bool both_eps = ws_size >= ws_used + (size_t)E * 16;
  ushort *eps0, *eps1 = nullptr;
  if (both_eps) {
    eps0 = (ushort*)(ws + ws_used);
    eps1 = eps0 + (size_t)E * 4;
  } else {
    eps0 = (ushort*)((char*)d_out + (size_t)N * 640);
  }

  int nb64 = (N + 63) / 64;

  prep_kernel<<<dim3(32, 18), 256, 0, stream>>>(Wq, Wk, Wv, WO, Wf1, Wf2, Wpi,
                                                W_h, W_pe, Wr1, Wr2, wb);
  fold_kernel<<<1, 256, 0, stream>>>(W_de, b_de, W_m, b_m, Wpd, bpd, Wpm, bpm, fold);
  rowptr_kernel<<<(N + 256) / 256, 256, 0, stream>>>(dst, E, N, row_ptr);
  hinit_mfma<<<nb64, 256, 0, stream>>>(x, pe, wb, b_pe, Hb, N);
  if (both_eps)
    escore_kernel<<<(E + 255) / 256, 256, 0, stream>>>(de, m, fold, eps0, eps1, E, 0);

  for (int lay = 0; lay < 2; ++lay) {
    if (!both_eps)
      escore_kernel<<<(E + 255) / 256, 256, 0, stream>>>(de, m, fold, eps0, nullptr, E, lay);
    qkv_mfma<<<nb64, 256, 0, stream>>>(Hb, wb, bq, bk, bv, Qb, Kb, Vb, N, lay);
    edge_kernel<<<(N + 3) / 4, 256, 0, stream>>>(Qb, (const _Float16*)Kb,
        (const _Float16*)Vb, src, row_ptr,
        (const _Float16*)((both_eps && lay) ? eps1 : eps0), attnb, N);
    post_mfma<<<nb64, 256, 0, stream>>>(Hb, attnb, I, wb, bpi, bO, g1, b1,
                                        bf1, bf2, g2, b2, N, lay);
  }
  readout_mfma<<<nb64, 256, 0, stream>>>(Hb, wb, br1, br2, out, N);
}

// Round 5
// 488.455 us; speedup vs baseline: 2.0898x; 1.0286x over previous
//
#include <hip/hip_runtime.h>
#include <hip/hip_bf16.h>

typedef __hip_bfloat16 bf16;
typedef __attribute__((ext_vector_type(8))) short s8v;
typedef __attribute__((ext_vector_type(4))) float f4v;
typedef __attribute__((ext_vector_type(8))) _Float16 h8v;
#define DEV __device__ __forceinline__
#define MFMA(a, b, c) __builtin_amdgcn_mfma_f32_16x16x32_bf16(a, b, c, 0, 0, 0)

// split-bf16 weight table offsets (elements); each section: [hi sz][lo sz]
constexpr int OFF_WQ = 0, OFF_WK = 8192, OFF_WV = 16384, OFF_WO = 24576;
constexpr int OFF_WF1 = 32768, OFF_WF2 = 49152, OFF_WPI = 65536;
constexpr int PL = 69632; // per-layer stride
constexpr int OFF_WH = 139264, OFF_WPE = 155648, OFF_WR1 = 159744, OFF_WR2 = 161792;
constexpr int WBF_TOT = 169984;

constexpr float LOG2E = 1.4426950408889634f;
constexpr float QSC = 4.f * LOG2E;         // folds 16*SCALE and log2(e) into Q
constexpr float CLB = 5.f * LOG2E;         // clamp bound in log2 domain

DEV short f2bs(float f) { union { bf16 b; short s; } u; u.b = __float2bfloat16(f); return u.s; }
DEV float bs2f(short s) { union { bf16 b; short s2; } u; u.s2 = s; return __bfloat162float(u.b); }
DEV ushort f2hs(float f) { union { _Float16 h; ushort u; } x; x.h = (_Float16)f; return x.u; }

DEV void split8(const float* p, s8v& hi, s8v& lo) {
  #pragma unroll
  for (int j = 0; j < 8; ++j) {
    float f = p[j];
    short h = f2bs(f);
    hi[j] = h;
    lo[j] = f2bs(f - bs2f(h));
  }
}

// ---------------- weight prep: transpose + split to bf16 hi/lo ----------------
__global__ __launch_bounds__(256) void prep_kernel(
    const float* __restrict__ Wq, const float* __restrict__ Wk,
    const float* __restrict__ Wv, const float* __restrict__ WO,
    const float* __restrict__ Wf1, const float* __restrict__ Wf2,
    const float* __restrict__ Wpi, const float* __restrict__ W_h,
    const float* __restrict__ W_pe, const float* __restrict__ Wr1,
    const float* __restrict__ Wr2, short* __restrict__ wb)
{
  const float* sp; int K, ksh, Nc, d0;
  switch (blockIdx.y) {
    case 0:  sp = Wq;         K = 64;  ksh = 6; Nc = 64;  d0 = OFF_WQ;       break;
    case 1:  sp = Wk;         K = 64;  ksh = 6; Nc = 64;  d0 = OFF_WK;       break;
    case 2:  sp = Wv;         K = 64;  ksh = 6; Nc = 64;  d0 = OFF_WV;       break;
    case 3:  sp = WO;         K = 64;  ksh = 6; Nc = 64;  d0 = OFF_WO;       break;
    case 4:  sp = Wf1;        K = 64;  ksh = 6; Nc = 128; d0 = OFF_WF1;      break;
    case 5:  sp = Wf2;        K = 128; ksh = 7; Nc = 64;  d0 = OFF_WF2;      break;
    case 6:  sp = Wpi;        K = 16;  ksh = 5; Nc = 64;  d0 = OFF_WPI;      break;
    case 7:  sp = Wq + 4096;  K = 64;  ksh = 6; Nc = 64;  d0 = PL + OFF_WQ;  break;
    case 8:  sp = Wk + 4096;  K = 64;  ksh = 6; Nc = 64;  d0 = PL + OFF_WK;  break;
    case 9:  sp = Wv + 4096;  K = 64;  ksh = 6; Nc = 64;  d0 = PL + OFF_WV;  break;
    case 10: sp = WO + 4096;  K = 64;  ksh = 6; Nc = 64;  d0 = PL + OFF_WO;  break;
    case 11: sp = Wf1 + 8192; K = 64;  ksh = 6; Nc = 128; d0 = PL + OFF_WF1; break;
    case 12: sp = Wf2 + 8192; K = 128; ksh = 7; Nc = 64;  d0 = PL + OFF_WF2; break;
    case 13: sp = Wpi + 1024; K = 16;  ksh = 5; Nc = 64;  d0 = PL + OFF_WPI; break;
    case 14: sp = W_h;        K = 128; ksh = 7; Nc = 64;  d0 = OFF_WH;       break;
    case 15: sp = W_pe;       K = 16;  ksh = 5; Nc = 64;  d0 = OFF_WPE;      break;
    case 16: sp = Wr1;        K = 64;  ksh = 6; Nc = 16;  d0 = OFF_WR1;      break;
    default: sp = Wr2;        K = 16;  ksh = 5; Nc = 128; d0 = OFF_WR2;      break;
  }
  int Kp = 1 << ksh;
  int tot = Kp * Nc;
  int i = blockIdx.x * 256 + threadIdx.x;
  if (i >= tot) return;
  int o = i >> ksh, kk = i & (Kp - 1);
  float v = (kk < K) ? sp[kk * Nc + o] : 0.f; // dst[o][kk] = src[kk][o], zero-pad K
  short h = f2bs(v);
  wb[d0 + i] = h;
  wb[d0 + tot + i] = f2bs(v - bs2f(h));
}

// ---------------- fold de/m through per-head column sums ----------------
__global__ __launch_bounds__(256) void fold_kernel(
    const float* __restrict__ W_de, const float* __restrict__ b_de,
    const float* __restrict__ W_m,  const float* __restrict__ b_m,
    const float* __restrict__ Wpd,  const float* __restrict__ bpd,
    const float* __restrict__ Wpm,  const float* __restrict__ bpm,
    float* __restrict__ fold)
{
  __shared__ float spd[64][4], spm[64][4];
  int tid = threadIdx.x;
  for (int l = 0; l < 2; ++l) {
    {
      int t = tid >> 2, hh = tid & 3;
      const float* wpd = Wpd + l * 4096 + t * 64 + hh * 16;
      const float* wpm = Wpm + l * 4096 + t * 64 + hh * 16;
      float sd = 0.f, sm = 0.f;
      #pragma unroll
      for (int hd = 0; hd < 16; ++hd) { sd += wpd[hd]; sm += wpm[hd]; }
      spd[t][hh] = sd; spm[t][hh] = sm;
    }
    __syncthreads();
    if (tid < 64) { int i = tid >> 2, hh = tid & 3;
      float a = 0.f;
      for (int k = 0; k < 64; ++k) a += W_de[i * 64 + k] * spd[k][hh];
      fold[l * 128 + i * 4 + hh] = a; }
    if (tid < 32) { int i = tid >> 2, hh = tid & 3;
      float a = 0.f;
      for (int k = 0; k < 64; ++k) a += W_m[i * 64 + k] * spm[k][hh];
      fold[l * 128 + 64 + i * 4 + hh] = a; }
    if (tid < 4) { int hh = tid;
      float a = 0.f;
      for (int k = 0; k < 64; ++k) a += b_de[k] * spd[k][hh] + b_m[k] * spm[k][hh];
      for (int hd = 0; hd < 16; ++hd)
        a += bpd[l * 64 + hh * 16 + hd] + bpm[l * 64 + hh * 16 + hd];
      fold[l * 128 + 96 + hh] = a; }
    __syncthreads();
  }
}

// ---------------- per-edge folded score, pre-scaled by log2(e), f16 out ------
__global__ __launch_bounds__(256) void escore_kernel(
    const float* __restrict__ de, const float* __restrict__ m,
    const float* __restrict__ fold, ushort* __restrict__ ep0,
    ushort* __restrict__ ep1, int E, int lay)
{
  int e = blockIdx.x * 256 + threadIdx.x;
  if (e >= E) return;
  float dv[16], mv[8];
  #pragma unroll
  for (int i = 0; i < 4; ++i)
    *(float4*)(dv + 4 * i) = ((const float4*)(de + (size_t)e * 16))[i];
  #pragma unroll
  for (int i = 0; i < 2; ++i)
    *(float4*)(mv + 4 * i) = ((const float4*)(m + (size_t)e * 8))[i];
  #pragma unroll
  for (int pass = 0; pass < 2; ++pass) {
    ushort* ep; int l;
    if (pass == 0) { ep = ep0; l = ep1 ? 0 : lay; }
    else { if (!ep1) break; ep = ep1; l = 1; }
    const float* f = fold + l * 128;
    ushort4 o;
    ushort* op = (ushort*)&o;
    #pragma unroll
    for (int hh = 0; hh < 4; ++hh) {
      float a = f[96 + hh];
      #pragma unroll
      for (int i = 0; i < 16; ++i) a += dv[i] * f[i * 4 + hh];
      #pragma unroll
      for (int i = 0; i < 8; ++i) a += mv[i] * f[64 + i * 4 + hh];
      op[hh] = f2hs(a * LOG2E);
    }
    *(ushort4*)(ep + (size_t)e * 4) = o;
  }
}

// ---------------- CSR rowptr ----------------
__global__ __launch_bounds__(256) void rowptr_kernel(
    const int* __restrict__ dst, int E, int N, int* __restrict__ rp)
{
  int n = blockIdx.x * blockDim.x + threadIdx.x;
  if (n > N) return;
  int lo = 0, hi = E;
  while (lo < hi) {
    int mid = (lo + hi) >> 1;
    if (dst[mid] < n) lo = mid + 1; else hi = mid;
  }
  rp[n] = lo;
}

// ---------------- fused hinit + qkv(layer 0); per-wave LDS, no barriers ------
__global__ __launch_bounds__(256) void hinit_qkv(
    const float* __restrict__ x, const float* __restrict__ pe,
    const short* __restrict__ wb, const float* __restrict__ b_pe,
    const float* __restrict__ bq, const float* __restrict__ bk,
    const float* __restrict__ bv, ushort* __restrict__ Hb,
    float* __restrict__ Qb, ushort* __restrict__ Kb, ushort* __restrict__ Vb,
    int N)
{
  __shared__ __align__(16) char bufc[4][4352];
  int tid = threadIdx.x, wv = tid >> 6, ln = tid & 63;
  int q = ln >> 4, p16 = ln & 15;
  int nb0 = blockIdx.x * 64;
  int arow = nb0 + wv * 16 + p16; if (arow >= N) arow = N - 1;
  ushort* bu = (ushort*)bufc[wv]; // stride-72 bf16 transpose buffer

  // ---- h = x@W_h + pe@W_pe + b_pe ----
  f4v acc[4] = {};
  for (int kt = 0; kt < 4; ++kt) {
    s8v ah, al;
    split8(x + (size_t)arow * 128 + kt * 32 + 8 * q, ah, al);
    #pragma unroll
    for (int ct = 0; ct < 4; ++ct) {
      int bo = (ct * 16 + p16) * 128 + kt * 32 + 8 * q;
      s8v bh = *(const s8v*)(wb + OFF_WH + bo);
      s8v bl = *(const s8v*)(wb + OFF_WH + 8192 + bo);
      acc[ct] = MFMA(ah, bh, acc[ct]);
      acc[ct] = MFMA(ah, bl, acc[ct]);
      acc[ct] = MFMA(al, bh, acc[ct]);
    }
  }
  {
    s8v ah = {}, al = {};
    if (q < 2) split8(pe + (size_t)arow * 16 + 8 * q, ah, al);
    #pragma unroll
    for (int ct = 0; ct < 4; ++ct) {
      int bo = (ct * 16 + p16) * 32 + 8 * q;
      s8v bh = *(const s8v*)(wb + OFF_WPE + bo);
      s8v bl = *(const s8v*)(wb + OFF_WPE + 2048 + bo);
      acc[ct] = MFMA(ah, bh, acc[ct]);
      acc[ct] = MFMA(ah, bl, acc[ct]);
      acc[ct] = MFMA(al, bh, acc[ct]);
    }
  }
  int rb = nb0 + wv * 16 + q * 4;
  #pragma unroll
  for (int ct = 0; ct < 4; ++ct) {
    int col = ct * 16 + p16;
    float bb = b_pe[col];
    #pragma unroll
    for (int j = 0; j < 4; ++j) {
      ushort hv = (ushort)f2bs(acc[ct][j] + bb);
      bu[(q * 4 + j) * 72 + col] = hv;                      // A-transpose staging
      if (rb + j < N) Hb[(size_t)(rb + j) * 64 + col] = hv; // residual for layer 0
    }
  }
  // per-wave DS in-order: reads below see the writes above
  s8v a0 = *(const s8v*)&bu[p16 * 72 + 8 * q];
  s8v a1 = *(const s8v*)&bu[p16 * 72 + 32 + 8 * q];

  // ---- qkv layer 0 ----
  f4v qa[4] = {}, ka[4] = {}, va[4] = {};
  #pragma unroll
  for (int kt = 0; kt < 2; ++kt) {
    s8v a = kt ? a1 : a0;
    #pragma unroll
    for (int ct = 0; ct < 4; ++ct) {
      int bo = (ct * 16 + p16) * 64 + kt * 32 + 8 * q;
      s8v bh, bl;
      bh = *(const s8v*)(wb + OFF_WQ + bo);
      bl = *(const s8v*)(wb + OFF_WQ + 4096 + bo);
      qa[ct] = MFMA(a, bh, qa[ct]); qa[ct] = MFMA(a, bl, qa[ct]);
      bh = *(const s8v*)(wb + OFF_WK + bo);
      bl = *(const s8v*)(wb + OFF_WK + 4096 + bo);
      ka[ct] = MFMA(a, bh, ka[ct]); ka[ct] = MFMA(a, bl, ka[ct]);
      bh = *(const s8v*)(wb + OFF_WV + bo);
      bl = *(const s8v*)(wb + OFF_WV + 4096 + bo);
      va[ct] = MFMA(a, bh, va[ct]); va[ct] = MFMA(a, bl, va[ct]);
    }
  }
  #pragma unroll
  for (int ct = 0; ct < 4; ++ct) {
    int col = ct * 16 + p16;
    float bQ = bq[col], bK = bk[col], bV = bv[col];
    #pragma unroll
    for (int j = 0; j < 4; ++j) {
      if (rb + j < N) {
        size_t o = (size_t)(rb + j) * 64 + col;
        Qb[o] = (qa[ct][j] + bQ) * QSC;
        Kb[o] = f2hs(ka[ct][j] + bK);
        Vb[o] = f2hs(va[ct][j] + bV);
      }
    }
  }
}

// ---------------- edge attention: lane = (edge_slot, head) -------------------
__global__ __launch_bounds__(256, 4) void edge_kernel(
    const float* __restrict__ Qb, const _Float16* __restrict__ Kb,
    const _Float16* __restrict__ Vb, const int* __restrict__ src,
    const int* __restrict__ rp, const _Float16* __restrict__ epsl,
    ushort* __restrict__ attnb, int N)
{
  __shared__ float red[4][16][64];
  int tid = threadIdx.x, ln = tid & 63;
  int wv = __builtin_amdgcn_readfirstlane(tid >> 6);
  int w = blockIdx.x * 4 + wv;
  bool wok = w < N;
  int wc = wok ? w : N - 1;
  int es = ln >> 2, h = ln & 3;

  float q[16];
  const float* qp = Qb + (size_t)wc * 64 + h * 16;
  #pragma unroll
  for (int i = 0; i < 4; ++i)
    *(float4*)(q + 4 * i) = ((const float4*)qp)[i];

  int e0 = rp[wc], e1 = rp[wc + 1];
  int elast = e1 - 1;
  float acc[16];
  #pragma unroll
  for (int i = 0; i < 16; ++i) acc[i] = 0.f;
  float z = 0.f;

  for (int e = e0; e < e1; e += 16) {
    int eidx = e + es;
    bool val = eidx <= elast;
    int eic = val ? eidx : elast;
    int sidx = src[eic];
    size_t ko = (size_t)sidx * 64 + h * 16;
    h8v k0 = *(const h8v*)(Kb + ko);
    h8v k1 = *(const h8v*)(Kb + ko + 8);
    h8v v0 = *(const h8v*)(Vb + ko);
    h8v v1 = *(const h8v*)(Vb + ko + 8);
    float pe_ = (float)epsl[(size_t)eic * 4 + h];
    float t0 = 0.f, t1 = 0.f;
    #pragma unroll
    for (int i = 0; i < 8; ++i) {
      t0 = fmaf((float)k0[i], q[i], t0);
      t1 = fmaf((float)k1[i], q[i + 8], t1);
    }
    float sc = fminf(fmaxf(t0 + t1 + pe_, -CLB), CLB);
    float sv = __builtin_amdgcn_exp2f(sc);
    sv = val ? sv : 0.f;
    z += sv;
    #pragma unroll
    for (int i = 0; i < 8; ++i) {
      acc[i] = fmaf(sv, (float)v0[i], acc[i]);
      acc[i + 8] = fmaf(sv, (float)v1[i], acc[i + 8]);
    }
  }

  z += __shfl_xor(z, 4, 64);
  z += __shfl_xor(z, 8, 64);
  z += __shfl_xor(z, 16, 64);
  z += __shfl_xor(z, 32, 64);

  float* rw = &red[wv][es][h * 16];
  #pragma unroll
  for (int i = 0; i < 4; ++i)
    *(float4*)(rw + i * 4) = *(const float4*)(acc + i * 4);
  __asm__ volatile("s_waitcnt lgkmcnt(0)" ::: "memory");
  int c = ln;
  float zc = __shfl(z, c >> 4, 64);
  float s = 0.f;
  #pragma unroll
  for (int es2 = 0; es2 < 16; ++es2) s += red[wv][es2][c];
  if (wok) attnb[(size_t)w * 64 + c] = (ushort)f2bs(s / (zc + 1e-10f));
}

// ---------------- fused post (+ optional qkv of next layer) ------------------
// Per-wave 16-row slice; zero __syncthreads; 4.25 KB LDS scratch per wave,
// reused sequentially for u(f32) -> h1(f32) -> t(bf16) -> h2(bf16) transposes.
template<int TAIL> // 1: also compute qkv(lay+1); 0: write Hb only
__global__ __launch_bounds__(256) void post_fused(
    ushort* __restrict__ Hb, const ushort* __restrict__ attnb,
    const float* __restrict__ I, const short* __restrict__ wb,
    const float* __restrict__ bpi, const float* __restrict__ bO,
    const float* __restrict__ g1, const float* __restrict__ b1,
    const float* __restrict__ bf1, const float* __restrict__ bf2,
    const float* __restrict__ g2, const float* __restrict__ b2,
    const float* __restrict__ bq, const float* __restrict__ bk,
    const float* __restrict__ bv, float* __restrict__ Qb,
    ushort* __restrict__ Kb, ushort* __restrict__ Vb, int N, int lay)
{
  constexpr float BN_S = 0.9999950000374997f;
  __shared__ __align__(16) char bufc[4][4352];
  int tid = threadIdx.x, wv = tid >> 6, ln = tid & 63;
  int q = ln >> 4, p16 = ln & 15;
  int nb0 = blockIdx.x * 64;
  int wbase = lay * PL;
  int rb = nb0 + wv * 16 + q * 4;
  int r_[4];
  #pragma unroll
  for (int j = 0; j < 4; ++j) { int rr = rb + j; r_[j] = (rr < N) ? rr : N - 1; }

  // C-layout loads of residual h and attn (imm-offset scalar loads, L2-hot)
  float hC[4][4], aC[4][4];
  #pragma unroll
  for (int j = 0; j < 4; ++j) {
    const ushort* hp = Hb + (size_t)r_[j] * 64 + p16;
    const ushort* ap = attnb + (size_t)r_[j] * 64 + p16;
    #pragma unroll
    for (int ct = 0; ct < 4; ++ct) {
      hC[ct][j] = bs2f((short)hp[ct * 16]);
      aC[ct][j] = bs2f((short)ap[ct * 16]);
    }
  }
  int arow = nb0 + wv * 16 + p16; if (arow >= N) arow = N - 1;

  // ---- u = I@Wpi + bpi + attn ----
  f4v uacc[4] = {};
  {
    s8v ah = {}, al = {};
    if (q < 2) split8(I + (size_t)arow * 16 + 8 * q, ah, al);
    #pragma unroll
    for (int ct = 0; ct < 4; ++ct) {
      int bo = (ct * 16 + p16) * 32 + 8 * q;
      s8v bh = *(const s8v*)(wb + wbase + OFF_WPI + bo);
      s8v bl = *(const s8v*)(wb + wbase + OFF_WPI + 2048 + bo);
      uacc[ct] = MFMA(ah, bh, uacc[ct]);
      uacc[ct] = MFMA(ah, bl, uacc[ct]);
      uacc[ct] = MFMA(al, bh, uacc[ct]);
    }
  }
  float* bf = (float*)bufc[wv]; // stride-68 f32 view
  #pragma unroll
  for (int ct = 0; ct < 4; ++ct) {
    int col = ct * 16 + p16;
    float bb = bpi[lay * 64 + col];
    #pragma unroll
    for (int j = 0; j < 4; ++j)
      bf[(q * 4 + j) * 68 + col] = uacc[ct][j] + bb + aC[ct][j];
  }
  // ---- v = u@WO + bO ; hw = h + v ; LN1 -> h1 ----
  f4v vacc[4] = {};
  #pragma unroll
  for (int kt = 0; kt < 2; ++kt) {
    s8v ah, al;
    split8(&bf[p16 * 68 + kt * 32 + 8 * q], ah, al);
    #pragma unroll
    for (int ct = 0; ct < 4; ++ct) {
      int bo = (ct * 16 + p16) * 64 + kt * 32 + 8 * q;
      s8v bh = *(const s8v*)(wb + wbase + OFF_WO + bo);
      s8v bl = *(const s8v*)(wb + wbase + OFF_WO + 4096 + bo);
      vacc[ct] = MFMA(ah, bh, vacc[ct]);
      vacc[ct] = MFMA(ah, bl, vacc[ct]);
      vacc[ct] = MFMA(al, bh, vacc[ct]);
    }
  }
  float hw[4][4];
  #pragma unroll
  for (int ct = 0; ct < 4; ++ct) {
    int col = ct * 16 + p16;
    float bb = bO[lay * 64 + col];
    #pragma unroll
    for (int j = 0; j < 4; ++j)
      hw[ct][j] = hC[ct][j] + vacc[ct][j] + bb;
  }
  float h1r[4][4];
  {
    float s0[4], mu[4], vv[4], rs[4];
    #pragma unroll
    for (int j = 0; j < 4; ++j) s0[j] = hw[0][j] + hw[1][j] + hw[2][j] + hw[3][j];
    #pragma unroll
    for (int msk = 1; msk < 16; msk <<= 1)
      #pragma unroll
      for (int j = 0; j < 4; ++j) s0[j] += __shfl_xor(s0[j], msk, 64);
    #pragma unroll
    for (int j = 0; j < 4; ++j) { mu[j] = s0[j] * (1.f / 64.f); vv[j] = 0.f; }
    #pragma unroll
    for (int ct = 0; ct < 4; ++ct)
      #pragma unroll
      for (int j = 0; j < 4; ++j) { float d = hw[ct][j] - mu[j]; hw[ct][j] = d; vv[j] += d * d; }
    #pragma unroll
    for (int msk = 1; msk < 16; msk <<= 1)
      #pragma unroll
      for (int j = 0; j < 4; ++j) vv[j] += __shfl_xor(vv[j], msk, 64);
    #pragma unroll
    for (int j = 0; j < 4; ++j) rs[j] = 1.f / sqrtf(vv[j] * (1.f / 64.f) + 1e-5f);
    #pragma unroll
    for (int ct = 0; ct < 4; ++ct) {
      int col = ct * 16 + p16;
      float gg = g1[lay * 64 + col], bb = b1[lay * 64 + col];
      #pragma unroll
      for (int j = 0; j < 4; ++j)
        h1r[ct][j] = (hw[ct][j] * rs[j] * gg + bb) * BN_S;
    }
  }
  // ---- h1 -> LDS; t = relu(h1@Wf1 + bf1) ----
  #pragma unroll
  for (int ct = 0; ct < 4; ++ct)
    #pragma unroll
    for (int j = 0; j < 4; ++j)
      bf[(q * 4 + j) * 68 + ct * 16 + p16] = h1r[ct][j];
  f4v tacc[8] = {};
  #pragma unroll
  for (int kt = 0; kt < 2; ++kt) {
    s8v ah, al;
    split8(&bf[p16 * 68 + kt * 32 + 8 * q], ah, al);
    #pragma unroll
    for (int ct = 0; ct < 8; ++ct) {
      int bo = (ct * 16 + p16) * 64 + kt * 32 + 8 * q;
      s8v bh = *(const s8v*)(wb + wbase + OFF_WF1 + bo);
      s8v bl = *(const s8v*)(wb + wbase + OFF_WF1 + 8192 + bo);
      tacc[ct] = MFMA(ah, bh, tacc[ct]);
      tacc[ct] = MFMA(ah, bl, tacc[ct]);
      tacc[ct] = MFMA(al, bh, tacc[ct]);
    }
  }
  ushort* bu = (ushort*)bufc[wv]; // stride-136 bf16 view for t
  #pragma unroll
  for (int ct = 0; ct < 8; ++ct) {
    int col = ct * 16 + p16;
    float bb = bf1[lay * 128 + col];
    #pragma unroll
    for (int j = 0; j < 4; ++j)
      bu[(q * 4 + j) * 136 + col] = (ushort)f2bs(fmaxf(tacc[ct][j] + bb, 0.f));
  }
  // ---- y = t@Wf2 + bf2 ; w2 = h1 + y ; LN2 -> h2 ----
  f4v yacc[4] = {};
  #pragma unroll
  for (int kt = 0; kt < 4; ++kt) {
    s8v at = *(const s8v*)&bu[p16 * 136 + kt * 32 + 8 * q];
    #pragma unroll
    for (int ct = 0; ct < 4; ++ct) {
      int bo = (ct * 16 + p16) * 128 + kt * 32 + 8 * q;
      s8v bh = *(const s8v*)(wb + wbase + OFF_WF2 + bo);
      s8v bl = *(const s8v*)(wb + wbase + OFF_WF2 + 8192 + bo);
      yacc[ct] = MFMA(at, bh, yacc[ct]);
      yacc[ct] = MFMA(at, bl, yacc[ct]);
    }
  }
  float w2[4][4];
  #pragma unroll
  for (int ct = 0; ct < 4; ++ct) {
    int col = ct * 16 + p16;
    float bb = bf2[lay * 64 + col];
    #pragma unroll
    for (int j = 0; j < 4; ++j)
      w2[ct][j] = h1r[ct][j] + yacc[ct][j] + bb;
  }
  ushort h2b[4][4];
  {
    float s0[4], mu[4], vv[4], rs[4];
    #pragma unroll
    for (int j = 0; j < 4; ++j) s0[j] = w2[0][j] + w2[1][j] + w2[2][j] + w2[3][j];
    #pragma unroll
    for (int msk = 1; msk < 16; msk <<= 1)
      #pragma unroll
      for (int j = 0; j < 4; ++j) s0[j] += __shfl_xor(s0[j], msk, 64);
    #pragma unroll
    for (int j = 0; j < 4; ++j) { mu[j] = s0[j] * (1.f / 64.f); vv[j] = 0.f; }
    #pragma unroll
    for (int ct = 0; ct < 4; ++ct)
      #pragma unroll
      for (int j = 0; j < 4; ++j) { float d = w2[ct][j] - mu[j]; w2[ct][j] = d; vv[j] += d * d; }
    #pragma unroll
    for (int msk = 1; msk < 16; msk <<= 1)
      #pragma unroll
      for (int j = 0; j < 4; ++j) vv[j] += __shfl_xor(vv[j], msk, 64);
    #pragma unroll
    for (int j = 0; j < 4; ++j) rs[j] = 1.f / sqrtf(vv[j] * (1.f / 64.f) + 1e-5f);
    #pragma unroll
    for (int ct = 0; ct < 4; ++ct) {
      int col = ct * 16 + p16;
      float gg = g2[lay * 64 + col], bb = b2[lay * 64 + col];
      #pragma unroll
      for (int j = 0; j < 4; ++j)
        h2b[ct][j] = (ushort)f2bs((w2[ct][j] * rs[j] * gg + bb) * BN_S);
    }
  }
  // ---- store h2 -> Hb ----
  #pragma unroll
  for (int ct = 0; ct < 4; ++ct) {
    int col = ct * 16 + p16;
    #pragma unroll
    for (int j = 0; j < 4; ++j)
      if (rb + j < N) Hb[(size_t)(rb + j) * 64 + col] = h2b[ct][j];
  }
  if (TAIL) {
    // ---- qkv(lay+1): h2 -> LDS transpose -> A-frags -> MFMAs -> stores ----
    #pragma unroll
    for (int ct = 0; ct < 4; ++ct)
      #pragma unroll
      for (int j = 0; j < 4; ++j)
        bu[(q * 4 + j) * 72 + ct * 16 + p16] = h2b[ct][j];
    s8v a0 = *(const s8v*)&bu[p16 * 72 + 8 * q];
    s8v a1 = *(const s8v*)&bu[p16 * 72 + 32 + 8 * q];
    int wb2 = (lay + 1) * PL;
    f4v qa[4] = {}, ka[4] = {}, va[4] = {};
    #pragma unroll
    for (int kt = 0; kt < 2; ++kt) {
      s8v a = kt ? a1 : a0;
      #pragma unroll
      for (int ct = 0; ct < 4; ++ct) {
        int bo = (ct * 16 + p16) * 64 + kt * 32 + 8 * q;
        s8v bh, bl;
        bh = *(const s8v*)(wb + wb2 + OFF_WQ + bo);
        bl = *(const s8v*)(wb + wb2 + OFF_WQ + 4096 + bo);
        qa[ct] = MFMA(a, bh, qa[ct]); qa[ct] = MFMA(a, bl, qa[ct]);
        bh = *(const s8v*)(wb + wb2 + OFF_WK + bo);
        bl = *(const s8v*)(wb + wb2 + OFF_WK + 4096 + bo);
        ka[ct] = MFMA(a, bh, ka[ct]); ka[ct] = MFMA(a, bl, ka[ct]);
        bh = *(const s8v*)(wb + wb2 + OFF_WV + bo);
        bl = *(const s8v*)(wb + wb2 + OFF_WV + 4096 + bo);
        va[ct] = MFMA(a, bh, va[ct]); va[ct] = MFMA(a, bl, va[ct]);
      }
    }
    #pragma unroll
    for (int ct = 0; ct < 4; ++ct) {
      int col = ct * 16 + p16;
      float bQ = bq[(lay + 1) * 64 + col];
      float bK = bk[(lay + 1) * 64 + col];
      float bV = bv[(lay + 1) * 64 + col];
      #pragma unroll
      for (int j = 0; j < 4; ++j) {
        if (rb + j < N) {
          size_t o = (size_t)(rb + j) * 64 + col;
          Qb[o] = (qa[ct][j] + bQ) * QSC;
          Kb[o] = f2hs(ka[ct][j] + bK);
          Vb[o] = f2hs(va[ct][j] + bV);
        }
      }
    }
  }
}

// ---------------- readout: out0 = h ; x_hat = selu(h@Wr1+br1)@Wr2+br2 --------
__global__ __launch_bounds__(256) void readout_f(
    const ushort* __restrict__ Hb, const short* __restrict__ wb,
    const float* __restrict__ br1, const float* __restrict__ br2,
    float* __restrict__ out, int N)
{
  __shared__ __align__(16) char bufc[4][4352];
  int tid = threadIdx.x, wv = tid >> 6, ln = tid & 63;
  int q = ln >> 4, p16 = ln & 15;
  int nb0 = blockIdx.x * 64;
  int rb = nb0 + wv * 16 + q * 4;
  int r_[4];
  #pragma unroll
  for (int j = 0; j < 4; ++j) { int rr = rb + j; r_[j] = (rr < N) ? rr : N - 1; }

  ushort hC[4][4];
  #pragma unroll
  for (int j = 0; j < 4; ++j) {
    const ushort* hp = Hb + (size_t)r_[j] * 64 + p16;
    #pragma unroll
    for (int ct = 0; ct < 4; ++ct) hC[ct][j] = hp[ct * 16];
  }
  // h out (fp32)
  #pragma unroll
  for (int ct = 0; ct < 4; ++ct) {
    int col = ct * 16 + p16;
    #pragma unroll
    for (int j = 0; j < 4; ++j)
      if (rb + j < N) out[(size_t)(rb + j) * 64 + col] = bs2f((short)hC[ct][j]);
  }
  // h -> LDS transpose for Wr1 A-side
  ushort* bu = (ushort*)bufc[wv];
  #pragma unroll
  for (int ct = 0; ct < 4; ++ct)
    #pragma unroll
    for (int j = 0; j < 4; ++j)
      bu[(q * 4 + j) * 72 + ct * 16 + p16] = hC[ct][j];
  s8v a0 = *(const s8v*)&bu[p16 * 72 + 8 * q];
  s8v a1 = *(const s8v*)&bu[p16 * 72 + 32 + 8 * q];
  // md = selu(h@Wr1 + br1)
  f4v macc = {};
  #pragma unroll
  for (int kt = 0; kt < 2; ++kt) {
    s8v a = kt ? a1 : a0;
    int bo = p16 * 64 + kt * 32 + 8 * q;
    s8v bh = *(const s8v*)(wb + OFF_WR1 + bo);
    s8v bl = *(const s8v*)(wb + OFF_WR1 + 1024 + bo);
    macc = MFMA(a, bh, macc);
    macc = MFMA(a, bl, macc);
  }
  const float SC = 1.0507009873554805f, AL = 1.6732632423543772f;
  float* bf = (float*)bufc[wv]; // stride-24 f32 view for md
  #pragma unroll
  for (int j = 0; j < 4; ++j) {
    float md = macc[j] + br1[p16];
    md = (md > 0.f) ? SC * md : SC * AL * expm1f(md);
    bf[(q * 4 + j) * 24 + p16] = md;
  }
  s8v ah = {}, al = {};
  if (q < 2) split8(&bf[p16 * 24 + 8 * q], ah, al);
  f4v xacc[8] = {};
  #pragma unroll
  for (int ct = 0; ct < 8; ++ct) {
    int bo = (ct * 16 + p16) * 32 + 8 * q;
    s8v bh = *(const s8v*)(wb + OFF_WR2 + bo);
    s8v bl = *(const s8v*)(wb + OFF_WR2 + 4096 + bo);
    xacc[ct] = MFMA(ah, bh, xacc[ct]);
    xacc[ct] = MFMA(ah, bl, xacc[ct]);
    xacc[ct] = MFMA(al, bh, xacc[ct]);
  }
  #pragma unroll
  for (int ct = 0; ct < 8; ++ct) {
    int col = ct * 16 + p16;
    float bb = br2[col];
    #pragma unroll
    for (int j = 0; j < 4; ++j)
      if (rb + j < N)
        out[(size_t)N * 64 + (size_t)(rb + j) * 128 + col] = xacc[ct][j] + bb;
  }
}

extern "C" void kernel_launch(void* const* d_in, const int* in_sizes, int n_in,
                              void* d_out, int out_size, void* d_ws, size_t ws_size,
                              hipStream_t stream)
{
  const int* src    = (const int*)d_in[0];
  const int* dst    = (const int*)d_in[1];
  const float* x    = (const float*)d_in[2];
  const float* pe   = (const float*)d_in[3];
  const float* de   = (const float*)d_in[4];
  const float* m    = (const float*)d_in[5];
  const float* I    = (const float*)d_in[6];
  const float* W_h  = (const float*)d_in[7];
  const float* W_pe = (const float*)d_in[8];
  const float* b_pe = (const float*)d_in[9];
  const float* W_de = (const float*)d_in[10];
  const float* b_de = (const float*)d_in[11];
  const float* W_m  = (const float*)d_in[12];
  const float* b_m  = (const float*)d_in[13];
  const float* Wq   = (const float*)d_in[14];
  const float* bq   = (const float*)d_in[15];
  const float* Wk   = (const float*)d_in[16];
  const float* bk   = (const float*)d_in[17];
  const float* Wv   = (const float*)d_in[18];
  const float* bv   = (const float*)d_in[19];
  const float* Wpd  = (const float*)d_in[20];
  const float* bpd  = (const float*)d_in[21];
  const float* Wpm  = (const float*)d_in[22];
  const float* bpm  = (const float*)d_in[23];
  const float* WO   = (const float*)d_in[24];
  const float* bO   = (const float*)d_in[25];
  const float* Wpi  = (const float*)d_in[26];
  const float* bpi  = (const float*)d_in[27];
  const float* g1   = (const float*)d_in[28];
  const float* b1   = (const float*)d_in[29];
  const float* g2   = (const float*)d_in[30];
  const float* b2   = (const float*)d_in[31];
  const float* Wf1  = (const float*)d_in[32];
  const float* bf1  = (const float*)d_in[33];
  const float* Wf2  = (const float*)d_in[34];
  const float* bf2  = (const float*)d_in[35];
  const float* Wr1  = (const float*)d_in[36];
  const float* br1  = (const float*)d_in[37];
  const float* Wr2  = (const float*)d_in[38];
  const float* br2  = (const float*)d_in[39];

  const int E = in_sizes[0];
  const int N = in_sizes[2] / 128;

  // ws: rowptr | fold | split-weights | H (bf16) | [eps both layers]
  char* ws = (char*)d_ws;
  int* row_ptr = (int*)ws;
  size_t rp_bytes = (((size_t)(N + 1) * 4) + 255) & ~(size_t)255;
  float* fold = (float*)(ws + rp_bytes);
  short* wb = (short*)(ws + rp_bytes + 1024);
  ushort* Hb = (ushort*)(ws + rp_bytes + 1024 + (size_t)WBF_TOT * 2);
  size_t ws_used = rp_bytes + 1024 + (size_t)WBF_TOT * 2 + (size_t)N * 128;

  // d_out doubles as scratch until readout rewrites every byte:
  // K f16 [0,128N) | V f16 [128N,256N) | Q f32 [256N,512N) | attn bf16 [512N,640N)
  // | eps fallback f16 [640N, 640N+8E)  (fits iff E <= 16N, true here)
  float* out = (float*)d_out;
  ushort* Kb = (ushort*)out;
  ushort* Vb = Kb + (size_t)N * 64;
  float* Qb = out + (size_t)N * 64;
  ushort* attnb = (ushort*)((char*)d_out + (size_t)N * 512);

  bool both_eps = ws_size >= ws_used + (size_t)E * 16;
  ushort *eps0, *eps1 = nullptr;
  if (both_eps) {
    eps0 = (ushort*)(ws + ws_used);
    eps1 = eps0 + (size_t)E * 4;
  } else {
    eps0 = (ushort*)((char*)d_out + (size_t)N * 640);
  }

  int nb64 = (N + 63) / 64;

  prep_kernel<<<dim3(32, 18), 256, 0, stream>>>(Wq, Wk, Wv, WO, Wf1, Wf2, Wpi,
                                                W_h, W_pe, Wr1, Wr2, wb);
  fold_kernel<<<1, 256, 0, stream>>>(W_de, b_de, W_m, b_m, Wpd, bpd, Wpm, bpm, fold);
  rowptr_kernel<<<(N + 256) / 256, 256, 0, stream>>>(dst, E, N, row_ptr);
  if (both_eps)
    escore_kernel<<<(E + 255) / 256, 256, 0, stream>>>(de, m, fold, eps0, eps1, E, 0);

  hinit_qkv<<<nb64, 256, 0, stream>>>(x, pe, wb, b_pe, bq, bk, bv, Hb, Qb, Kb, Vb, N);

  for (int lay = 0; lay < 2; ++lay) {
    if (!both_eps)
      escore_kernel<<<(E + 255) / 256, 256, 0, stream>>>(de, m, fold, eps0, nullptr, E, lay);
    edge_kernel<<<(N + 3) / 4, 256, 0, stream>>>(Qb, (const _Float16*)Kb,
        (const _Float16*)Vb, src, row_ptr,
        (const _Float16*)((both_eps && lay) ? eps1 : eps0), attnb, N);
    if (lay == 0)
      post_fused<1><<<nb64, 256, 0, stream>>>(Hb, attnb, I, wb, bpi, bO, g1, b1,
          bf1, bf2, g2, b2, bq, bk, bv, Qb, Kb, Vb, N, 0);
    else
      post_fused<0><<<nb64, 256, 0, stream>>>(Hb, attnb, I, wb, bpi, bO, g1, b1,
          bf1, bf2, g2, b2, bq, bk, bv, Qb, Kb, Vb, N, 1);
  }
  readout_f<<<nb64, 256, 0, stream>>>(Hb, wb, br1, br2, out, N);
}

// Round 6
// 475.460 us; speedup vs baseline: 2.1469x; 1.0273x over previous
//
#include <hip/hip_runtime.h>
#include <hip/hip_bf16.h>

typedef __hip_bfloat16 bf16;
typedef __attribute__((ext_vector_type(8))) short s8v;
typedef __attribute__((ext_vector_type(4))) float f4v;
typedef __attribute__((ext_vector_type(8))) _Float16 h8v;
#define DEV __device__ __forceinline__
#define MFMA(a, b, c) __builtin_amdgcn_mfma_f32_16x16x32_bf16(a, b, c, 0, 0, 0)

// split-bf16 weight table offsets (elements); each section: [hi sz][lo sz]
constexpr int OFF_WQ = 0, OFF_WK = 8192, OFF_WV = 16384, OFF_WO = 24576;
constexpr int OFF_WF1 = 32768, OFF_WF2 = 49152, OFF_WPI = 65536;
constexpr int PL = 69632; // per-layer stride
constexpr int OFF_WH = 139264, OFF_WPE = 155648, OFF_WR1 = 159744, OFF_WR2 = 161792;
constexpr int WBF_TOT = 169984;

constexpr float LOG2E = 1.4426950408889634f;
constexpr float QSC = 4.f * LOG2E;         // folds 16*SCALE and log2(e) into Q
constexpr float CLB = 5.f * LOG2E;         // clamp bound in log2 domain

// LDS scratch strides chosen for <=2-way bank aliasing on the read patterns:
constexpr int SF = 65;   // f32 view (u, h1): scalar reads bank=(p16+8q+j)%32
constexpr int ST = 152;  // ushort t view: b128 reads, 304B rows -> 12*p16%32
constexpr int SB = 88;   // ushort transpose view: b128 reads, 176B rows

DEV short f2bs(float f) { union { bf16 b; short s; } u; u.b = __float2bfloat16(f); return u.s; }
DEV float bs2f(short s) { union { bf16 b; short s2; } u; u.s2 = s; return __bfloat162float(u.b); }
DEV ushort f2hs(float f) { union { _Float16 h; ushort u; } x; x.h = (_Float16)f; return x.u; }

DEV void split8(const float* p, s8v& hi, s8v& lo) {
  #pragma unroll
  for (int j = 0; j < 8; ++j) {
    float f = p[j];
    short h = f2bs(f);
    hi[j] = h;
    lo[j] = f2bs(f - bs2f(h));
  }
}

// ---------------- weight prep: transpose + split to bf16 hi/lo ----------------
__global__ __launch_bounds__(256) void prep_kernel(
    const float* __restrict__ Wq, const float* __restrict__ Wk,
    const float* __restrict__ Wv, const float* __restrict__ WO,
    const float* __restrict__ Wf1, const float* __restrict__ Wf2,
    const float* __restrict__ Wpi, const float* __restrict__ W_h,
    const float* __restrict__ W_pe, const float* __restrict__ Wr1,
    const float* __restrict__ Wr2, short* __restrict__ wb)
{
  const float* sp; int K, ksh, Nc, d0;
  switch (blockIdx.y) {
    case 0:  sp = Wq;         K = 64;  ksh = 6; Nc = 64;  d0 = OFF_WQ;       break;
    case 1:  sp = Wk;         K = 64;  ksh = 6; Nc = 64;  d0 = OFF_WK;       break;
    case 2:  sp = Wv;         K = 64;  ksh = 6; Nc = 64;  d0 = OFF_WV;       break;
    case 3:  sp = WO;         K = 64;  ksh = 6; Nc = 64;  d0 = OFF_WO;       break;
    case 4:  sp = Wf1;        K = 64;  ksh = 6; Nc = 128; d0 = OFF_WF1;      break;
    case 5:  sp = Wf2;        K = 128; ksh = 7; Nc = 64;  d0 = OFF_WF2;      break;
    case 6:  sp = Wpi;        K = 16;  ksh = 5; Nc = 64;  d0 = OFF_WPI;      break;
    case 7:  sp = Wq + 4096;  K = 64;  ksh = 6; Nc = 64;  d0 = PL + OFF_WQ;  break;
    case 8:  sp = Wk + 4096;  K = 64;  ksh = 6; Nc = 64;  d0 = PL + OFF_WK;  break;
    case 9:  sp = Wv + 4096;  K = 64;  ksh = 6; Nc = 64;  d0 = PL + OFF_WV;  break;
    case 10: sp = WO + 4096;  K = 64;  ksh = 6; Nc = 64;  d0 = PL + OFF_WO;  break;
    case 11: sp = Wf1 + 8192; K = 64;  ksh = 6; Nc = 128; d0 = PL + OFF_WF1; break;
    case 12: sp = Wf2 + 8192; K = 128; ksh = 7; Nc = 64;  d0 = PL + OFF_WF2; break;
    case 13: sp = Wpi + 1024; K = 16;  ksh = 5; Nc = 64;  d0 = PL + OFF_WPI; break;
    case 14: sp = W_h;        K = 128; ksh = 7; Nc = 64;  d0 = OFF_WH;       break;
    case 15: sp = W_pe;       K = 16;  ksh = 5; Nc = 64;  d0 = OFF_WPE;      break;
    case 16: sp = Wr1;        K = 64;  ksh = 6; Nc = 16;  d0 = OFF_WR1;      break;
    default: sp = Wr2;        K = 16;  ksh = 5; Nc = 128; d0 = OFF_WR2;      break;
  }
  int Kp = 1 << ksh;
  int tot = Kp * Nc;
  int i = blockIdx.x * 256 + threadIdx.x;
  if (i >= tot) return;
  int o = i >> ksh, kk = i & (Kp - 1);
  float v = (kk < K) ? sp[kk * Nc + o] : 0.f; // dst[o][kk] = src[kk][o], zero-pad K
  short h = f2bs(v);
  wb[d0 + i] = h;
  wb[d0 + tot + i] = f2bs(v - bs2f(h));
}

// ---------------- fold de/m through per-head column sums ----------------
__global__ __launch_bounds__(256) void fold_kernel(
    const float* __restrict__ W_de, const float* __restrict__ b_de,
    const float* __restrict__ W_m,  const float* __restrict__ b_m,
    const float* __restrict__ Wpd,  const float* __restrict__ bpd,
    const float* __restrict__ Wpm,  const float* __restrict__ bpm,
    float* __restrict__ fold)
{
  __shared__ float spd[64][4], spm[64][4];
  int tid = threadIdx.x;
  for (int l = 0; l < 2; ++l) {
    {
      int t = tid >> 2, hh = tid & 3;
      const float* wpd = Wpd + l * 4096 + t * 64 + hh * 16;
      const float* wpm = Wpm + l * 4096 + t * 64 + hh * 16;
      float sd = 0.f, sm = 0.f;
      #pragma unroll
      for (int hd = 0; hd < 16; ++hd) { sd += wpd[hd]; sm += wpm[hd]; }
      spd[t][hh] = sd; spm[t][hh] = sm;
    }
    __syncthreads();
    if (tid < 64) { int i = tid >> 2, hh = tid & 3;
      float a = 0.f;
      for (int k = 0; k < 64; ++k) a += W_de[i * 64 + k] * spd[k][hh];
      fold[l * 128 + i * 4 + hh] = a; }
    if (tid < 32) { int i = tid >> 2, hh = tid & 3;
      float a = 0.f;
      for (int k = 0; k < 64; ++k) a += W_m[i * 64 + k] * spm[k][hh];
      fold[l * 128 + 64 + i * 4 + hh] = a; }
    if (tid < 4) { int hh = tid;
      float a = 0.f;
      for (int k = 0; k < 64; ++k) a += b_de[k] * spd[k][hh] + b_m[k] * spm[k][hh];
      for (int hd = 0; hd < 16; ++hd)
        a += bpd[l * 64 + hh * 16 + hd] + bpm[l * 64 + hh * 16 + hd];
      fold[l * 128 + 96 + hh] = a; }
    __syncthreads();
  }
}

// ---------------- per-edge folded score, pre-scaled by log2(e), f16 out ------
__global__ __launch_bounds__(256) void escore_kernel(
    const float* __restrict__ de, const float* __restrict__ m,
    const float* __restrict__ fold, ushort* __restrict__ ep0,
    ushort* __restrict__ ep1, int E, int lay)
{
  int e = blockIdx.x * 256 + threadIdx.x;
  if (e >= E) return;
  float dv[16], mv[8];
  #pragma unroll
  for (int i = 0; i < 4; ++i)
    *(float4*)(dv + 4 * i) = ((const float4*)(de + (size_t)e * 16))[i];
  #pragma unroll
  for (int i = 0; i < 2; ++i)
    *(float4*)(mv + 4 * i) = ((const float4*)(m + (size_t)e * 8))[i];
  #pragma unroll
  for (int pass = 0; pass < 2; ++pass) {
    ushort* ep; int l;
    if (pass == 0) { ep = ep0; l = ep1 ? 0 : lay; }
    else { if (!ep1) break; ep = ep1; l = 1; }
    const float* f = fold + l * 128;
    ushort4 o;
    ushort* op = (ushort*)&o;
    #pragma unroll
    for (int hh = 0; hh < 4; ++hh) {
      float a = f[96 + hh];
      #pragma unroll
      for (int i = 0; i < 16; ++i) a += dv[i] * f[i * 4 + hh];
      #pragma unroll
      for (int i = 0; i < 8; ++i) a += mv[i] * f[64 + i * 4 + hh];
      op[hh] = f2hs(a * LOG2E);
    }
    *(ushort4*)(ep + (size_t)e * 4) = o;
  }
}

// ---------------- CSR rowptr ----------------
__global__ __launch_bounds__(256) void rowptr_kernel(
    const int* __restrict__ dst, int E, int N, int* __restrict__ rp)
{
  int n = blockIdx.x * blockDim.x + threadIdx.x;
  if (n > N) return;
  int lo = 0, hi = E;
  while (lo < hi) {
    int mid = (lo + hi) >> 1;
    if (dst[mid] < n) lo = mid + 1; else hi = mid;
  }
  rp[n] = lo;
}

// ---------------- fused hinit + qkv(layer 0); per-wave LDS, no barriers ------
__global__ __launch_bounds__(256, 3) void hinit_qkv(
    const float* __restrict__ x, const float* __restrict__ pe,
    const short* __restrict__ wb, const float* __restrict__ b_pe,
    const float* __restrict__ bq, const float* __restrict__ bk,
    const float* __restrict__ bv, ushort* __restrict__ Hb,
    float* __restrict__ Qb, ushort* __restrict__ Kb, ushort* __restrict__ Vb,
    int N)
{
  __shared__ __align__(16) char bufc[4][2816];
  int tid = threadIdx.x, wv = tid >> 6, ln = tid & 63;
  int q = ln >> 4, p16 = ln & 15;
  int nb0 = blockIdx.x * 64;
  int arow = nb0 + wv * 16 + p16; if (arow >= N) arow = N - 1;
  ushort* bu = (ushort*)bufc[wv];

  // ---- h = x@W_h + pe@W_pe + b_pe ----
  f4v acc[4] = {};
  #pragma unroll
  for (int kt = 0; kt < 4; ++kt) {
    // batch weight frags first (prefetch), then A split, then MFMAs
    s8v whh[4], whl[4];
    #pragma unroll
    for (int ct = 0; ct < 4; ++ct) {
      int bo = (ct * 16 + p16) * 128 + kt * 32 + 8 * q;
      whh[ct] = *(const s8v*)(wb + OFF_WH + bo);
      whl[ct] = *(const s8v*)(wb + OFF_WH + 8192 + bo);
    }
    s8v ah, al;
    split8(x + (size_t)arow * 128 + kt * 32 + 8 * q, ah, al);
    #pragma unroll
    for (int ct = 0; ct < 4; ++ct) {
      acc[ct] = MFMA(ah, whh[ct], acc[ct]);
      acc[ct] = MFMA(ah, whl[ct], acc[ct]);
      acc[ct] = MFMA(al, whh[ct], acc[ct]);
    }
  }
  {
    s8v pih[4], pil[4];
    #pragma unroll
    for (int ct = 0; ct < 4; ++ct) {
      int bo = (ct * 16 + p16) * 32 + 8 * q;
      pih[ct] = *(const s8v*)(wb + OFF_WPE + bo);
      pil[ct] = *(const s8v*)(wb + OFF_WPE + 2048 + bo);
    }
    s8v ah = {}, al = {};
    if (q < 2) split8(pe + (size_t)arow * 16 + 8 * q, ah, al);
    #pragma unroll
    for (int ct = 0; ct < 4; ++ct) {
      acc[ct] = MFMA(ah, pih[ct], acc[ct]);
      acc[ct] = MFMA(ah, pil[ct], acc[ct]);
      acc[ct] = MFMA(al, pih[ct], acc[ct]);
    }
  }
  int rb = nb0 + wv * 16 + q * 4;
  #pragma unroll
  for (int ct = 0; ct < 4; ++ct) {
    int col = ct * 16 + p16;
    float bb = b_pe[col];
    #pragma unroll
    for (int j = 0; j < 4; ++j) {
      ushort hv = (ushort)f2bs(acc[ct][j] + bb);
      bu[(q * 4 + j) * SB + col] = hv;                      // A-transpose staging
      if (rb + j < N) Hb[(size_t)(rb + j) * 64 + col] = hv; // residual for layer 0
    }
  }
  // per-wave DS in-order: reads below see the writes above
  s8v a0 = *(const s8v*)&bu[p16 * SB + 8 * q];
  s8v a1 = *(const s8v*)&bu[p16 * SB + 32 + 8 * q];

  // ---- qkv layer 0 (batched frag loads per ct-pair) ----
  f4v qa[4] = {}, ka[4] = {}, va[4] = {};
  #pragma unroll
  for (int kt = 0; kt < 2; ++kt) {
    s8v a = kt ? a1 : a0;
    #pragma unroll
    for (int c2 = 0; c2 < 2; ++c2) {
      s8v qh[2], ql[2], kh[2], kl[2], vh[2], vl[2];
      #pragma unroll
      for (int u2 = 0; u2 < 2; ++u2) {
        int ct = c2 * 2 + u2;
        int bo = (ct * 16 + p16) * 64 + kt * 32 + 8 * q;
        qh[u2] = *(const s8v*)(wb + OFF_WQ + bo);
        ql[u2] = *(const s8v*)(wb + OFF_WQ + 4096 + bo);
        kh[u2] = *(const s8v*)(wb + OFF_WK + bo);
        kl[u2] = *(const s8v*)(wb + OFF_WK + 4096 + bo);
        vh[u2] = *(const s8v*)(wb + OFF_WV + bo);
        vl[u2] = *(const s8v*)(wb + OFF_WV + 4096 + bo);
      }
      #pragma unroll
      for (int u2 = 0; u2 < 2; ++u2) {
        int ct = c2 * 2 + u2;
        qa[ct] = MFMA(a, qh[u2], qa[ct]); qa[ct] = MFMA(a, ql[u2], qa[ct]);
        ka[ct] = MFMA(a, kh[u2], ka[ct]); ka[ct] = MFMA(a, kl[u2], ka[ct]);
        va[ct] = MFMA(a, vh[u2], va[ct]); va[ct] = MFMA(a, vl[u2], va[ct]);
      }
    }
  }
  #pragma unroll
  for (int ct = 0; ct < 4; ++ct) {
    int col = ct * 16 + p16;
    float bQ = bq[col], bK = bk[col], bV = bv[col];
    #pragma unroll
    for (int j = 0; j < 4; ++j) {
      if (rb + j < N) {
        size_t o = (size_t)(rb + j) * 64 + col;
        Qb[o] = (qa[ct][j] + bQ) * QSC;
        Kb[o] = f2hs(ka[ct][j] + bK);
        Vb[o] = f2hs(va[ct][j] + bV);
      }
    }
  }
}

// ---------------- edge attention: lane = (edge_slot, head) -------------------
__global__ __launch_bounds__(256, 4) void edge_kernel(
    const float* __restrict__ Qb, const _Float16* __restrict__ Kb,
    const _Float16* __restrict__ Vb, const int* __restrict__ src,
    const int* __restrict__ rp, const _Float16* __restrict__ epsl,
    ushort* __restrict__ attnb, int N)
{
  __shared__ float red[4][16][64];
  int tid = threadIdx.x, ln = tid & 63;
  int wv = __builtin_amdgcn_readfirstlane(tid >> 6);
  int w = blockIdx.x * 4 + wv;
  bool wok = w < N;
  int wc = wok ? w : N - 1;
  int es = ln >> 2, h = ln & 3;

  float q[16];
  const float* qp = Qb + (size_t)wc * 64 + h * 16;
  #pragma unroll
  for (int i = 0; i < 4; ++i)
    *(float4*)(q + 4 * i) = ((const float4*)qp)[i];

  int e0 = rp[wc], e1 = rp[wc + 1];
  int elast = e1 - 1;
  float acc[16];
  #pragma unroll
  for (int i = 0; i < 16; ++i) acc[i] = 0.f;
  float z = 0.f;

  for (int e = e0; e < e1; e += 16) {
    int eidx = e + es;
    bool val = eidx <= elast;
    int eic = val ? eidx : elast;
    int sidx = src[eic];
    size_t ko = (size_t)sidx * 64 + h * 16;
    h8v k0 = *(const h8v*)(Kb + ko);
    h8v k1 = *(const h8v*)(Kb + ko + 8);
    h8v v0 = *(const h8v*)(Vb + ko);
    h8v v1 = *(const h8v*)(Vb + ko + 8);
    float pe_ = (float)epsl[(size_t)eic * 4 + h];
    float t0 = 0.f, t1 = 0.f;
    #pragma unroll
    for (int i = 0; i < 8; ++i) {
      t0 = fmaf((float)k0[i], q[i], t0);
      t1 = fmaf((float)k1[i], q[i + 8], t1);
    }
    float sc = fminf(fmaxf(t0 + t1 + pe_, -CLB), CLB);
    float sv = __builtin_amdgcn_exp2f(sc);
    sv = val ? sv : 0.f;
    z += sv;
    #pragma unroll
    for (int i = 0; i < 8; ++i) {
      acc[i] = fmaf(sv, (float)v0[i], acc[i]);
      acc[i + 8] = fmaf(sv, (float)v1[i], acc[i + 8]);
    }
  }

  z += __shfl_xor(z, 4, 64);
  z += __shfl_xor(z, 8, 64);
  z += __shfl_xor(z, 16, 64);
  z += __shfl_xor(z, 32, 64);

  float* rw = &red[wv][es][h * 16];
  #pragma unroll
  for (int i = 0; i < 4; ++i)
    *(float4*)(rw + i * 4) = *(const float4*)(acc + i * 4);
  __asm__ volatile("s_waitcnt lgkmcnt(0)" ::: "memory");
  int c = ln;
  float zc = __shfl(z, c >> 4, 64);
  float s = 0.f;
  #pragma unroll
  for (int es2 = 0; es2 < 16; ++es2) s += red[wv][es2][c];
  if (wok) attnb[(size_t)w * 64 + c] = (ushort)f2bs(s / (zc + 1e-10f));
}

// ---------------- fused post (+ optional qkv of next layer) ------------------
// Per-wave 16-row slice; zero __syncthreads; batched weight-frag prefetch.
template<int TAIL>
__global__ __launch_bounds__(256, 3) void post_fused(
    ushort* __restrict__ Hb, const ushort* __restrict__ attnb,
    const float* __restrict__ I, const short* __restrict__ wb,
    const float* __restrict__ bpi, const float* __restrict__ bO,
    const float* __restrict__ g1, const float* __restrict__ b1,
    const float* __restrict__ bf1, const float* __restrict__ bf2,
    const float* __restrict__ g2, const float* __restrict__ b2,
    const float* __restrict__ bq, const float* __restrict__ bk,
    const float* __restrict__ bv, float* __restrict__ Qb,
    ushort* __restrict__ Kb, ushort* __restrict__ Vb, int N, int lay)
{
  constexpr float BN_S = 0.9999950000374997f;
  __shared__ __align__(16) char bufc[4][4864];
  int tid = threadIdx.x, wv = tid >> 6, ln = tid & 63;
  int q = ln >> 4, p16 = ln & 15;
  int nb0 = blockIdx.x * 64;
  int wbase = lay * PL;
  int rb = nb0 + wv * 16 + q * 4;
  int r_[4];
  #pragma unroll
  for (int j = 0; j < 4; ++j) { int rr = rb + j; r_[j] = (rr < N) ? rr : N - 1; }

  // C-layout loads of residual h and attn (issued first; L2-hot)
  float hC[4][4], aC[4][4];
  #pragma unroll
  for (int j = 0; j < 4; ++j) {
    const ushort* hp = Hb + (size_t)r_[j] * 64 + p16;
    const ushort* ap = attnb + (size_t)r_[j] * 64 + p16;
    #pragma unroll
    for (int ct = 0; ct < 4; ++ct) {
      hC[ct][j] = bs2f((short)hp[ct * 16]);
      aC[ct][j] = bs2f((short)ap[ct * 16]);
    }
  }
  int arow = nb0 + wv * 16 + p16; if (arow >= N) arow = N - 1;

  // ---- u = I@Wpi + bpi + attn (batched WPI frags) ----
  f4v uacc[4] = {};
  {
    s8v pih[4], pil[4];
    #pragma unroll
    for (int ct = 0; ct < 4; ++ct) {
      int bo = (ct * 16 + p16) * 32 + 8 * q;
      pih[ct] = *(const s8v*)(wb + wbase + OFF_WPI + bo);
      pil[ct] = *(const s8v*)(wb + wbase + OFF_WPI + 2048 + bo);
    }
    s8v ah = {}, al = {};
    if (q < 2) split8(I + (size_t)arow * 16 + 8 * q, ah, al);
    #pragma unroll
    for (int ct = 0; ct < 4; ++ct) {
      uacc[ct] = MFMA(ah, pih[ct], uacc[ct]);
      uacc[ct] = MFMA(ah, pil[ct], uacc[ct]);
      uacc[ct] = MFMA(al, pih[ct], uacc[ct]);
    }
  }
  // issue ALL WO frag loads before the u LDS round-trip they must hide
  s8v woh[2][4], wol[2][4];
  #pragma unroll
  for (int kt = 0; kt < 2; ++kt)
    #pragma unroll
    for (int ct = 0; ct < 4; ++ct) {
      int bo = (ct * 16 + p16) * 64 + kt * 32 + 8 * q;
      woh[kt][ct] = *(const s8v*)(wb + wbase + OFF_WO + bo);
      wol[kt][ct] = *(const s8v*)(wb + wbase + OFF_WO + 4096 + bo);
    }
  float* bf = (float*)bufc[wv]; // stride-SF f32 view
  #pragma unroll
  for (int ct = 0; ct < 4; ++ct) {
    int col = ct * 16 + p16;
    float bb = bpi[lay * 64 + col];
    #pragma unroll
    for (int j = 0; j < 4; ++j)
      bf[(q * 4 + j) * SF + col] = uacc[ct][j] + bb + aC[ct][j];
  }
  // ---- v = u@WO + bO ; hw = h + v ; LN1 -> h1 ----
  f4v vacc[4] = {};
  #pragma unroll
  for (int kt = 0; kt < 2; ++kt) {
    s8v ah, al;
    split8(&bf[p16 * SF + kt * 32 + 8 * q], ah, al);
    #pragma unroll
    for (int ct = 0; ct < 4; ++ct) {
      vacc[ct] = MFMA(ah, woh[kt][ct], vacc[ct]);
      vacc[ct] = MFMA(ah, wol[kt][ct], vacc[ct]);
      vacc[ct] = MFMA(al, woh[kt][ct], vacc[ct]);
    }
  }
  float hw[4][4];
  #pragma unroll
  for (int ct = 0; ct < 4; ++ct) {
    int col = ct * 16 + p16;
    float bb = bO[lay * 64 + col];
    #pragma unroll
    for (int j = 0; j < 4; ++j)
      hw[ct][j] = hC[ct][j] + vacc[ct][j] + bb;
  }
  float h1r[4][4];
  {
    float s0[4], mu[4], vv[4], rs[4];
    #pragma unroll
    for (int j = 0; j < 4; ++j) s0[j] = hw[0][j] + hw[1][j] + hw[2][j] + hw[3][j];
    #pragma unroll
    for (int msk = 1; msk < 16; msk <<= 1)
      #pragma unroll
      for (int j = 0; j < 4; ++j) s0[j] += __shfl_xor(s0[j], msk, 64);
    #pragma unroll
    for (int j = 0; j < 4; ++j) { mu[j] = s0[j] * (1.f / 64.f); vv[j] = 0.f; }
    #pragma unroll
    for (int ct = 0; ct < 4; ++ct)
      #pragma unroll
      for (int j = 0; j < 4; ++j) { float d = hw[ct][j] - mu[j]; hw[ct][j] = d; vv[j] += d * d; }
    #pragma unroll
    for (int msk = 1; msk < 16; msk <<= 1)
      #pragma unroll
      for (int j = 0; j < 4; ++j) vv[j] += __shfl_xor(vv[j], msk, 64);
    #pragma unroll
    for (int j = 0; j < 4; ++j) rs[j] = 1.f / sqrtf(vv[j] * (1.f / 64.f) + 1e-5f);
    #pragma unroll
    for (int ct = 0; ct < 4; ++ct) {
      int col = ct * 16 + p16;
      float gg = g1[lay * 64 + col], bb = b1[lay * 64 + col];
      #pragma unroll
      for (int j = 0; j < 4; ++j)
        h1r[ct][j] = (hw[ct][j] * rs[j] * gg + bb) * BN_S;
    }
  }
  // ---- h1 -> LDS; t = relu(h1@Wf1 + bf1) (batched per-kt WF1 frags) ----
  #pragma unroll
  for (int ct = 0; ct < 4; ++ct)
    #pragma unroll
    for (int j = 0; j < 4; ++j)
      bf[(q * 4 + j) * SF + ct * 16 + p16] = h1r[ct][j];
  f4v tacc[8] = {};
  #pragma unroll
  for (int kt = 0; kt < 2; ++kt) {
    s8v f1h[8], f1l[8];
    #pragma unroll
    for (int ct = 0; ct < 8; ++ct) {
      int bo = (ct * 16 + p16) * 64 + kt * 32 + 8 * q;
      f1h[ct] = *(const s8v*)(wb + wbase + OFF_WF1 + bo);
      f1l[ct] = *(const s8v*)(wb + wbase + OFF_WF1 + 8192 + bo);
    }
    s8v ah, al;
    split8(&bf[p16 * SF + kt * 32 + 8 * q], ah, al);
    #pragma unroll
    for (int ct = 0; ct < 8; ++ct) {
      tacc[ct] = MFMA(ah, f1h[ct], tacc[ct]);
      tacc[ct] = MFMA(ah, f1l[ct], tacc[ct]);
      tacc[ct] = MFMA(al, f1h[ct], tacc[ct]);
    }
  }
  ushort* bt = (ushort*)bufc[wv]; // stride-ST bf16 view for t
  #pragma unroll
  for (int ct = 0; ct < 8; ++ct) {
    int col = ct * 16 + p16;
    float bb = bf1[lay * 128 + col];
    #pragma unroll
    for (int j = 0; j < 4; ++j)
      bt[(q * 4 + j) * ST + col] = (ushort)f2bs(fmaxf(tacc[ct][j] + bb, 0.f));
  }
  // ---- y = t@Wf2 + bf2 ; w2 = h1 + y ; LN2 -> h2 ----
  f4v yacc[4] = {};
  #pragma unroll
  for (int kt = 0; kt < 4; ++kt) {
    s8v f2h[4], f2l[4];
    #pragma unroll
    for (int ct = 0; ct < 4; ++ct) {
      int bo = (ct * 16 + p16) * 128 + kt * 32 + 8 * q;
      f2h[ct] = *(const s8v*)(wb + wbase + OFF_WF2 + bo);
      f2l[ct] = *(const s8v*)(wb + wbase + OFF_WF2 + 8192 + bo);
    }
    s8v at = *(const s8v*)&bt[p16 * ST + kt * 32 + 8 * q];
    #pragma unroll
    for (int ct = 0; ct < 4; ++ct) {
      yacc[ct] = MFMA(at, f2h[ct], yacc[ct]);
      yacc[ct] = MFMA(at, f2l[ct], yacc[ct]);
    }
  }
  float w2[4][4];
  #pragma unroll
  for (int ct = 0; ct < 4; ++ct) {
    int col = ct * 16 + p16;
    float bb = bf2[lay * 64 + col];
    #pragma unroll
    for (int j = 0; j < 4; ++j)
      w2[ct][j] = h1r[ct][j] + yacc[ct][j] + bb;
  }
  ushort h2b[4][4];
  {
    float s0[4], mu[4], vv[4], rs[4];
    #pragma unroll
    for (int j = 0; j < 4; ++j) s0[j] = w2[0][j] + w2[1][j] + w2[2][j] + w2[3][j];
    #pragma unroll
    for (int msk = 1; msk < 16; msk <<= 1)
      #pragma unroll
      for (int j = 0; j < 4; ++j) s0[j] += __shfl_xor(s0[j], msk, 64);
    #pragma unroll
    for (int j = 0; j < 4; ++j) { mu[j] = s0[j] * (1.f / 64.f); vv[j] = 0.f; }
    #pragma unroll
    for (int ct = 0; ct < 4; ++ct)
      #pragma unroll
      for (int j = 0; j < 4; ++j) { float d = w2[ct][j] - mu[j]; w2[ct][j] = d; vv[j] += d * d; }
    #pragma unroll
    for (int msk = 1; msk < 16; msk <<= 1)
      #pragma unroll
      for (int j = 0; j < 4; ++j) vv[j] += __shfl_xor(vv[j], msk, 64);
    #pragma unroll
    for (int j = 0; j < 4; ++j) rs[j] = 1.f / sqrtf(vv[j] * (1.f / 64.f) + 1e-5f);
    #pragma unroll
    for (int ct = 0; ct < 4; ++ct) {
      int col = ct * 16 + p16;
      float gg = g2[lay * 64 + col], bb = b2[lay * 64 + col];
      #pragma unroll
      for (int j = 0; j < 4; ++j)
        h2b[ct][j] = (ushort)f2bs((w2[ct][j] * rs[j] * gg + bb) * BN_S);
    }
  }
  // ---- store h2 -> Hb ----
  #pragma unroll
  for (int ct = 0; ct < 4; ++ct) {
    int col = ct * 16 + p16;
    #pragma unroll
    for (int j = 0; j < 4; ++j)
      if (rb + j < N) Hb[(size_t)(rb + j) * 64 + col] = h2b[ct][j];
  }
  if (TAIL) {
    // ---- qkv(lay+1): h2 -> LDS transpose -> A-frags -> batched MFMAs ----
    ushort* bu = (ushort*)bufc[wv]; // stride-SB view
    #pragma unroll
    for (int ct = 0; ct < 4; ++ct)
      #pragma unroll
      for (int j = 0; j < 4; ++j)
        bu[(q * 4 + j) * SB + ct * 16 + p16] = h2b[ct][j];
    s8v a0 = *(const s8v*)&bu[p16 * SB + 8 * q];
    s8v a1 = *(const s8v*)&bu[p16 * SB + 32 + 8 * q];
    int wb2 = (lay + 1) * PL;
    f4v qa[4] = {}, ka[4] = {}, va[4] = {};
    #pragma unroll
    for (int kt = 0; kt < 2; ++kt) {
      s8v a = kt ? a1 : a0;
      #pragma unroll
      for (int c2 = 0; c2 < 2; ++c2) {
        s8v qh[2], ql[2], kh[2], kl[2], vh[2], vl[2];
        #pragma unroll
        for (int u2 = 0; u2 < 2; ++u2) {
          int ct = c2 * 2 + u2;
          int bo = (ct * 16 + p16) * 64 + kt * 32 + 8 * q;
          qh[u2] = *(const s8v*)(wb + wb2 + OFF_WQ + bo);
          ql[u2] = *(const s8v*)(wb + wb2 + OFF_WQ + 4096 + bo);
          kh[u2] = *(const s8v*)(wb + wb2 + OFF_WK + bo);
          kl[u2] = *(const s8v*)(wb + wb2 + OFF_WK + 4096 + bo);
          vh[u2] = *(const s8v*)(wb + wb2 + OFF_WV + bo);
          vl[u2] = *(const s8v*)(wb + wb2 + OFF_WV + 4096 + bo);
        }
        #pragma unroll
        for (int u2 = 0; u2 < 2; ++u2) {
          int ct = c2 * 2 + u2;
          qa[ct] = MFMA(a, qh[u2], qa[ct]); qa[ct] = MFMA(a, ql[u2], qa[ct]);
          ka[ct] = MFMA(a, kh[u2], ka[ct]); ka[ct] = MFMA(a, kl[u2], ka[ct]);
          va[ct] = MFMA(a, vh[u2], va[ct]); va[ct] = MFMA(a, vl[u2], va[ct]);
        }
      }
    }
    #pragma unroll
    for (int ct = 0; ct < 4; ++ct) {
      int col = ct * 16 + p16;
      float bQ = bq[(lay + 1) * 64 + col];
      float bK = bk[(lay + 1) * 64 + col];
      float bV = bv[(lay + 1) * 64 + col];
      #pragma unroll
      for (int j = 0; j < 4; ++j) {
        if (rb + j < N) {
          size_t o = (size_t)(rb + j) * 64 + col;
          Qb[o] = (qa[ct][j] + bQ) * QSC;
          Kb[o] = f2hs(ka[ct][j] + bK);
          Vb[o] = f2hs(va[ct][j] + bV);
        }
      }
    }
  }
}

// ---------------- readout: out0 = h ; x_hat = selu(h@Wr1+br1)@Wr2+br2 --------
__global__ __launch_bounds__(256, 3) void readout_f(
    const ushort* __restrict__ Hb, const short* __restrict__ wb,
    const float* __restrict__ br1, const float* __restrict__ br2,
    float* __restrict__ out, int N)
{
  __shared__ __align__(16) char bufc[4][2816];
  int tid = threadIdx.x, wv = tid >> 6, ln = tid & 63;
  int q = ln >> 4, p16 = ln & 15;
  int nb0 = blockIdx.x * 64;
  int rb = nb0 + wv * 16 + q * 4;
  int r_[4];
  #pragma unroll
  for (int j = 0; j < 4; ++j) { int rr = rb + j; r_[j] = (rr < N) ? rr : N - 1; }

  ushort hC[4][4];
  #pragma unroll
  for (int j = 0; j < 4; ++j) {
    const ushort* hp = Hb + (size_t)r_[j] * 64 + p16;
    #pragma unroll
    for (int ct = 0; ct < 4; ++ct) hC[ct][j] = hp[ct * 16];
  }
  // h out (fp32)
  #pragma unroll
  for (int ct = 0; ct < 4; ++ct) {
    int col = ct * 16 + p16;
    #pragma unroll
    for (int j = 0; j < 4; ++j)
      if (rb + j < N) out[(size_t)(rb + j) * 64 + col] = bs2f((short)hC[ct][j]);
  }
  // h -> LDS transpose for Wr1 A-side
  ushort* bu = (ushort*)bufc[wv];
  #pragma unroll
  for (int ct = 0; ct < 4; ++ct)
    #pragma unroll
    for (int j = 0; j < 4; ++j)
      bu[(q * 4 + j) * SB + ct * 16 + p16] = hC[ct][j];
  // batched Wr1 frags
  s8v r1h[2], r1l[2];
  #pragma unroll
  for (int kt = 0; kt < 2; ++kt) {
    int bo = p16 * 64 + kt * 32 + 8 * q;
    r1h[kt] = *(const s8v*)(wb + OFF_WR1 + bo);
    r1l[kt] = *(const s8v*)(wb + OFF_WR1 + 1024 + bo);
  }
  s8v a0 = *(const s8v*)&bu[p16 * SB + 8 * q];
  s8v a1 = *(const s8v*)&bu[p16 * SB + 32 + 8 * q];
  f4v macc = {};
  macc = MFMA(a0, r1h[0], macc);
  macc = MFMA(a0, r1l[0], macc);
  macc = MFMA(a1, r1h[1], macc);
  macc = MFMA(a1, r1l[1], macc);
  const float SC = 1.0507009873554805f, AL = 1.6732632423543772f;
  float* bf = (float*)bufc[wv]; // stride-25 f32 view for md
  #pragma unroll
  for (int j = 0; j < 4; ++j) {
    float md = macc[j] + br1[p16];
    md = (md > 0.f) ? SC * md : SC * AL * expm1f(md);
    bf[(q * 4 + j) * 25 + p16] = md;
  }
  // batched Wr2 frags (8ct x hi/lo)
  s8v r2h[8], r2l[8];
  #pragma unroll
  for (int ct = 0; ct < 8; ++ct) {
    int bo = (ct * 16 + p16) * 32 + 8 * q;
    r2h[ct] = *(const s8v*)(wb + OFF_WR2 + bo);
    r2l[ct] = *(const s8v*)(wb + OFF_WR2 + 4096 + bo);
  }
  s8v ah = {}, al = {};
  if (q < 2) split8(&bf[p16 * 25 + 8 * q], ah, al);
  f4v xacc[8] = {};
  #pragma unroll
  for (int ct = 0; ct < 8; ++ct) {
    xacc[ct] = MFMA(ah, r2h[ct], xacc[ct]);
    xacc[ct] = MFMA(ah, r2l[ct], xacc[ct]);
    xacc[ct] = MFMA(al, r2h[ct], xacc[ct]);
  }
  #pragma unroll
  for (int ct = 0; ct < 8; ++ct) {
    int col = ct * 16 + p16;
    float bb = br2[col];
    #pragma unroll
    for (int j = 0; j < 4; ++j)
      if (rb + j < N)
        out[(size_t)N * 64 + (size_t)(rb + j) * 128 + col] = xacc[ct][j] + bb;
  }
}

extern "C" void kernel_launch(void* const* d_in, const int* in_sizes, int n_in,
                              void* d_out, int out_size, void* d_ws, size_t ws_size,
                              hipStream_t stream)
{
  const int* src    = (const int*)d_in[0];
  const int* dst    = (const int*)d_in[1];
  const float* x    = (const float*)d_in[2];
  const float* pe   = (const float*)d_in[3];
  const float* de   = (const float*)d_in[4];
  const float* m    = (const float*)d_in[5];
  const float* I    = (const float*)d_in[6];
  const float* W_h  = (const float*)d_in[7];
  const float* W_pe = (const float*)d_in[8];
  const float* b_pe = (const float*)d_in[9];
  const float* W_de = (const float*)d_in[10];
  const float* b_de = (const float*)d_in[11];
  const float* W_m  = (const float*)d_in[12];
  const float* b_m  = (const float*)d_in[13];
  const float* Wq   = (const float*)d_in[14];
  const float* bq   = (const float*)d_in[15];
  const float* Wk   = (const float*)d_in[16];
  const float* bk   = (const float*)d_in[17];
  const float* Wv   = (const float*)d_in[18];
  const float* bv   = (const float*)d_in[19];
  const float* Wpd  = (const float*)d_in[20];
  const float* bpd  = (const float*)d_in[21];
  const float* Wpm  = (const float*)d_in[22];
  const float* bpm  = (const float*)d_in[23];
  const float* WO   = (const float*)d_in[24];
  const float* bO   = (const float*)d_in[25];
  const float* Wpi  = (const float*)d_in[26];
  const float* bpi  = (const float*)d_in[27];
  const float* g1   = (const float*)d_in[28];
  const float* b1   = (const float*)d_in[29];
  const float* g2   = (const float*)d_in[30];
  const float* b2   = (const float*)d_in[31];
  const float* Wf1  = (const float*)d_in[32];
  const float* bf1  = (const float*)d_in[33];
  const float* Wf2  = (const float*)d_in[34];
  const float* bf2  = (const float*)d_in[35];
  const float* Wr1  = (const float*)d_in[36];
  const float* br1  = (const float*)d_in[37];
  const float* Wr2  = (const float*)d_in[38];
  const float* br2  = (const float*)d_in[39];

  const int E = in_sizes[0];
  const int N = in_sizes[2] / 128;

  // ws: rowptr | fold | split-weights | H (bf16) | [eps both layers]
  char* ws = (char*)d_ws;
  int* row_ptr = (int*)ws;
  size_t rp_bytes = (((size_t)(N + 1) * 4) + 255) & ~(size_t)255;
  float* fold = (float*)(ws + rp_bytes);
  short* wb = (short*)(ws + rp_bytes + 1024);
  ushort* Hb = (ushort*)(ws + rp_bytes + 1024 + (size_t)WBF_TOT * 2);
  size_t ws_used = rp_bytes + 1024 + (size_t)WBF_TOT * 2 + (size_t)N * 128;

  // d_out doubles as scratch until readout rewrites every byte:
  // K f16 [0,128N) | V f16 [128N,256N) | Q f32 [256N,512N) | attn bf16 [512N,640N)
  // | eps fallback f16 [640N, 640N+8E)  (fits iff E <= 16N, true here)
  float* out = (float*)d_out;
  ushort* Kb = (ushort*)out;
  ushort* Vb = Kb + (size_t)N * 64;
  float* Qb = out + (size_t)N * 64;
  ushort* attnb = (ushort*)((char*)d_out + (size_t)N * 512);

  bool both_eps = ws_size >= ws_used + (size_t)E * 16;
  ushort *eps0, *eps1 = nullptr;
  if (both_eps) {
    eps0 = (ushort*)(ws + ws_used);
    eps1 = eps0 + (size_t)E * 4;
  } else {
    eps0 = (ushort*)((char*)d_out + (size_t)N * 640);
  }

  int nb64 = (N + 63) / 64;

  prep_kernel<<<dim3(32, 18), 256, 0, stream>>>(Wq, Wk, Wv, WO, Wf1, Wf2, Wpi,
                                                W_h, W_pe, Wr1, Wr2, wb);
  fold_kernel<<<1, 256, 0, stream>>>(W_de, b_de, W_m, b_m, Wpd, bpd, Wpm, bpm, fold);
  rowptr_kernel<<<(N + 256) / 256, 256, 0, stream>>>(dst, E, N, row_ptr);
  if (both_eps)
    escore_kernel<<<(E + 255) / 256, 256, 0, stream>>>(de, m, fold, eps0, eps1, E, 0);

  hinit_qkv<<<nb64, 256, 0, stream>>>(x, pe, wb, b_pe, bq, bk, bv, Hb, Qb, Kb, Vb, N);

  for (int lay = 0; lay < 2; ++lay) {
    if (!both_eps)
      escore_kernel<<<(E + 255) / 256, 256, 0, stream>>>(de, m, fold, eps0, nullptr, E, lay);
    edge_kernel<<<(N + 3) / 4, 256, 0, stream>>>(Qb, (const _Float16*)Kb,
        (const _Float16*)Vb, src, row_ptr,
        (const _Float16*)((both_eps && lay) ? eps1 : eps0), attnb, N);
    if (lay == 0)
      post_fused<1><<<nb64, 256, 0, stream>>>(Hb, attnb, I, wb, bpi, bO, g1, b1,
          bf1, bf2, g2, b2, bq, bk, bv, Qb, Kb, Vb, N, 0);
    else
      post_fused<0><<<nb64, 256, 0, stream>>>(Hb, attnb, I, wb, bpi, bO, g1, b1,
          bf1, bf2, g2, b2, bq, bk, bv, Qb, Kb, Vb, N, 1);
  }
  readout_f<<<nb64, 256, 0, stream>>>(Hb, wb, br1, br2, out, N);
}